// Round 2
// baseline (268.476 us; speedup 1.0000x reference)
//
#include <hip/hip_runtime.h>
#include <hip/hip_bf16.h>
#include <math.h>

#define Bn   4
#define Hh   56
#define Wn   56
#define Cn   256
#define NHn  8
#define HDn  32
#define Nn   3136
#define LLn  9
#define PLn  196
#define PWn  14
#define KTABn 2048
#define Mrows 12544
#define MP   224            // padded pool-key count (14 x 16)
#define PLSZ (Bn*NHn*Nn*HDn)   // one head-major plane, elements

// cvt5 segment offsets (elements)
#define XCNT   3211264
#define QWOFF  XCNT
#define KVWOFF (QWOFF + 65536)
#define SRWOFF (KVWOFF + 131072)
#define PWOFF  (SRWOFF + 65536)
#define TOTCVT (PWOFF + 65536)

typedef __attribute__((ext_vector_type(8))) short short8v;
typedef __attribute__((ext_vector_type(4))) float float4v;

__device__ __forceinline__ unsigned short f2b(float f) {
  __hip_bfloat16 h = __float2bfloat16(f);
  return *(unsigned short*)&h;
}
__device__ __forceinline__ float b2f(unsigned short u) {
  union { unsigned int i; float f; } x; x.i = ((unsigned int)u) << 16; return x.f;
}
__device__ __forceinline__ void u4_to8f(uint4 u, float* o) {
  o[0]=b2f((unsigned short)(u.x&0xffff)); o[1]=b2f((unsigned short)(u.x>>16));
  o[2]=b2f((unsigned short)(u.y&0xffff)); o[3]=b2f((unsigned short)(u.y>>16));
  o[4]=b2f((unsigned short)(u.z&0xffff)); o[5]=b2f((unsigned short)(u.z>>16));
  o[6]=b2f((unsigned short)(u.w&0xffff)); o[7]=b2f((unsigned short)(u.w>>16));
}

// ---------------------------------------------------------------------------
// Convert x + q_w + kv_w + sr_w + proj_w to one contiguous bf16 area.
// ---------------------------------------------------------------------------
__launch_bounds__(256)
__global__ void cvt5(const float* __restrict__ x, const float* __restrict__ qw,
                     const float* __restrict__ kvw, const float* __restrict__ srw,
                     const float* __restrict__ pw, unsigned short* __restrict__ dst)
{
  const int i = (blockIdx.x * 256 + threadIdx.x) * 4;
  const float* src; int off;
  if      (i < XCNT)   { src = x;   off = 0; }
  else if (i < KVWOFF) { src = qw;  off = QWOFF; }
  else if (i < SRWOFF) { src = kvw; off = KVWOFF; }
  else if (i < PWOFF)  { src = srw; off = SRWOFF; }
  else                 { src = pw;  off = PWOFF; }
  const float4 v = *(const float4*)(src + (i - off));
  ushort4 o2;
  o2.x = f2b(v.x); o2.y = f2b(v.y); o2.z = f2b(v.z); o2.w = f2b(v.w);
  *(ushort4*)(dst + i) = o2;
}

// ---------------------------------------------------------------------------
// bf16 MFMA GEMM, 512 threads = 8 waves.
// MODE 0 (proj): fp32 out via LDS-staged stores (two row-halves).
// MODE 1 (QKVS): bf16 out, fused per-head norm epilogue.
//   segs 0-2 (q/k/v) -> head-major planes [b*8+h][N][32] (coalesced for attn_f)
//   seg 3 (gelu sr)  -> fused [n][1024] cols 768.. (read by pool_ln_k)
// ---------------------------------------------------------------------------
template <int MODE>
__launch_bounds__(512)
__global__ void mgemm(const unsigned short* __restrict__ A,
                      const unsigned short* __restrict__ Wb,
                      const float* __restrict__ b0, const float* __restrict__ b1,
                      const float* __restrict__ b2, void* __restrict__ Cv, int Nc,
                      const float* __restrict__ sls, const float* __restrict__ qe,
                      const float* __restrict__ temp, float* __restrict__ Mq,
                      unsigned short* __restrict__ planes)
{
  __shared__ __align__(16) unsigned char smem[34816];
  unsigned short* As = (unsigned short*)smem;            // [128][64]
  unsigned short* Bs = (unsigned short*)(smem + 16384);  // [128][64]
  const int t = threadIdx.x;
  const int w = t >> 6, lane = t & 63;
  const int q = lane >> 4, ln = lane & 15;
  const int n0 = blockIdx.x * 128, m0 = blockIdx.y * 128;
  const int wm = (w >> 1) * 32, wn = (w & 1) * 64;

  float4v acc[2][4];
  #pragma unroll
  for (int mt = 0; mt < 2; ++mt)
    #pragma unroll
    for (int nt = 0; nt < 4; ++nt)
      acc[mt][nt] = (float4v){0.f, 0.f, 0.f, 0.f};

  for (int k0 = 0; k0 < 256; k0 += 64) {
    #pragma unroll
    for (int j = 0; j < 2; ++j) {
      const int u = t + 512 * j;
      const int r = u >> 3, cg = u & 7;
      const int cs = cg ^ (r & 7);
      const uint4 av = *(const uint4*)(A  + (size_t)(m0 + r) * 256 + k0 + cg * 8);
      *(uint4*)(As + r * 64 + cs * 8) = av;
      const uint4 bv = *(const uint4*)(Wb + (size_t)(n0 + r) * 256 + k0 + cg * 8);
      *(uint4*)(Bs + r * 64 + cs * 8) = bv;
    }
    __syncthreads();
    #pragma unroll
    for (int kk = 0; kk < 2; ++kk) {
      short8v af[2], bfr[4];
      const int cg = kk * 4 + q;
      #pragma unroll
      for (int mt = 0; mt < 2; ++mt) {
        const int r = wm + mt * 16 + ln;
        af[mt] = *(const short8v*)(As + r * 64 + (cg ^ (r & 7)) * 8);
      }
      #pragma unroll
      for (int nt = 0; nt < 4; ++nt) {
        const int r = wn + nt * 16 + ln;
        bfr[nt] = *(const short8v*)(Bs + r * 64 + (cg ^ (r & 7)) * 8);
      }
      #pragma unroll
      for (int mt = 0; mt < 2; ++mt)
        #pragma unroll
        for (int nt = 0; nt < 4; ++nt)
          acc[mt][nt] = __builtin_amdgcn_mfma_f32_16x16x32_bf16(af[mt], bfr[nt], acc[mt][nt], 0, 0, 0);
    }
    __syncthreads();
  }

  if constexpr (MODE == 0) {
    float* C = (float*)Cv;
    float* tileF = (float*)smem;
    float bia[4];
    #pragma unroll
    for (int nt = 0; nt < 4; ++nt) bia[nt] = b0[n0 + wn + nt * 16 + ln];
    #pragma unroll
    for (int half = 0; half < 2; ++half) {
      if ((w >> 2) == half) {
        #pragma unroll
        for (int mt = 0; mt < 2; ++mt)
          #pragma unroll
          for (int r = 0; r < 4; ++r)
            #pragma unroll
            for (int nt = 0; nt < 4; ++nt)
              tileF[(wm - half*64 + mt*16 + q*4 + r) * 132 + wn + nt*16 + ln] = acc[mt][nt][r] + bia[nt];
      }
      __syncthreads();
      #pragma unroll
      for (int j = 0; j < 4; ++j) {
        const int i = j * 512 + t;
        const int row = i >> 5, ch = i & 31;
        float4 v = *(const float4*)(tileF + row * 132 + ch * 4);
        *(float4*)(C + (size_t)(m0 + half * 64 + row) * Nc + n0 + ch * 4) = v;
      }
      __syncthreads();
    }
  } else {
    unsigned short* Cb = (unsigned short*)Cv;
    unsigned short* tileC = (unsigned short*)smem;     // [128][136] bf16
    const int seg = n0 >> 8;
    const int h0 = (n0 + wn) >> 5, h1 = h0 + 1;
    float spt0 = 0.f, spt1 = 0.f;
    if (seg == 0) { spt0 = log1pf(__expf(temp[h0])); spt1 = log1pf(__expf(temp[h1])); }
    float bia[4], qev[4];
    #pragma unroll
    for (int nt = 0; nt < 4; ++nt) {
      const int col = n0 + wn + nt * 16 + ln;
      bia[nt] = (seg == 0) ? b0[col] : (seg == 3 ? b2[col - 768] : b1[col - 256]);
      if (seg == 0) qev[nt] = qe[col];
    }
    #pragma unroll
    for (int mt = 0; mt < 2; ++mt) {
      #pragma unroll
      for (int r = 0; r < 4; ++r) {
        const int row = m0 + wm + mt * 16 + q * 4 + r;
        const int lrow = wm + mt * 16 + q * 4 + r;
        float vals[4];
        #pragma unroll
        for (int nt = 0; nt < 4; ++nt) vals[nt] = acc[mt][nt][r] + bia[nt];
        if (seg == 0) {
          float ss0 = vals[0]*vals[0] + vals[1]*vals[1];
          float ss1 = vals[2]*vals[2] + vals[3]*vals[3];
          #pragma unroll
          for (int mk = 1; mk <= 8; mk <<= 1) { ss0 += __shfl_xor(ss0, mk); ss1 += __shfl_xor(ss1, mk); }
          const float i0 = 1.f / fmaxf(sqrtf(ss0), 1e-12f);
          const float i1 = 1.f / fmaxf(sqrtf(ss1), 1e-12f);
          const int nidx = row % Nn, bb = row / Nn;
          const float sl = sls[nidx];
          float qsv[4];
          #pragma unroll
          for (int nt = 0; nt < 4; ++nt) {
            const float inv = (nt < 2) ? i0 : i1;
            const float sp  = (nt < 2) ? spt0 : spt1;
            qsv[nt] = (vals[nt] * inv + qev[nt]) * sp * sl;
          }
          float t0 = qsv[0]*qsv[0] + qsv[1]*qsv[1];
          float t1 = qsv[2]*qsv[2] + qsv[3]*qsv[3];
          #pragma unroll
          for (int mk = 1; mk <= 8; mk <<= 1) { t0 += __shfl_xor(t0, mk); t1 += __shfl_xor(t1, mk); }
          if (ln == 0) {
            Mq[((size_t)(bb * NHn + h0)) * Nn + nidx] = sqrtf(t0);
            Mq[((size_t)(bb * NHn + h1)) * Nn + nidx] = sqrtf(t1);
          }
          #pragma unroll
          for (int nt = 0; nt < 4; ++nt)
            tileC[lrow * 136 + wn + nt*16 + ln] = f2b(qsv[nt]);
        } else if (seg == 1) {
          float ss0 = vals[0]*vals[0] + vals[1]*vals[1];
          float ss1 = vals[2]*vals[2] + vals[3]*vals[3];
          #pragma unroll
          for (int mk = 1; mk <= 8; mk <<= 1) { ss0 += __shfl_xor(ss0, mk); ss1 += __shfl_xor(ss1, mk); }
          const float i0 = 1.f / fmaxf(sqrtf(ss0), 1e-12f);
          const float i1 = 1.f / fmaxf(sqrtf(ss1), 1e-12f);
          #pragma unroll
          for (int nt = 0; nt < 4; ++nt)
            tileC[lrow * 136 + wn + nt*16 + ln] = f2b(vals[nt] * ((nt < 2) ? i0 : i1));
        } else if (seg == 2) {
          #pragma unroll
          for (int nt = 0; nt < 4; ++nt)
            tileC[lrow * 136 + wn + nt*16 + ln] = f2b(vals[nt]);
        } else {
          #pragma unroll
          for (int nt = 0; nt < 4; ++nt) {
            const float v = vals[nt];
            tileC[lrow * 136 + wn + nt*16 + ln] =
              f2b(0.5f * v * (1.0f + erff(v * 0.70710678118654752f)));
          }
        }
      }
    }
    __syncthreads();
    if (seg == 3) {
      // gelu'd sr -> fused [n][1024], cols 768..1023
      #pragma unroll
      for (int j = 0; j < 4; ++j) {
        const int i = j * 512 + t;
        const int row = i >> 4, ch = i & 15;
        uint4 v = *(const uint4*)(tileC + row * 136 + ch * 8);
        *(uint4*)(Cb + (size_t)(m0 + row) * 1024 + n0 + ch * 8) = v;
      }
    } else {
      // q/k/v -> head-major plane [b*8+h][N][32]; per-j one head,
      // wave writes 1 KB contiguous within the plane.
      unsigned short* plane = planes + (size_t)seg * PLSZ;
      const int hbase = (n0 & 255) >> 5;
      const int row = t >> 2, c4 = t & 3;
      const int grow = m0 + row;
      const int bb2 = grow / Nn, nidx = grow - bb2 * Nn;
      #pragma unroll
      for (int j = 0; j < 4; ++j) {
        uint4 v = *(const uint4*)(tileC + row * 136 + (j * 4 + c4) * 8);
        const int bh2 = bb2 * NHn + hbase + j;
        *(uint4*)(plane + ((size_t)bh2 * Nn + nidx) * HDn + c4 * 8) = v;
      }
    }
  }
}

// ---------------------------------------------------------------------------
// fp32 tiled GEMM (pool path only)
// ---------------------------------------------------------------------------
__launch_bounds__(256)
__global__ void gemm_k(const float* __restrict__ A, const float* __restrict__ W,
                       const float* __restrict__ bias, float* __restrict__ Co,
                       int Mr, int Nc, int K)
{
  __shared__ __align__(16) float As[16][64];
  __shared__ __align__(16) float Ws[16][64];
  const int t  = threadIdx.x;
  const int m0 = blockIdx.y * 64, n0 = blockIdx.x * 64;
  const int lm = t >> 2, lk = (t & 3) << 2;
  const int tx = t & 15, ty = t >> 4;
  float acc[4][4] = {};
  int arow = m0 + lm; if (arow >= Mr) arow = Mr - 1;
  const int wrow = n0 + lm;
  for (int k0 = 0; k0 < K; k0 += 16) {
    float4 av = *(const float4*)(A + (size_t)arow * K + k0 + lk);
    As[lk+0][lm] = av.x; As[lk+1][lm] = av.y; As[lk+2][lm] = av.z; As[lk+3][lm] = av.w;
    float4 wv = *(const float4*)(W + (size_t)wrow * K + k0 + lk);
    Ws[lk+0][lm] = wv.x; Ws[lk+1][lm] = wv.y; Ws[lk+2][lm] = wv.z; Ws[lk+3][lm] = wv.w;
    __syncthreads();
    #pragma unroll
    for (int k = 0; k < 16; ++k) {
      float4 a = *(const float4*)&As[k][ty << 2];
      float4 w = *(const float4*)&Ws[k][tx << 2];
      acc[0][0] += a.x*w.x; acc[0][1] += a.x*w.y; acc[0][2] += a.x*w.z; acc[0][3] += a.x*w.w;
      acc[1][0] += a.y*w.x; acc[1][1] += a.y*w.y; acc[1][2] += a.y*w.z; acc[1][3] += a.y*w.w;
      acc[2][0] += a.z*w.x; acc[2][1] += a.z*w.y; acc[2][2] += a.z*w.z; acc[2][3] += a.z*w.w;
      acc[3][0] += a.w*w.x; acc[3][1] += a.w*w.y; acc[3][2] += a.w*w.z; acc[3][3] += a.w*w.w;
    }
    __syncthreads();
  }
  #pragma unroll
  for (int i = 0; i < 4; ++i) {
    const int row = m0 + (ty << 2) + i;
    if (row >= Mr) continue;
    #pragma unroll
    for (int j = 0; j < 4; ++j) {
      const int col = n0 + (tx << 2) + j;
      Co[(size_t)row * Nc + col] = acc[i][j] + bias[col];
    }
  }
}

// ---------------------------------------------------------------------------
// 4x4 average pool of gelu'd sr (fused bf16 cols 768..1023) + LayerNorm over C
// ---------------------------------------------------------------------------
__launch_bounds__(256)
__global__ void pool_ln_k(const unsigned short* __restrict__ fused, float* __restrict__ pln,
                          const float* __restrict__ g, const float* __restrict__ bb)
{
  const int blk = blockIdx.x;
  const int b = blk / PLn, pc = blk % PLn;
  const int pi = pc / PWn, pj = pc % PWn;
  const int c = threadIdx.x;
  float s = 0.f;
  #pragma unroll
  for (int r = 0; r < 4; ++r)
    #pragma unroll
    for (int cc = 0; cc < 4; ++cc) {
      const int n = (pi*4 + r) * Wn + pj*4 + cc;
      s += b2f(fused[((size_t)b * Nn + n) * 1024 + 768 + c]);
    }
  s *= (1.f/16.f);
  float sum = s, sq = s*s;
  #pragma unroll
  for (int m = 32; m >= 1; m >>= 1) { sum += __shfl_xor(sum, m); sq += __shfl_xor(sq, m); }
  __shared__ float sm[8];
  const int lane = c & 63, wid = c >> 6;
  if (lane == 0) { sm[wid] = sum; sm[4+wid] = sq; }
  __syncthreads();
  const float tot  = sm[0]+sm[1]+sm[2]+sm[3];
  const float totq = sm[4]+sm[5]+sm[6]+sm[7];
  const float mu  = tot * (1.f/256.f);
  const float var = totq * (1.f/256.f) - mu*mu;
  pln[(size_t)blk * Cn + c] = (s - mu) / sqrtf(var + 1e-5f) * g[c] + bb[c];
}

// ---------------------------------------------------------------------------
// pool_pack: kvp -> kbf [bh][224 m][32 d] bf16 (L2-normed k, zero pad m>=196)
//            and vbf [bh][32 d][224 m] bf16 (v transposed)
// ---------------------------------------------------------------------------
__launch_bounds__(256)
__global__ void pool_pack(const float* __restrict__ kvp, unsigned short* __restrict__ kbf,
                          unsigned short* __restrict__ vbf)
{
  const int bh = blockIdx.x;
  const int b = bh >> 3, h = bh & 7;
  const int t = threadIdx.x, mg = t >> 5, d = t & 31;
  for (int mi = 0; mi < MP/8; ++mi) {
    const int m = mi * 8 + mg;
    float kv2 = 0.f, vv = 0.f;
    if (m < PLn) {
      kv2 = kvp[((size_t)(b * PLn + m)) * 512 + h * HDn + d];
      vv  = kvp[((size_t)(b * PLn + m)) * 512 + 256 + h * HDn + d];
    }
    float ssn = kv2 * kv2;
    #pragma unroll
    for (int mm = 16; mm >= 1; mm >>= 1) ssn += __shfl_xor(ssn, mm);
    const float kn = (m < PLn) ? kv2 / fmaxf(sqrtf(ssn), 1e-12f) : 0.f;
    kbf[((size_t)bh * MP + m) * HDn + d] = f2b(kn);
    vbf[((size_t)bh * 32 + d) * MP + m] = f2b(vv);
  }
}

// ---------------------------------------------------------------------------
// CPB MLP
// ---------------------------------------------------------------------------
__launch_bounds__(64)
__global__ void cpb_k(const float* __restrict__ rct, const float* __restrict__ w1,
                      const float* __restrict__ b1, const float* __restrict__ w2,
                      const float* __restrict__ b2, float* __restrict__ tab)
{
  const int r = blockIdx.x, t = threadIdx.x;
  const float c0 = rct[r*2], c1 = rct[r*2+1];
  float part[8] = {};
  #pragma unroll
  for (int jj = 0; jj < 8; ++jj) {
    const int j = t * 8 + jj;
    float hv = fmaxf(c0 * w1[j*2] + c1 * w1[j*2+1] + b1[j], 0.f);
    #pragma unroll
    for (int h = 0; h < 8; ++h) part[h] += hv * w2[h*512 + j];
  }
  #pragma unroll
  for (int h = 0; h < 8; ++h)
    for (int mm = 32; mm >= 1; mm >>= 1) part[h] += __shfl_xor(part[h], mm);
  if (t < 8) tab[r*8 + t] = part[t] + b2[t];
}

// ---------------------------------------------------------------------------
// global max over tab and rpb -> scal[0]
// ---------------------------------------------------------------------------
__launch_bounds__(256)
__global__ void redmax_k(const float* __restrict__ tab, const float* __restrict__ rpb,
                         float* __restrict__ scal)
{
  float mx = -1e30f;
  for (int i = threadIdx.x; i < KTABn*NHn; i += 256) mx = fmaxf(mx, tab[i]);
  if (threadIdx.x < NHn*LLn) mx = fmaxf(mx, rpb[threadIdx.x]);
  #pragma unroll
  for (int m = 32; m >= 1; m >>= 1) mx = fmaxf(mx, __shfl_xor(mx, m));
  __shared__ float sm[4];
  if ((threadIdx.x & 63) == 0) sm[threadIdx.x >> 6] = mx;
  __syncthreads();
  if (threadIdx.x == 0) scal[0] = fmaxf(fmaxf(sm[0], sm[1]), fmaxf(sm[2], sm[3]));
}

// ---------------------------------------------------------------------------
// bias_g2: bias2[h][n][224] bf16 = tab[rpi[n][m]][h] ; m>=196 -> -inf
// ---------------------------------------------------------------------------
__launch_bounds__(256)
__global__ void bias_g2(const int* __restrict__ rpi, const float* __restrict__ tab,
                        unsigned short* __restrict__ bias2)
{
  const int tid = blockIdx.x * 256 + threadIdx.x;
  const int n = tid / MP, m = tid - n * MP;
  if (m < PLn) {
    const int idx = rpi[(size_t)n * PLn + m];
    #pragma unroll
    for (int h = 0; h < NHn; ++h)
      bias2[((size_t)h * Nn + n) * MP + m] = f2b(tab[(size_t)idx * NHn + h]);
  } else {
    #pragma unroll
    for (int h = 0; h < NHn; ++h)
      bias2[((size_t)h * Nn + n) * MP + m] = 0xFF80;   // bf16 -inf
  }
}

// ---------------------------------------------------------------------------
// attn_f: FUSED attention, occupancy-first + coalesced layouts.
//  - q/k/v read from head-major planes [b*8+h][N][32]: every wave load is
//    1 KB contiguous (addr = base + lane*16B) instead of 16-cacheline scatter.
//  - kbf/vbf L2-resident, read straight from global.
//  - P in 32-key chunks via wave-private [16][40] LDS strip (barrier-free).
//  - pool partials parked wave-private; only one entry barrier (tables).
// ---------------------------------------------------------------------------
__launch_bounds__(256)
__global__ void attn_f(const unsigned short* __restrict__ qloc,
                       const unsigned short* __restrict__ kloc,
                       const unsigned short* __restrict__ vloc,
                       const unsigned short* __restrict__ kbf,
                       const unsigned short* __restrict__ vbf,
                       const unsigned short* __restrict__ bias2,
                       const float* __restrict__ Mq, const float* __restrict__ scal,
                       const float* __restrict__ slsp, const float* __restrict__ temp,
                       const float* __restrict__ qe, const float* __restrict__ lt,
                       const float* __restrict__ lb, const float* __restrict__ rpb,
                       unsigned short* __restrict__ outp)
{
  __shared__ __align__(16) unsigned short sh[7488];   // 14976 B
  unsigned short* p_lds = sh;                    // 4 waves x [16][40] bf16
  float* park = (float*)(sh + 2560);             // 4 waves x [16][33] fp32
  float* tabf = park + 2112;                     // qe[32] lt[288] lb[9] rpb[9]
  float* qe_s  = tabf;
  float* lt_s  = tabf + 32;
  float* lb_s  = tabf + 320;
  float* rpb_s = tabf + 329;
  const int t = threadIdx.x;
  const int w = t >> 6, lane = t & 63;
  const int ln = lane & 15, quad = lane >> 4;
  const int tile = blockIdx.x, h = blockIdx.y, b = blockIdx.z;
  const int bh = b * NHn + h;

  if (t < 32) qe_s[t] = qe[h * HDn + t];
  for (int i = t; i < HDn * LLn; i += 256) lt_s[i] = lt[h * HDn * LLn + i];
  if (t < LLn) { lb_s[t] = lb[h * LLn + t]; rpb_s[t] = rpb[h * LLn + t]; }
  __syncthreads();

  const unsigned short* qpl = qloc + (size_t)bh * Nn * HDn;   // [N][32]
  const unsigned short* kpl = kloc + (size_t)bh * Nn * HDn;
  const unsigned short* vpl = vloc + (size_t)bh * Nn * HDn;

  // ---- pool part (MFMA), wave w owns q-rows nb..nb+15 ----
  const int nb = tile * 64 + w * 16;
  const short8v afrag = *(const short8v*)(qpl + (size_t)(nb + ln) * HDn + quad * 8);
  float M4[4];
  const float sc = scal[0];
  #pragma unroll
  for (int r = 0; r < 4; ++r) M4[r] = Mq[(size_t)bh * Nn + nb + quad * 4 + r] + sc;

  const unsigned short* kg = kbf + (size_t)bh * (MP * HDn);   // [224][32]
  const unsigned short* vg = vbf + (size_t)bh * (32 * MP);    // [32][224]
  unsigned short* pst = p_lds + w * 640;                       // [16][40]

  float4v accO[2];
  accO[0] = (float4v){0.f,0.f,0.f,0.f};
  accO[1] = (float4v){0.f,0.f,0.f,0.f};
  float lsum[4] = {0.f, 0.f, 0.f, 0.f};

  #pragma unroll
  for (int kc = 0; kc < 7; ++kc) {
    #pragma unroll
    for (int mtl = 0; mtl < 2; ++mtl) {
      const int mt = kc * 2 + mtl;
      short8v bfrag = *(const short8v*)(kg + (mt * 16 + ln) * HDn + quad * 8);
      float4v s = __builtin_amdgcn_mfma_f32_16x16x32_bf16(afrag, bfrag,
                                                          (float4v){0.f,0.f,0.f,0.f}, 0, 0, 0);
      #pragma unroll
      for (int r = 0; r < 4; ++r) {
        const int nr = nb + quad * 4 + r;
        const float bv = b2f(bias2[((size_t)h * Nn + nr) * MP + mt * 16 + ln]);
        const float p = __expf(s[r] + bv - M4[r]);
        const unsigned short pb = f2b(p);
        lsum[r] += b2f(pb);                       // bf16-rounded, matches ones-row MFMA
        pst[(quad * 4 + r) * 40 + mtl * 16 + ln] = pb;
      }
    }
    // P chunk (this wave's own strip; same-wave LDS ordering, no barrier)
    short8v pa = *(const short8v*)(pst + ln * 40 + quad * 8);
    #pragma unroll
    for (int nt = 0; nt < 2; ++nt) {
      short8v vb = *(const short8v*)(vg + (size_t)(nt * 16 + ln) * MP + kc * 32 + quad * 8);
      accO[nt] = __builtin_amdgcn_mfma_f32_16x16x32_bf16(pa, vb, accO[nt], 0, 0, 0);
    }
  }

  // row-sum of P (l_pool): reduce lsum across the 16 ln lanes of each quad
  #pragma unroll
  for (int r = 0; r < 4; ++r) {
    #pragma unroll
    for (int mk = 1; mk <= 8; mk <<= 1) lsum[r] += __shfl_xor(lsum[r], mk);
  }

  // park pool partials in this wave's private region: [16 rows][33] fp32
  float* mypark = park + w * 528;
  #pragma unroll
  for (int r = 0; r < 4; ++r) {
    const int row = quad * 4 + r;
    mypark[row * 33 + ln]      = accO[0][r];
    mypark[row * 33 + 16 + ln] = accO[1][r];
    if (ln == 0) mypark[row * 33 + 32] = lsum[r];
  }

  // ---- local part: thread t -> n = tile*64 + (t>>2), d-slice dg = t&3 ----
  const int nl = t >> 2, dg = t & 3;
  const int n = tile * 64 + nl;
  float qs8[8];
  u4_to8f(*(const uint4*)(qpl + (size_t)n * HDn + dg * 8), qs8);
  const float M = Mq[(size_t)bh * Nn + n] + sc;
  const float spt = log1pf(__expf(temp[h]));
  const float inv_qs = 1.f / (spt * slsp[n]);

  float acc8[8], ext8[8];
  #pragma unroll
  for (int j = 0; j < 8; ++j) { acc8[j] = 0.f; ext8[j] = 0.f; }
  float l_run = 0.f;
  const int pi = n / Wn, pj = n % Wn;
  #pragma unroll
  for (int lc = 0; lc < LLn; ++lc) {
    const int ii = pi + lc/3 - 1, jj = pj + (lc%3) - 1;
    if (ii < 0 || ii >= Hh || jj < 0 || jj >= Wn) continue;   // uniform in 4-group
    const int nb2 = ii * Wn + jj;
    float kk8[8], vv8[8];
    u4_to8f(*(const uint4*)(kpl + (size_t)nb2 * HDn + dg * 8), kk8);
    u4_to8f(*(const uint4*)(vpl + (size_t)nb2 * HDn + dg * 8), vv8);
    float pp = 0.f, ep = 0.f;
    #pragma unroll
    for (int j = 0; j < 8; ++j) {
      pp += qs8[j] * kk8[j];
      ep += (qs8[j] * inv_qs - qe_s[dg*8 + j]) * lt_s[(dg*8 + j) * LLn + lc];
    }
    pp += __shfl_xor(pp, 1); pp += __shfl_xor(pp, 2);
    ep += __shfl_xor(ep, 1); ep += __shfl_xor(ep, 2);
    const float e = ep + lb_s[lc];
    const float p = __expf(pp + rpb_s[lc] - M);
    l_run += p;
    #pragma unroll
    for (int j = 0; j < 8; ++j) { acc8[j] += p * vv8[j]; ext8[j] += e * vv8[j]; }
  }

  // combine with pool partials (this wave's region; no barrier needed)
  const float* pool_r = park + w * 528 + (nl - w * 16) * 33;
  const float l_pool = pool_r[32];
  const float invl = 1.f / (l_run + l_pool);
  uint4 u;
  {
    const float* op = pool_r + dg * 8;
    float o0 = (acc8[0]+op[0])*invl + ext8[0], o1 = (acc8[1]+op[1])*invl + ext8[1];
    float o2 = (acc8[2]+op[2])*invl + ext8[2], o3 = (acc8[3]+op[3])*invl + ext8[3];
    float o4 = (acc8[4]+op[4])*invl + ext8[4], o5 = (acc8[5]+op[5])*invl + ext8[5];
    float o6 = (acc8[6]+op[6])*invl + ext8[6], o7 = (acc8[7]+op[7])*invl + ext8[7];
    u.x = f2b(o0) | ((unsigned int)f2b(o1) << 16);
    u.y = f2b(o2) | ((unsigned int)f2b(o3) << 16);
    u.z = f2b(o4) | ((unsigned int)f2b(o5) << 16);
    u.w = f2b(o6) | ((unsigned int)f2b(o7) << 16);
  }
  *(uint4*)(outp + ((size_t)b * Nn + n) * Cn + h * HDn + dg * 8) = u;
}

// ---------------------------------------------------------------------------
extern "C" void kernel_launch(void* const* d_in, const int* in_sizes, int n_in,
                              void* d_out, int out_size, void* d_ws, size_t ws_size,
                              hipStream_t stream)
{
  const float* x    = (const float*)d_in[0];
  const int*   rpi  = (const int*)d_in[3];
  const float* rct  = (const float*)d_in[4];
  const float* sls  = (const float*)d_in[5];
  const float* q_w  = (const float*)d_in[7];
  const float* q_b  = (const float*)d_in[8];
  const float* kv_w = (const float*)d_in[9];
  const float* kv_b = (const float*)d_in[10];
  const float* sr_w = (const float*)d_in[11];
  const float* sr_b = (const float*)d_in[12];
  const float* ng   = (const float*)d_in[13];
  const float* nbta = (const float*)d_in[14];
  const float* c1w  = (const float*)d_in[15];
  const float* c1b  = (const float*)d_in[16];
  const float* c2w  = (const float*)d_in[17];
  const float* c2b  = (const float*)d_in[18];
  const float* temp = (const float*)d_in[19];
  const float* qe   = (const float*)d_in[20];
  const float* rpb  = (const float*)d_in[21];
  const float* lt   = (const float*)d_in[22];
  const float* lb   = (const float*)d_in[23];
  const float* pw   = (const float*)d_in[24];
  const float* pb   = (const float*)d_in[25];

  float* ws = (float*)d_ws;
  size_t o = 0;
  unsigned short* bf = (unsigned short*)(ws + o); o += TOTCVT / 2;
  unsigned short* fused = (unsigned short*)(ws + o); o += (size_t)Mrows * 512;  // bf16 [12544][1024]
  float* Mq    = ws + o;  o += (size_t)Bn * NHn * Nn;
  float* pln   = ws + o;  o += (size_t)Bn * PLn * Cn;
  float* kvp   = ws + o;  o += (size_t)Bn * PLn * 2 * Cn;
  unsigned short* kbf = (unsigned short*)(ws + o); o += (size_t)Bn * NHn * MP * HDn / 2;
  unsigned short* vbf = (unsigned short*)(ws + o); o += (size_t)Bn * NHn * 32 * MP / 2;
  float* tab   = ws + o;  o += (size_t)KTABn * NHn;
  float* scal  = ws + o;  o += 8;
  unsigned short* bias2 = (unsigned short*)(ws + o); o += (size_t)NHn * Nn * MP / 2;
  unsigned short* outp  = (unsigned short*)(ws + o); o += (size_t)Mrows * Cn / 2;
  unsigned short* qkv3  = (unsigned short*)(ws + o); o += 3 * (size_t)PLSZ / 2;
  unsigned short* qloc = qkv3;
  unsigned short* klocp = qkv3 + PLSZ;
  unsigned short* vlocp = qkv3 + 2 * (size_t)PLSZ;

  const unsigned short* xbf   = bf;
  const unsigned short* qkvsw = bf + QWOFF;
  const unsigned short* pwbf  = bf + PWOFF;

  cvt5<<<TOTCVT/1024, 256, 0, stream>>>(x, q_w, kv_w, sr_w, pw, bf);
  mgemm<1><<<dim3(8, 98), 512, 0, stream>>>(xbf, qkvsw, q_b, kv_b, sr_b, fused, 1024,
                                            sls, qe, temp, Mq, qkv3);
  pool_ln_k<<<Bn*PLn, 256, 0, stream>>>(fused, pln, ng, nbta);
  gemm_k<<<dim3(8, 13), 256, 0, stream>>>(pln, kv_w, kv_b, kvp, Bn*PLn, 512, 256);
  pool_pack<<<Bn*NHn, 256, 0, stream>>>(kvp, kbf, vbf);
  cpb_k<<<KTABn, 64, 0, stream>>>(rct, c1w, c1b, c2w, c2b, tab);
  redmax_k<<<1, 256, 0, stream>>>(tab, rpb, scal);
  bias_g2<<<(Nn*MP)/256, 256, 0, stream>>>(rpi, tab, bias2);
  attn_f<<<dim3(49, NHn, Bn), 256, 0, stream>>>(qloc, klocp, vlocp, kbf, vbf, bias2,
                                                Mq, scal, sls, temp, qe, lt, lb, rpb, outp);
  mgemm<0><<<dim3(2, 98), 512, 0, stream>>>(outp, pwbf, pb, pb, pb, (float*)d_out, 256,
                                            nullptr, nullptr, nullptr, nullptr, nullptr);
}

// Round 3
// 251.231 us; speedup vs baseline: 1.0686x; 1.0686x over previous
//
#include <hip/hip_runtime.h>
#include <hip/hip_bf16.h>
#include <math.h>

#define Bn   4
#define Hh   56
#define Wn   56
#define Cn   256
#define NHn  8
#define HDn  32
#define Nn   3136
#define LLn  9
#define PLn  196
#define PWn  14
#define KTABn 2048
#define Mrows 12544
#define MP   224            // padded pool-key count (14 x 16)

// cvt5 segment offsets (elements)
#define XCNT   3211264
#define QWOFF  XCNT
#define KVWOFF (QWOFF + 65536)
#define SRWOFF (KVWOFF + 131072)
#define PWOFF  (SRWOFF + 65536)
#define TOTCVT (PWOFF + 65536)

typedef __attribute__((ext_vector_type(8))) short short8v;
typedef __attribute__((ext_vector_type(4))) float float4v;

__device__ __forceinline__ unsigned short f2b(float f) {
  __hip_bfloat16 h = __float2bfloat16(f);
  return *(unsigned short*)&h;
}
__device__ __forceinline__ float b2f(unsigned short u) {
  union { unsigned int i; float f; } x; x.i = ((unsigned int)u) << 16; return x.f;
}
__device__ __forceinline__ void u4_to8f(uint4 u, float* o) {
  o[0]=b2f((unsigned short)(u.x&0xffff)); o[1]=b2f((unsigned short)(u.x>>16));
  o[2]=b2f((unsigned short)(u.y&0xffff)); o[3]=b2f((unsigned short)(u.y>>16));
  o[4]=b2f((unsigned short)(u.z&0xffff)); o[5]=b2f((unsigned short)(u.z>>16));
  o[6]=b2f((unsigned short)(u.w&0xffff)); o[7]=b2f((unsigned short)(u.w>>16));
}

// ---------------------------------------------------------------------------
// Convert x + q_w + kv_w + sr_w + proj_w to one contiguous bf16 area.
// ---------------------------------------------------------------------------
__launch_bounds__(256)
__global__ void cvt5(const float* __restrict__ x, const float* __restrict__ qw,
                     const float* __restrict__ kvw, const float* __restrict__ srw,
                     const float* __restrict__ pw, unsigned short* __restrict__ dst)
{
  const int i = (blockIdx.x * 256 + threadIdx.x) * 4;
  const float* src; int off;
  if      (i < XCNT)   { src = x;   off = 0; }
  else if (i < KVWOFF) { src = qw;  off = QWOFF; }
  else if (i < SRWOFF) { src = kvw; off = KVWOFF; }
  else if (i < PWOFF)  { src = srw; off = SRWOFF; }
  else                 { src = pw;  off = PWOFF; }
  const float4 v = *(const float4*)(src + (i - off));
  ushort4 o2;
  o2.x = f2b(v.x); o2.y = f2b(v.y); o2.z = f2b(v.z); o2.w = f2b(v.w);
  *(ushort4*)(dst + i) = o2;
}

// ---------------------------------------------------------------------------
// bf16 MFMA GEMM, 512 threads = 8 waves.
// MODE 0 (proj): fp32 out via LDS-staged stores (two row-halves).
// MODE 1 (QKVS): bf16 out, fused per-head norm epilogue, LDS-staged stores.
// ---------------------------------------------------------------------------
template <int MODE>
__launch_bounds__(512)
__global__ void mgemm(const unsigned short* __restrict__ A,
                      const unsigned short* __restrict__ Wb,
                      const float* __restrict__ b0, const float* __restrict__ b1,
                      const float* __restrict__ b2, void* __restrict__ Cv, int Nc,
                      const float* __restrict__ sls, const float* __restrict__ qe,
                      const float* __restrict__ temp, float* __restrict__ Mq)
{
  __shared__ __align__(16) unsigned char smem[34816];
  unsigned short* As = (unsigned short*)smem;            // [128][64]
  unsigned short* Bs = (unsigned short*)(smem + 16384);  // [128][64]
  const int t = threadIdx.x;
  const int w = t >> 6, lane = t & 63;
  const int q = lane >> 4, ln = lane & 15;
  const int n0 = blockIdx.x * 128, m0 = blockIdx.y * 128;
  const int wm = (w >> 1) * 32, wn = (w & 1) * 64;

  float4v acc[2][4];
  #pragma unroll
  for (int mt = 0; mt < 2; ++mt)
    #pragma unroll
    for (int nt = 0; nt < 4; ++nt)
      acc[mt][nt] = (float4v){0.f, 0.f, 0.f, 0.f};

  for (int k0 = 0; k0 < 256; k0 += 64) {
    #pragma unroll
    for (int j = 0; j < 2; ++j) {
      const int u = t + 512 * j;
      const int r = u >> 3, cg = u & 7;
      const int cs = cg ^ (r & 7);
      const uint4 av = *(const uint4*)(A  + (size_t)(m0 + r) * 256 + k0 + cg * 8);
      *(uint4*)(As + r * 64 + cs * 8) = av;
      const uint4 bv = *(const uint4*)(Wb + (size_t)(n0 + r) * 256 + k0 + cg * 8);
      *(uint4*)(Bs + r * 64 + cs * 8) = bv;
    }
    __syncthreads();
    #pragma unroll
    for (int kk = 0; kk < 2; ++kk) {
      short8v af[2], bfr[4];
      const int cg = kk * 4 + q;
      #pragma unroll
      for (int mt = 0; mt < 2; ++mt) {
        const int r = wm + mt * 16 + ln;
        af[mt] = *(const short8v*)(As + r * 64 + (cg ^ (r & 7)) * 8);
      }
      #pragma unroll
      for (int nt = 0; nt < 4; ++nt) {
        const int r = wn + nt * 16 + ln;
        bfr[nt] = *(const short8v*)(Bs + r * 64 + (cg ^ (r & 7)) * 8);
      }
      #pragma unroll
      for (int mt = 0; mt < 2; ++mt)
        #pragma unroll
        for (int nt = 0; nt < 4; ++nt)
          acc[mt][nt] = __builtin_amdgcn_mfma_f32_16x16x32_bf16(af[mt], bfr[nt], acc[mt][nt], 0, 0, 0);
    }
    __syncthreads();
  }

  if constexpr (MODE == 0) {
    float* C = (float*)Cv;
    float* tileF = (float*)smem;
    float bia[4];
    #pragma unroll
    for (int nt = 0; nt < 4; ++nt) bia[nt] = b0[n0 + wn + nt * 16 + ln];
    #pragma unroll
    for (int half = 0; half < 2; ++half) {
      if ((w >> 2) == half) {
        #pragma unroll
        for (int mt = 0; mt < 2; ++mt)
          #pragma unroll
          for (int r = 0; r < 4; ++r)
            #pragma unroll
            for (int nt = 0; nt < 4; ++nt)
              tileF[(wm - half*64 + mt*16 + q*4 + r) * 132 + wn + nt*16 + ln] = acc[mt][nt][r] + bia[nt];
      }
      __syncthreads();
      #pragma unroll
      for (int j = 0; j < 4; ++j) {
        const int i = j * 512 + t;
        const int row = i >> 5, ch = i & 31;
        float4 v = *(const float4*)(tileF + row * 132 + ch * 4);
        *(float4*)(C + (size_t)(m0 + half * 64 + row) * Nc + n0 + ch * 4) = v;
      }
      __syncthreads();
    }
  } else {
    unsigned short* Cb = (unsigned short*)Cv;
    unsigned short* tileC = (unsigned short*)smem;     // [128][136] bf16
    const int seg = n0 >> 8;
    const int h0 = (n0 + wn) >> 5, h1 = h0 + 1;
    float spt0 = 0.f, spt1 = 0.f;
    if (seg == 0) { spt0 = log1pf(__expf(temp[h0])); spt1 = log1pf(__expf(temp[h1])); }
    float bia[4], qev[4];
    #pragma unroll
    for (int nt = 0; nt < 4; ++nt) {
      const int col = n0 + wn + nt * 16 + ln;
      bia[nt] = (seg == 0) ? b0[col] : (seg == 3 ? b2[col - 768] : b1[col - 256]);
      if (seg == 0) qev[nt] = qe[col];
    }
    #pragma unroll
    for (int mt = 0; mt < 2; ++mt) {
      #pragma unroll
      for (int r = 0; r < 4; ++r) {
        const int row = m0 + wm + mt * 16 + q * 4 + r;
        const int lrow = wm + mt * 16 + q * 4 + r;
        float vals[4];
        #pragma unroll
        for (int nt = 0; nt < 4; ++nt) vals[nt] = acc[mt][nt][r] + bia[nt];
        if (seg == 0) {
          float ss0 = vals[0]*vals[0] + vals[1]*vals[1];
          float ss1 = vals[2]*vals[2] + vals[3]*vals[3];
          #pragma unroll
          for (int mk = 1; mk <= 8; mk <<= 1) { ss0 += __shfl_xor(ss0, mk); ss1 += __shfl_xor(ss1, mk); }
          const float i0 = 1.f / fmaxf(sqrtf(ss0), 1e-12f);
          const float i1 = 1.f / fmaxf(sqrtf(ss1), 1e-12f);
          const int nidx = row % Nn, bb = row / Nn;
          const float sl = sls[nidx];
          float qsv[4];
          #pragma unroll
          for (int nt = 0; nt < 4; ++nt) {
            const float inv = (nt < 2) ? i0 : i1;
            const float sp  = (nt < 2) ? spt0 : spt1;
            qsv[nt] = (vals[nt] * inv + qev[nt]) * sp * sl;
          }
          float t0 = qsv[0]*qsv[0] + qsv[1]*qsv[1];
          float t1 = qsv[2]*qsv[2] + qsv[3]*qsv[3];
          #pragma unroll
          for (int mk = 1; mk <= 8; mk <<= 1) { t0 += __shfl_xor(t0, mk); t1 += __shfl_xor(t1, mk); }
          if (ln == 0) {
            Mq[((size_t)(bb * NHn + h0)) * Nn + nidx] = sqrtf(t0);
            Mq[((size_t)(bb * NHn + h1)) * Nn + nidx] = sqrtf(t1);
          }
          #pragma unroll
          for (int nt = 0; nt < 4; ++nt)
            tileC[lrow * 136 + wn + nt*16 + ln] = f2b(qsv[nt]);
        } else if (seg == 1) {
          float ss0 = vals[0]*vals[0] + vals[1]*vals[1];
          float ss1 = vals[2]*vals[2] + vals[3]*vals[3];
          #pragma unroll
          for (int mk = 1; mk <= 8; mk <<= 1) { ss0 += __shfl_xor(ss0, mk); ss1 += __shfl_xor(ss1, mk); }
          const float i0 = 1.f / fmaxf(sqrtf(ss0), 1e-12f);
          const float i1 = 1.f / fmaxf(sqrtf(ss1), 1e-12f);
          #pragma unroll
          for (int nt = 0; nt < 4; ++nt)
            tileC[lrow * 136 + wn + nt*16 + ln] = f2b(vals[nt] * ((nt < 2) ? i0 : i1));
        } else if (seg == 2) {
          #pragma unroll
          for (int nt = 0; nt < 4; ++nt)
            tileC[lrow * 136 + wn + nt*16 + ln] = f2b(vals[nt]);
        } else {
          #pragma unroll
          for (int nt = 0; nt < 4; ++nt) {
            const float v = vals[nt];
            tileC[lrow * 136 + wn + nt*16 + ln] =
              f2b(0.5f * v * (1.0f + erff(v * 0.70710678118654752f)));
          }
        }
      }
    }
    __syncthreads();
    #pragma unroll
    for (int j = 0; j < 4; ++j) {
      const int i = j * 512 + t;
      const int row = i >> 4, ch = i & 15;
      uint4 v = *(const uint4*)(tileC + row * 136 + ch * 8);
      *(uint4*)(Cb + (size_t)(m0 + row) * 1024 + n0 + ch * 8) = v;
    }
  }
}

// ---------------------------------------------------------------------------
// fp32 tiled GEMM (pool path only)
// ---------------------------------------------------------------------------
__launch_bounds__(256)
__global__ void gemm_k(const float* __restrict__ A, const float* __restrict__ W,
                       const float* __restrict__ bias, float* __restrict__ Co,
                       int Mr, int Nc, int K)
{
  __shared__ __align__(16) float As[16][64];
  __shared__ __align__(16) float Ws[16][64];
  const int t  = threadIdx.x;
  const int m0 = blockIdx.y * 64, n0 = blockIdx.x * 64;
  const int lm = t >> 2, lk = (t & 3) << 2;
  const int tx = t & 15, ty = t >> 4;
  float acc[4][4] = {};
  int arow = m0 + lm; if (arow >= Mr) arow = Mr - 1;
  const int wrow = n0 + lm;
  for (int k0 = 0; k0 < K; k0 += 16) {
    float4 av = *(const float4*)(A + (size_t)arow * K + k0 + lk);
    As[lk+0][lm] = av.x; As[lk+1][lm] = av.y; As[lk+2][lm] = av.z; As[lk+3][lm] = av.w;
    float4 wv = *(const float4*)(W + (size_t)wrow * K + k0 + lk);
    Ws[lk+0][lm] = wv.x; Ws[lk+1][lm] = wv.y; Ws[lk+2][lm] = wv.z; Ws[lk+3][lm] = wv.w;
    __syncthreads();
    #pragma unroll
    for (int k = 0; k < 16; ++k) {
      float4 a = *(const float4*)&As[k][ty << 2];
      float4 w = *(const float4*)&Ws[k][tx << 2];
      acc[0][0] += a.x*w.x; acc[0][1] += a.x*w.y; acc[0][2] += a.x*w.z; acc[0][3] += a.x*w.w;
      acc[1][0] += a.y*w.x; acc[1][1] += a.y*w.y; acc[1][2] += a.y*w.z; acc[1][3] += a.y*w.w;
      acc[2][0] += a.z*w.x; acc[2][1] += a.z*w.y; acc[2][2] += a.z*w.z; acc[2][3] += a.z*w.w;
      acc[3][0] += a.w*w.x; acc[3][1] += a.w*w.y; acc[3][2] += a.w*w.z; acc[3][3] += a.w*w.w;
    }
    __syncthreads();
  }
  #pragma unroll
  for (int i = 0; i < 4; ++i) {
    const int row = m0 + (ty << 2) + i;
    if (row >= Mr) continue;
    #pragma unroll
    for (int j = 0; j < 4; ++j) {
      const int col = n0 + (tx << 2) + j;
      Co[(size_t)row * Nc + col] = acc[i][j] + bias[col];
    }
  }
}

// ---------------------------------------------------------------------------
// 4x4 average pool of gelu'd sr (fused bf16 cols 768..1023) + LayerNorm over C
// ---------------------------------------------------------------------------
__launch_bounds__(256)
__global__ void pool_ln_k(const unsigned short* __restrict__ fused, float* __restrict__ pln,
                          const float* __restrict__ g, const float* __restrict__ bb)
{
  const int blk = blockIdx.x;
  const int b = blk / PLn, pc = blk % PLn;
  const int pi = pc / PWn, pj = pc % PWn;
  const int c = threadIdx.x;
  float s = 0.f;
  #pragma unroll
  for (int r = 0; r < 4; ++r)
    #pragma unroll
    for (int cc = 0; cc < 4; ++cc) {
      const int n = (pi*4 + r) * Wn + pj*4 + cc;
      s += b2f(fused[((size_t)b * Nn + n) * 1024 + 768 + c]);
    }
  s *= (1.f/16.f);
  float sum = s, sq = s*s;
  #pragma unroll
  for (int m = 32; m >= 1; m >>= 1) { sum += __shfl_xor(sum, m); sq += __shfl_xor(sq, m); }
  __shared__ float sm[8];
  const int lane = c & 63, wid = c >> 6;
  if (lane == 0) { sm[wid] = sum; sm[4+wid] = sq; }
  __syncthreads();
  const float tot  = sm[0]+sm[1]+sm[2]+sm[3];
  const float totq = sm[4]+sm[5]+sm[6]+sm[7];
  const float mu  = tot * (1.f/256.f);
  const float var = totq * (1.f/256.f) - mu*mu;
  pln[(size_t)blk * Cn + c] = (s - mu) / sqrtf(var + 1e-5f) * g[c] + bb[c];
}

// ---------------------------------------------------------------------------
// pool_pack: kvp -> kbf [bh][224 m][32 d] bf16 (L2-normed k, zero pad m>=196)
//            and vbf [bh][32 d][224 m] bf16 (v transposed)
// ---------------------------------------------------------------------------
__launch_bounds__(256)
__global__ void pool_pack(const float* __restrict__ kvp, unsigned short* __restrict__ kbf,
                          unsigned short* __restrict__ vbf)
{
  const int bh = blockIdx.x;
  const int b = bh >> 3, h = bh & 7;
  const int t = threadIdx.x, mg = t >> 5, d = t & 31;
  for (int mi = 0; mi < MP/8; ++mi) {
    const int m = mi * 8 + mg;
    float kv2 = 0.f, vv = 0.f;
    if (m < PLn) {
      kv2 = kvp[((size_t)(b * PLn + m)) * 512 + h * HDn + d];
      vv  = kvp[((size_t)(b * PLn + m)) * 512 + 256 + h * HDn + d];
    }
    float ssn = kv2 * kv2;
    #pragma unroll
    for (int mm = 16; mm >= 1; mm >>= 1) ssn += __shfl_xor(ssn, mm);
    const float kn = (m < PLn) ? kv2 / fmaxf(sqrtf(ssn), 1e-12f) : 0.f;
    kbf[((size_t)bh * MP + m) * HDn + d] = f2b(kn);
    vbf[((size_t)bh * 32 + d) * MP + m] = f2b(vv);
  }
}

// ---------------------------------------------------------------------------
// CPB MLP
// ---------------------------------------------------------------------------
__launch_bounds__(64)
__global__ void cpb_k(const float* __restrict__ rct, const float* __restrict__ w1,
                      const float* __restrict__ b1, const float* __restrict__ w2,
                      const float* __restrict__ b2, float* __restrict__ tab)
{
  const int r = blockIdx.x, t = threadIdx.x;
  const float c0 = rct[r*2], c1 = rct[r*2+1];
  float part[8] = {};
  #pragma unroll
  for (int jj = 0; jj < 8; ++jj) {
    const int j = t * 8 + jj;
    float hv = fmaxf(c0 * w1[j*2] + c1 * w1[j*2+1] + b1[j], 0.f);
    #pragma unroll
    for (int h = 0; h < 8; ++h) part[h] += hv * w2[h*512 + j];
  }
  #pragma unroll
  for (int h = 0; h < 8; ++h)
    for (int mm = 32; mm >= 1; mm >>= 1) part[h] += __shfl_xor(part[h], mm);
  if (t < 8) tab[r*8 + t] = part[t] + b2[t];
}

// ---------------------------------------------------------------------------
// global max over tab and rpb -> scal[0]
// ---------------------------------------------------------------------------
__launch_bounds__(256)
__global__ void redmax_k(const float* __restrict__ tab, const float* __restrict__ rpb,
                         float* __restrict__ scal)
{
  float mx = -1e30f;
  for (int i = threadIdx.x; i < KTABn*NHn; i += 256) mx = fmaxf(mx, tab[i]);
  if (threadIdx.x < NHn*LLn) mx = fmaxf(mx, rpb[threadIdx.x]);
  #pragma unroll
  for (int m = 32; m >= 1; m >>= 1) mx = fmaxf(mx, __shfl_xor(mx, m));
  __shared__ float sm[4];
  if ((threadIdx.x & 63) == 0) sm[threadIdx.x >> 6] = mx;
  __syncthreads();
  if (threadIdx.x == 0) scal[0] = fmaxf(fmaxf(sm[0], sm[1]), fmaxf(sm[2], sm[3]));
}

// ---------------------------------------------------------------------------
// bias_g2 (tiled): bias2[h][nt(196)][mt(14)][16 n][16 m] bf16, m>=196 -> -inf.
// Each block fills one (nt, mt) tile for all 8 heads; stores 512 B contiguous.
// ---------------------------------------------------------------------------
__launch_bounds__(256)
__global__ void bias_g2(const int* __restrict__ rpi, const float* __restrict__ tab,
                        unsigned short* __restrict__ bias2)
{
  const int mt = blockIdx.x, nt = blockIdx.y;
  const int t = threadIdx.x;
  const int nn = t >> 4, mm = t & 15;
  const int n = nt * 16 + nn, m = mt * 16 + mm;
  unsigned short vh[NHn];
  if (m < PLn) {
    const int idx = rpi[(size_t)n * PLn + m];
    #pragma unroll
    for (int h = 0; h < NHn; ++h) vh[h] = f2b(tab[(size_t)idx * NHn + h]);
  } else {
    #pragma unroll
    for (int h = 0; h < NHn; ++h) vh[h] = 0xFF80;   // bf16 -inf
  }
  #pragma unroll
  for (int h = 0; h < NHn; ++h)
    bias2[(((size_t)h * 196 + nt) * 14 + mt) * 256 + t] = vh[h];
}

// ---------------------------------------------------------------------------
// attn_f: FUSED attention (fused-layout base, round-1 structure) +
//  (a) local k/v window [tile*64-57, tile*64+120] staged ONCE into LDS
//      (stride-40 rows, near-uniform banks for b128); the 9-neighbor loop
//      reads LDS instead of 16-line global scatters.
//  (b) bias2 read from 16x16 tiles: 4 fully-used lines per mt, streamed.
//  P strips / park / tables as in round 1 (wave-private, barrier-free after
//  the single entry barrier).
// ---------------------------------------------------------------------------
__launch_bounds__(256)
__global__ void attn_f(const unsigned short* __restrict__ fused,
                       const unsigned short* __restrict__ kbf,
                       const unsigned short* __restrict__ vbf,
                       const unsigned short* __restrict__ bias2,
                       const float* __restrict__ Mq, const float* __restrict__ scal,
                       const float* __restrict__ slsp, const float* __restrict__ temp,
                       const float* __restrict__ qe, const float* __restrict__ lt,
                       const float* __restrict__ lb, const float* __restrict__ rpb,
                       unsigned short* __restrict__ outp)
{
  __shared__ __align__(16) unsigned short sh[21888];   // 43776 B
  unsigned short* k_s   = sh;              // [180][40] bf16 local-k window
  unsigned short* v_s   = sh + 7200;       // [180][40] bf16 local-v window
  unsigned short* p_lds = sh + 14400;      // 4 waves x [16][40] bf16
  float* park = (float*)(sh + 16960);      // 4 waves x [16][33] fp32
  float* tabf = (float*)(sh + 21184);      // qe[32] lt[288] lb[9] rpb[9]
  float* qe_s  = tabf;
  float* lt_s  = tabf + 32;
  float* lb_s  = tabf + 320;
  float* rpb_s = tabf + 329;
  const int t = threadIdx.x;
  const int w = t >> 6, lane = t & 63;
  const int ln = lane & 15, quad = lane >> 4;
  const int tile = blockIdx.x, h = blockIdx.y, b = blockIdx.z;
  const int bh = b * NHn + h;

  if (t < 32) qe_s[t] = qe[h * HDn + t];
  for (int i = t; i < HDn * LLn; i += 256) lt_s[i] = lt[h * HDn * LLn + i];
  if (t < LLn) { lb_s[t] = lb[h * LLn + t]; rpb_s[t] = rpb[h * LLn + t]; }
  // stage the 178-row local k/v window (rows clamped; out-of-range slots unused)
  const int base_n = tile * 64 - 57;
  for (int i = t; i < 720; i += 256) {
    const int row = i >> 2, c4 = i & 3;
    int rg = base_n + row; rg = rg < 0 ? 0 : (rg > Nn - 1 ? Nn - 1 : rg);
    const unsigned short* src = fused + ((size_t)(b * Nn + rg)) * 1024 + 256 + h * HDn + c4 * 8;
    *(uint4*)(k_s + row * 40 + c4 * 8) = *(const uint4*)src;
    *(uint4*)(v_s + row * 40 + c4 * 8) = *(const uint4*)(src + 256);
  }
  __syncthreads();

  // ---- pool part (MFMA), wave w owns q-rows nb..nb+15 ----
  const int nb = tile * 64 + w * 16;
  const short8v afrag = *(const short8v*)(fused +
      ((size_t)(b * Nn + nb + ln)) * 1024 + h * HDn + quad * 8);
  float M4[4];
  const float sc = scal[0];
  #pragma unroll
  for (int r = 0; r < 4; ++r) M4[r] = Mq[(size_t)bh * Nn + nb + quad * 4 + r] + sc;

  const unsigned short* kg = kbf + (size_t)bh * (MP * HDn);   // [224][32]
  const unsigned short* vg = vbf + (size_t)bh * (32 * MP);    // [32][224]
  const unsigned short* b2t = bias2 + (((size_t)h * 196 + (tile * 4 + w)) * 14) * 256;
  unsigned short* pst = p_lds + w * 640;                       // [16][40]

  float4v accO[2];
  accO[0] = (float4v){0.f,0.f,0.f,0.f};
  accO[1] = (float4v){0.f,0.f,0.f,0.f};
  float lsum[4] = {0.f, 0.f, 0.f, 0.f};

  #pragma unroll
  for (int kc = 0; kc < 7; ++kc) {
    #pragma unroll
    for (int mtl = 0; mtl < 2; ++mtl) {
      const int mt = kc * 2 + mtl;
      short8v bfrag = *(const short8v*)(kg + (mt * 16 + ln) * HDn + quad * 8);
      float4v s = __builtin_amdgcn_mfma_f32_16x16x32_bf16(afrag, bfrag,
                                                          (float4v){0.f,0.f,0.f,0.f}, 0, 0, 0);
      #pragma unroll
      for (int r = 0; r < 4; ++r) {
        const float bv = b2f(b2t[mt * 256 + (quad * 4 + r) * 16 + ln]);
        const float p = __expf(s[r] + bv - M4[r]);
        const unsigned short pb = f2b(p);
        lsum[r] += b2f(pb);                       // bf16-rounded, matches ones-row MFMA
        pst[(quad * 4 + r) * 40 + mtl * 16 + ln] = pb;
      }
    }
    // P chunk (this wave's own strip; same-wave LDS ordering, no barrier)
    short8v pa = *(const short8v*)(pst + ln * 40 + quad * 8);
    #pragma unroll
    for (int nt = 0; nt < 2; ++nt) {
      short8v vb = *(const short8v*)(vg + (size_t)(nt * 16 + ln) * MP + kc * 32 + quad * 8);
      accO[nt] = __builtin_amdgcn_mfma_f32_16x16x32_bf16(pa, vb, accO[nt], 0, 0, 0);
    }
  }

  // row-sum of P (l_pool): reduce lsum across the 16 ln lanes of each quad
  #pragma unroll
  for (int r = 0; r < 4; ++r) {
    #pragma unroll
    for (int mk = 1; mk <= 8; mk <<= 1) lsum[r] += __shfl_xor(lsum[r], mk);
  }

  // park pool partials in this wave's private region: [16 rows][33] fp32
  float* mypark = park + w * 528;
  #pragma unroll
  for (int r = 0; r < 4; ++r) {
    const int row = quad * 4 + r;
    mypark[row * 33 + ln]      = accO[0][r];
    mypark[row * 33 + 16 + ln] = accO[1][r];
    if (ln == 0) mypark[row * 33 + 32] = lsum[r];
  }

  // ---- local part: thread t -> n = tile*64 + (t>>2), d-slice dg = t&3 ----
  const int nl = t >> 2, dg = t & 3;
  const int n = tile * 64 + nl;
  float qs8[8];
  u4_to8f(*(const uint4*)(fused + ((size_t)(b * Nn + n)) * 1024 + h * HDn + dg * 8), qs8);
  const float M = Mq[(size_t)bh * Nn + n] + sc;
  const float spt = log1pf(__expf(temp[h]));
  const float inv_qs = 1.f / (spt * slsp[n]);

  float acc8[8], ext8[8];
  #pragma unroll
  for (int j = 0; j < 8; ++j) { acc8[j] = 0.f; ext8[j] = 0.f; }
  float l_run = 0.f;
  const int pi = n / Wn, pj = n % Wn;
  const int sb = nl + 57;
  #pragma unroll
  for (int lc = 0; lc < LLn; ++lc) {
    const int ii = pi + lc/3 - 1, jj = pj + (lc%3) - 1;
    if (ii < 0 || ii >= Hh || jj < 0 || jj >= Wn) continue;   // uniform in 4-group
    const int slot = sb + (lc/3 - 1) * 56 + (lc%3) - 1;
    float kk8[8], vv8[8];
    u4_to8f(*(const uint4*)(k_s + slot * 40 + dg * 8), kk8);
    u4_to8f(*(const uint4*)(v_s + slot * 40 + dg * 8), vv8);
    float pp = 0.f, ep = 0.f;
    #pragma unroll
    for (int j = 0; j < 8; ++j) {
      pp += qs8[j] * kk8[j];
      ep += (qs8[j] * inv_qs - qe_s[dg*8 + j]) * lt_s[(dg*8 + j) * LLn + lc];
    }
    pp += __shfl_xor(pp, 1); pp += __shfl_xor(pp, 2);
    ep += __shfl_xor(ep, 1); ep += __shfl_xor(ep, 2);
    const float e = ep + lb_s[lc];
    const float p = __expf(pp + rpb_s[lc] - M);
    l_run += p;
    #pragma unroll
    for (int j = 0; j < 8; ++j) { acc8[j] += p * vv8[j]; ext8[j] += e * vv8[j]; }
  }

  // combine with pool partials (this wave's region; no barrier needed)
  const float* pool_r = park + w * 528 + (nl - w * 16) * 33;
  const float l_pool = pool_r[32];
  const float invl = 1.f / (l_run + l_pool);
  uint4 u;
  {
    const float* op = pool_r + dg * 8;
    float o0 = (acc8[0]+op[0])*invl + ext8[0], o1 = (acc8[1]+op[1])*invl + ext8[1];
    float o2 = (acc8[2]+op[2])*invl + ext8[2], o3 = (acc8[3]+op[3])*invl + ext8[3];
    float o4 = (acc8[4]+op[4])*invl + ext8[4], o5 = (acc8[5]+op[5])*invl + ext8[5];
    float o6 = (acc8[6]+op[6])*invl + ext8[6], o7 = (acc8[7]+op[7])*invl + ext8[7];
    u.x = f2b(o0) | ((unsigned int)f2b(o1) << 16);
    u.y = f2b(o2) | ((unsigned int)f2b(o3) << 16);
    u.z = f2b(o4) | ((unsigned int)f2b(o5) << 16);
    u.w = f2b(o6) | ((unsigned int)f2b(o7) << 16);
  }
  *(uint4*)(outp + ((size_t)b * Nn + n) * Cn + h * HDn + dg * 8) = u;
}

// ---------------------------------------------------------------------------
extern "C" void kernel_launch(void* const* d_in, const int* in_sizes, int n_in,
                              void* d_out, int out_size, void* d_ws, size_t ws_size,
                              hipStream_t stream)
{
  const float* x    = (const float*)d_in[0];
  const int*   rpi  = (const int*)d_in[3];
  const float* rct  = (const float*)d_in[4];
  const float* sls  = (const float*)d_in[5];
  const float* q_w  = (const float*)d_in[7];
  const float* q_b  = (const float*)d_in[8];
  const float* kv_w = (const float*)d_in[9];
  const float* kv_b = (const float*)d_in[10];
  const float* sr_w = (const float*)d_in[11];
  const float* sr_b = (const float*)d_in[12];
  const float* ng   = (const float*)d_in[13];
  const float* nbta = (const float*)d_in[14];
  const float* c1w  = (const float*)d_in[15];
  const float* c1b  = (const float*)d_in[16];
  const float* c2w  = (const float*)d_in[17];
  const float* c2b  = (const float*)d_in[18];
  const float* temp = (const float*)d_in[19];
  const float* qe   = (const float*)d_in[20];
  const float* rpb  = (const float*)d_in[21];
  const float* lt   = (const float*)d_in[22];
  const float* lb   = (const float*)d_in[23];
  const float* pw   = (const float*)d_in[24];
  const float* pb   = (const float*)d_in[25];

  float* ws = (float*)d_ws;
  size_t o = 0;
  unsigned short* bf = (unsigned short*)(ws + o); o += TOTCVT / 2;
  unsigned short* fused = (unsigned short*)(ws + o); o += (size_t)Mrows * 512;  // bf16 [12544][1024]
  float* Mq    = ws + o;  o += (size_t)Bn * NHn * Nn;
  float* pln   = ws + o;  o += (size_t)Bn * PLn * Cn;
  float* kvp   = ws + o;  o += (size_t)Bn * PLn * 2 * Cn;
  unsigned short* kbf = (unsigned short*)(ws + o); o += (size_t)Bn * NHn * MP * HDn / 2;
  unsigned short* vbf = (unsigned short*)(ws + o); o += (size_t)Bn * NHn * 32 * MP / 2;
  float* tab   = ws + o;  o += (size_t)KTABn * NHn;
  float* scal  = ws + o;  o += 8;
  unsigned short* bias2 = (unsigned short*)(ws + o); o += (size_t)NHn * Nn * MP / 2;
  unsigned short* outp  = (unsigned short*)(ws + o); o += (size_t)Mrows * Cn / 2;

  const unsigned short* xbf   = bf;
  const unsigned short* qkvsw = bf + QWOFF;
  const unsigned short* pwbf  = bf + PWOFF;

  cvt5<<<TOTCVT/1024, 256, 0, stream>>>(x, q_w, kv_w, sr_w, pw, bf);
  mgemm<1><<<dim3(8, 98), 512, 0, stream>>>(xbf, qkvsw, q_b, kv_b, sr_b, fused, 1024,
                                            sls, qe, temp, Mq);
  pool_ln_k<<<Bn*PLn, 256, 0, stream>>>(fused, pln, ng, nbta);
  gemm_k<<<dim3(8, 13), 256, 0, stream>>>(pln, kv_w, kv_b, kvp, Bn*PLn, 512, 256);
  pool_pack<<<Bn*NHn, 256, 0, stream>>>(kvp, kbf, vbf);
  cpb_k<<<KTABn, 64, 0, stream>>>(rct, c1w, c1b, c2w, c2b, tab);
  redmax_k<<<1, 256, 0, stream>>>(tab, rpb, scal);
  bias_g2<<<dim3(14, 196), 256, 0, stream>>>(rpi, tab, bias2);
  attn_f<<<dim3(49, NHn, Bn), 256, 0, stream>>>(fused, kbf, vbf, bias2, Mq, scal,
                                                sls, temp, qe, lt, lb, rpb, outp);
  mgemm<0><<<dim3(2, 98), 512, 0, stream>>>(outp, pwbf, pb, pb, pb, (float*)d_out, 256,
                                            nullptr, nullptr, nullptr, nullptr);
}

// Round 4
// 238.972 us; speedup vs baseline: 1.1235x; 1.0513x over previous
//
#include <hip/hip_runtime.h>
#include <hip/hip_bf16.h>
#include <math.h>

#define Bn   4
#define Hh   56
#define Wn   56
#define Cn   256
#define NHn  8
#define HDn  32
#define Nn   3136
#define LLn  9
#define PLn  196
#define PWn  14
#define KTABn 2048
#define Mrows 12544
#define MP   224            // padded pool-key count (14 x 16)

// cvt5 segment offsets (elements)
#define XCNT   3211264
#define QWOFF  XCNT
#define KVWOFF (QWOFF + 65536)
#define SRWOFF (KVWOFF + 131072)
#define PWOFF  (SRWOFF + 65536)
#define TOTCVT (PWOFF + 65536)

typedef __attribute__((ext_vector_type(8))) short short8v;
typedef __attribute__((ext_vector_type(4))) float float4v;

__device__ __forceinline__ unsigned short f2b(float f) {
  __hip_bfloat16 h = __float2bfloat16(f);
  return *(unsigned short*)&h;
}
__device__ __forceinline__ float b2f(unsigned short u) {
  union { unsigned int i; float f; } x; x.i = ((unsigned int)u) << 16; return x.f;
}
__device__ __forceinline__ void u4_to8f(uint4 u, float* o) {
  o[0]=b2f((unsigned short)(u.x&0xffff)); o[1]=b2f((unsigned short)(u.x>>16));
  o[2]=b2f((unsigned short)(u.y&0xffff)); o[3]=b2f((unsigned short)(u.y>>16));
  o[4]=b2f((unsigned short)(u.z&0xffff)); o[5]=b2f((unsigned short)(u.z>>16));
  o[6]=b2f((unsigned short)(u.w&0xffff)); o[7]=b2f((unsigned short)(u.w>>16));
}

// ---------------------------------------------------------------------------
// Convert x + q_w + kv_w + sr_w + proj_w to one contiguous bf16 area.
// ---------------------------------------------------------------------------
__launch_bounds__(256)
__global__ void cvt5(const float* __restrict__ x, const float* __restrict__ qw,
                     const float* __restrict__ kvw, const float* __restrict__ srw,
                     const float* __restrict__ pw, unsigned short* __restrict__ dst)
{
  const int i = (blockIdx.x * 256 + threadIdx.x) * 4;
  const float* src; int off;
  if      (i < XCNT)   { src = x;   off = 0; }
  else if (i < KVWOFF) { src = qw;  off = QWOFF; }
  else if (i < SRWOFF) { src = kvw; off = KVWOFF; }
  else if (i < PWOFF)  { src = srw; off = SRWOFF; }
  else                 { src = pw;  off = PWOFF; }
  const float4 v = *(const float4*)(src + (i - off));
  ushort4 o2;
  o2.x = f2b(v.x); o2.y = f2b(v.y); o2.z = f2b(v.z); o2.w = f2b(v.w);
  *(ushort4*)(dst + i) = o2;
}

// ---------------------------------------------------------------------------
// bf16 MFMA GEMM, 512 threads = 8 waves.
// MODE 0 (proj): fp32 out via LDS-staged stores (two row-halves).
// MODE 1 (QKVS): bf16 out, fused per-head norm epilogue, LDS-staged stores.
// ---------------------------------------------------------------------------
template <int MODE>
__launch_bounds__(512)
__global__ void mgemm(const unsigned short* __restrict__ A,
                      const unsigned short* __restrict__ Wb,
                      const float* __restrict__ b0, const float* __restrict__ b1,
                      const float* __restrict__ b2, void* __restrict__ Cv, int Nc,
                      const float* __restrict__ sls, const float* __restrict__ qe,
                      const float* __restrict__ temp, float* __restrict__ Mq)
{
  __shared__ __align__(16) unsigned char smem[34816];
  unsigned short* As = (unsigned short*)smem;            // [128][64]
  unsigned short* Bs = (unsigned short*)(smem + 16384);  // [128][64]
  const int t = threadIdx.x;
  const int w = t >> 6, lane = t & 63;
  const int q = lane >> 4, ln = lane & 15;
  const int n0 = blockIdx.x * 128, m0 = blockIdx.y * 128;
  const int wm = (w >> 1) * 32, wn = (w & 1) * 64;

  float4v acc[2][4];
  #pragma unroll
  for (int mt = 0; mt < 2; ++mt)
    #pragma unroll
    for (int nt = 0; nt < 4; ++nt)
      acc[mt][nt] = (float4v){0.f, 0.f, 0.f, 0.f};

  for (int k0 = 0; k0 < 256; k0 += 64) {
    #pragma unroll
    for (int j = 0; j < 2; ++j) {
      const int u = t + 512 * j;
      const int r = u >> 3, cg = u & 7;
      const int cs = cg ^ (r & 7);
      const uint4 av = *(const uint4*)(A  + (size_t)(m0 + r) * 256 + k0 + cg * 8);
      *(uint4*)(As + r * 64 + cs * 8) = av;
      const uint4 bv = *(const uint4*)(Wb + (size_t)(n0 + r) * 256 + k0 + cg * 8);
      *(uint4*)(Bs + r * 64 + cs * 8) = bv;
    }
    __syncthreads();
    #pragma unroll
    for (int kk = 0; kk < 2; ++kk) {
      short8v af[2], bfr[4];
      const int cg = kk * 4 + q;
      #pragma unroll
      for (int mt = 0; mt < 2; ++mt) {
        const int r = wm + mt * 16 + ln;
        af[mt] = *(const short8v*)(As + r * 64 + (cg ^ (r & 7)) * 8);
      }
      #pragma unroll
      for (int nt = 0; nt < 4; ++nt) {
        const int r = wn + nt * 16 + ln;
        bfr[nt] = *(const short8v*)(Bs + r * 64 + (cg ^ (r & 7)) * 8);
      }
      #pragma unroll
      for (int mt = 0; mt < 2; ++mt)
        #pragma unroll
        for (int nt = 0; nt < 4; ++nt)
          acc[mt][nt] = __builtin_amdgcn_mfma_f32_16x16x32_bf16(af[mt], bfr[nt], acc[mt][nt], 0, 0, 0);
    }
    __syncthreads();
  }

  if constexpr (MODE == 0) {
    float* C = (float*)Cv;
    float* tileF = (float*)smem;
    float bia[4];
    #pragma unroll
    for (int nt = 0; nt < 4; ++nt) bia[nt] = b0[n0 + wn + nt * 16 + ln];
    #pragma unroll
    for (int half = 0; half < 2; ++half) {
      if ((w >> 2) == half) {
        #pragma unroll
        for (int mt = 0; mt < 2; ++mt)
          #pragma unroll
          for (int r = 0; r < 4; ++r)
            #pragma unroll
            for (int nt = 0; nt < 4; ++nt)
              tileF[(wm - half*64 + mt*16 + q*4 + r) * 132 + wn + nt*16 + ln] = acc[mt][nt][r] + bia[nt];
      }
      __syncthreads();
      #pragma unroll
      for (int j = 0; j < 4; ++j) {
        const int i = j * 512 + t;
        const int row = i >> 5, ch = i & 31;
        float4 v = *(const float4*)(tileF + row * 132 + ch * 4);
        *(float4*)(C + (size_t)(m0 + half * 64 + row) * Nc + n0 + ch * 4) = v;
      }
      __syncthreads();
    }
  } else {
    unsigned short* Cb = (unsigned short*)Cv;
    unsigned short* tileC = (unsigned short*)smem;     // [128][136] bf16
    const int seg = n0 >> 8;
    const int h0 = (n0 + wn) >> 5, h1 = h0 + 1;
    float spt0 = 0.f, spt1 = 0.f;
    if (seg == 0) { spt0 = log1pf(__expf(temp[h0])); spt1 = log1pf(__expf(temp[h1])); }
    float bia[4], qev[4];
    #pragma unroll
    for (int nt = 0; nt < 4; ++nt) {
      const int col = n0 + wn + nt * 16 + ln;
      bia[nt] = (seg == 0) ? b0[col] : (seg == 3 ? b2[col - 768] : b1[col - 256]);
      if (seg == 0) qev[nt] = qe[col];
    }
    #pragma unroll
    for (int mt = 0; mt < 2; ++mt) {
      #pragma unroll
      for (int r = 0; r < 4; ++r) {
        const int row = m0 + wm + mt * 16 + q * 4 + r;
        const int lrow = wm + mt * 16 + q * 4 + r;
        float vals[4];
        #pragma unroll
        for (int nt = 0; nt < 4; ++nt) vals[nt] = acc[mt][nt][r] + bia[nt];
        if (seg == 0) {
          float ss0 = vals[0]*vals[0] + vals[1]*vals[1];
          float ss1 = vals[2]*vals[2] + vals[3]*vals[3];
          #pragma unroll
          for (int mk = 1; mk <= 8; mk <<= 1) { ss0 += __shfl_xor(ss0, mk); ss1 += __shfl_xor(ss1, mk); }
          const float i0 = 1.f / fmaxf(sqrtf(ss0), 1e-12f);
          const float i1 = 1.f / fmaxf(sqrtf(ss1), 1e-12f);
          const int nidx = row % Nn, bb = row / Nn;
          const float sl = sls[nidx];
          float qsv[4];
          #pragma unroll
          for (int nt = 0; nt < 4; ++nt) {
            const float inv = (nt < 2) ? i0 : i1;
            const float sp  = (nt < 2) ? spt0 : spt1;
            qsv[nt] = (vals[nt] * inv + qev[nt]) * sp * sl;
          }
          float t0 = qsv[0]*qsv[0] + qsv[1]*qsv[1];
          float t1 = qsv[2]*qsv[2] + qsv[3]*qsv[3];
          #pragma unroll
          for (int mk = 1; mk <= 8; mk <<= 1) { t0 += __shfl_xor(t0, mk); t1 += __shfl_xor(t1, mk); }
          if (ln == 0) {
            Mq[((size_t)(bb * NHn + h0)) * Nn + nidx] = sqrtf(t0);
            Mq[((size_t)(bb * NHn + h1)) * Nn + nidx] = sqrtf(t1);
          }
          #pragma unroll
          for (int nt = 0; nt < 4; ++nt)
            tileC[lrow * 136 + wn + nt*16 + ln] = f2b(qsv[nt]);
        } else if (seg == 1) {
          float ss0 = vals[0]*vals[0] + vals[1]*vals[1];
          float ss1 = vals[2]*vals[2] + vals[3]*vals[3];
          #pragma unroll
          for (int mk = 1; mk <= 8; mk <<= 1) { ss0 += __shfl_xor(ss0, mk); ss1 += __shfl_xor(ss1, mk); }
          const float i0 = 1.f / fmaxf(sqrtf(ss0), 1e-12f);
          const float i1 = 1.f / fmaxf(sqrtf(ss1), 1e-12f);
          #pragma unroll
          for (int nt = 0; nt < 4; ++nt)
            tileC[lrow * 136 + wn + nt*16 + ln] = f2b(vals[nt] * ((nt < 2) ? i0 : i1));
        } else if (seg == 2) {
          #pragma unroll
          for (int nt = 0; nt < 4; ++nt)
            tileC[lrow * 136 + wn + nt*16 + ln] = f2b(vals[nt]);
        } else {
          #pragma unroll
          for (int nt = 0; nt < 4; ++nt) {
            const float v = vals[nt];
            tileC[lrow * 136 + wn + nt*16 + ln] =
              f2b(0.5f * v * (1.0f + erff(v * 0.70710678118654752f)));
          }
        }
      }
    }
    __syncthreads();
    #pragma unroll
    for (int j = 0; j < 4; ++j) {
      const int i = j * 512 + t;
      const int row = i >> 4, ch = i & 15;
      uint4 v = *(const uint4*)(tileC + row * 136 + ch * 8);
      *(uint4*)(Cb + (size_t)(m0 + row) * 1024 + n0 + ch * 8) = v;
    }
  }
}

// ---------------------------------------------------------------------------
// fp32 tiled GEMM (pool path only)
// ---------------------------------------------------------------------------
__launch_bounds__(256)
__global__ void gemm_k(const float* __restrict__ A, const float* __restrict__ W,
                       const float* __restrict__ bias, float* __restrict__ Co,
                       int Mr, int Nc, int K)
{
  __shared__ __align__(16) float As[16][64];
  __shared__ __align__(16) float Ws[16][64];
  const int t  = threadIdx.x;
  const int m0 = blockIdx.y * 64, n0 = blockIdx.x * 64;
  const int lm = t >> 2, lk = (t & 3) << 2;
  const int tx = t & 15, ty = t >> 4;
  float acc[4][4] = {};
  int arow = m0 + lm; if (arow >= Mr) arow = Mr - 1;
  const int wrow = n0 + lm;
  for (int k0 = 0; k0 < K; k0 += 16) {
    float4 av = *(const float4*)(A + (size_t)arow * K + k0 + lk);
    As[lk+0][lm] = av.x; As[lk+1][lm] = av.y; As[lk+2][lm] = av.z; As[lk+3][lm] = av.w;
    float4 wv = *(const float4*)(W + (size_t)wrow * K + k0 + lk);
    Ws[lk+0][lm] = wv.x; Ws[lk+1][lm] = wv.y; Ws[lk+2][lm] = wv.z; Ws[lk+3][lm] = wv.w;
    __syncthreads();
    #pragma unroll
    for (int k = 0; k < 16; ++k) {
      float4 a = *(const float4*)&As[k][ty << 2];
      float4 w = *(const float4*)&Ws[k][tx << 2];
      acc[0][0] += a.x*w.x; acc[0][1] += a.x*w.y; acc[0][2] += a.x*w.z; acc[0][3] += a.x*w.w;
      acc[1][0] += a.y*w.x; acc[1][1] += a.y*w.y; acc[1][2] += a.y*w.z; acc[1][3] += a.y*w.w;
      acc[2][0] += a.z*w.x; acc[2][1] += a.z*w.y; acc[2][2] += a.z*w.z; acc[2][3] += a.z*w.w;
      acc[3][0] += a.w*w.x; acc[3][1] += a.w*w.y; acc[3][2] += a.w*w.z; acc[3][3] += a.w*w.w;
    }
    __syncthreads();
  }
  #pragma unroll
  for (int i = 0; i < 4; ++i) {
    const int row = m0 + (ty << 2) + i;
    if (row >= Mr) continue;
    #pragma unroll
    for (int j = 0; j < 4; ++j) {
      const int col = n0 + (tx << 2) + j;
      Co[(size_t)row * Nc + col] = acc[i][j] + bias[col];
    }
  }
}

// ---------------------------------------------------------------------------
// 4x4 average pool of gelu'd sr (fused bf16 cols 768..1023) + LayerNorm over C
// ---------------------------------------------------------------------------
__launch_bounds__(256)
__global__ void pool_ln_k(const unsigned short* __restrict__ fused, float* __restrict__ pln,
                          const float* __restrict__ g, const float* __restrict__ bb)
{
  const int blk = blockIdx.x;
  const int b = blk / PLn, pc = blk % PLn;
  const int pi = pc / PWn, pj = pc % PWn;
  const int c = threadIdx.x;
  float s = 0.f;
  #pragma unroll
  for (int r = 0; r < 4; ++r)
    #pragma unroll
    for (int cc = 0; cc < 4; ++cc) {
      const int n = (pi*4 + r) * Wn + pj*4 + cc;
      s += b2f(fused[((size_t)b * Nn + n) * 1024 + 768 + c]);
    }
  s *= (1.f/16.f);
  float sum = s, sq = s*s;
  #pragma unroll
  for (int m = 32; m >= 1; m >>= 1) { sum += __shfl_xor(sum, m); sq += __shfl_xor(sq, m); }
  __shared__ float sm[8];
  const int lane = c & 63, wid = c >> 6;
  if (lane == 0) { sm[wid] = sum; sm[4+wid] = sq; }
  __syncthreads();
  const float tot  = sm[0]+sm[1]+sm[2]+sm[3];
  const float totq = sm[4]+sm[5]+sm[6]+sm[7];
  const float mu  = tot * (1.f/256.f);
  const float var = totq * (1.f/256.f) - mu*mu;
  pln[(size_t)blk * Cn + c] = (s - mu) / sqrtf(var + 1e-5f) * g[c] + bb[c];
}

// ---------------------------------------------------------------------------
// pool_pack: kvp -> kbf [bh][224 m][32 d] bf16 (L2-normed k, zero pad m>=196)
//            and vbf [bh][32 d][224 m] bf16 (v transposed)
// ---------------------------------------------------------------------------
__launch_bounds__(256)
__global__ void pool_pack(const float* __restrict__ kvp, unsigned short* __restrict__ kbf,
                          unsigned short* __restrict__ vbf)
{
  const int bh = blockIdx.x;
  const int b = bh >> 3, h = bh & 7;
  const int t = threadIdx.x, mg = t >> 5, d = t & 31;
  const int mi0 = blockIdx.y * 4;
  for (int mi = mi0; mi < mi0 + 4; ++mi) {
    const int m = mi * 8 + mg;
    float kv2 = 0.f, vv = 0.f;
    if (m < PLn) {
      kv2 = kvp[((size_t)(b * PLn + m)) * 512 + h * HDn + d];
      vv  = kvp[((size_t)(b * PLn + m)) * 512 + 256 + h * HDn + d];
    }
    float ssn = kv2 * kv2;
    #pragma unroll
    for (int mm = 16; mm >= 1; mm >>= 1) ssn += __shfl_xor(ssn, mm);
    const float kn = (m < PLn) ? kv2 / fmaxf(sqrtf(ssn), 1e-12f) : 0.f;
    kbf[((size_t)bh * MP + m) * HDn + d] = f2b(kn);
    vbf[((size_t)bh * 32 + d) * MP + m] = f2b(vv);
  }
}

// ---------------------------------------------------------------------------
// CPB MLP
// ---------------------------------------------------------------------------
__launch_bounds__(64)
__global__ void cpb_k(const float* __restrict__ rct, const float* __restrict__ w1,
                      const float* __restrict__ b1, const float* __restrict__ w2,
                      const float* __restrict__ b2, float* __restrict__ tab)
{
  const int r = blockIdx.x, t = threadIdx.x;
  const float c0 = rct[r*2], c1 = rct[r*2+1];
  float part[8] = {};
  #pragma unroll
  for (int jj = 0; jj < 8; ++jj) {
    const int j = t * 8 + jj;
    float hv = fmaxf(c0 * w1[j*2] + c1 * w1[j*2+1] + b1[j], 0.f);
    #pragma unroll
    for (int h = 0; h < 8; ++h) part[h] += hv * w2[h*512 + j];
  }
  #pragma unroll
  for (int h = 0; h < 8; ++h)
    for (int mm = 32; mm >= 1; mm >>= 1) part[h] += __shfl_xor(part[h], mm);
  if (t < 8) tab[r*8 + t] = part[t] + b2[t];
}

// ---------------------------------------------------------------------------
// global max over tab and rpb -> scal[0]
// ---------------------------------------------------------------------------
__launch_bounds__(1024)
__global__ void redmax_k(const float* __restrict__ tab, const float* __restrict__ rpb,
                         float* __restrict__ scal)
{
  float mx = -1e30f;
  for (int i = threadIdx.x; i < KTABn*NHn; i += 1024) mx = fmaxf(mx, tab[i]);
  if (threadIdx.x < NHn*LLn) mx = fmaxf(mx, rpb[threadIdx.x]);
  #pragma unroll
  for (int m = 32; m >= 1; m >>= 1) mx = fmaxf(mx, __shfl_xor(mx, m));
  __shared__ float sm[16];
  if ((threadIdx.x & 63) == 0) sm[threadIdx.x >> 6] = mx;
  __syncthreads();
  if (threadIdx.x == 0) {
    float m2 = sm[0];
    #pragma unroll
    for (int i = 1; i < 16; ++i) m2 = fmaxf(m2, sm[i]);
    scal[0] = m2;
  }
}

// ---------------------------------------------------------------------------
// bias_g2: bias2[h][nt(196)][16 qrow][16 m][16 mt-pad] bf16.
// Block (nt, h): thread t=(qrow,ln) packs its 14 mt values contiguously and
// stores 32 B coalesced. attn_f prefetches these rows into registers.
// ---------------------------------------------------------------------------
__launch_bounds__(256)
__global__ void bias_g2(const int* __restrict__ rpi, const float* __restrict__ tab,
                        unsigned short* __restrict__ bias2)
{
  const int nt = blockIdx.x, h = blockIdx.y;
  const int t = threadIdx.x;
  const int row = t >> 4, ln = t & 15;
  const int n = nt * 16 + row;
  union { uint4 u[2]; unsigned short s[16]; } pk;
  #pragma unroll
  for (int mt = 0; mt < 16; ++mt) {
    const int m = mt * 16 + ln;
    unsigned short v;
    if (mt < 14 && m < PLn) {
      const int idx = rpi[(size_t)n * PLn + m];
      v = f2b(tab[(size_t)idx * NHn + h]);
    } else {
      v = 0xFF80;   // bf16 -inf (also fills pad slots)
    }
    pk.s[mt] = v;
  }
  unsigned short* dst = bias2 + ((((size_t)h * 196 + nt) * 256 + t) << 4);
  *(uint4*)dst = pk.u[0];
  *(uint4*)(dst + 8) = pk.u[1];
}

// ---------------------------------------------------------------------------
// attn_f: FUSED attention.
//  - local k/v window [tile*64-57, tile*64+120] staged once into LDS.
//  - bias2 row prefetched into registers (8 coalesced uint4 loads) before the
//    pool loop -> pool loop has no dependent scalar loads.
//  - park region OVERLAYS the dead P strips (per-wave data dependence through
//    accO orders the LDS ops) -> LDS 38,280 B -> 4 blocks/CU (16 waves).
// ---------------------------------------------------------------------------
__launch_bounds__(256, 4)
__global__ void attn_f(const unsigned short* __restrict__ fused,
                       const unsigned short* __restrict__ kbf,
                       const unsigned short* __restrict__ vbf,
                       const unsigned short* __restrict__ bias2,
                       const float* __restrict__ Mq, const float* __restrict__ scal,
                       const float* __restrict__ slsp, const float* __restrict__ temp,
                       const float* __restrict__ qe, const float* __restrict__ lt,
                       const float* __restrict__ lb, const float* __restrict__ rpb,
                       unsigned short* __restrict__ outp)
{
  __shared__ __align__(16) unsigned short sh[19140];   // 38280 B
  unsigned short* k_s = sh;                  // [178][40] bf16 local-k window
  unsigned short* v_s = sh + 7120;           // [178][40] bf16 local-v window
  // overlay: 4 waves x 528 fp32 park; P strip [16][40] lives in low 640 shorts
  float* park = (float*)(sh + 14240);
  float* tabf = (float*)(sh + 18464);        // qe[32] lt[288] lb[9] rpb[9]
  float* qe_s  = tabf;
  float* lt_s  = tabf + 32;
  float* lb_s  = tabf + 320;
  float* rpb_s = tabf + 329;
  const int t = threadIdx.x;
  const int w = t >> 6, lane = t & 63;
  const int ln = lane & 15, quad = lane >> 4;
  const int tile = blockIdx.x, h = blockIdx.y, b = blockIdx.z;
  const int bh = b * NHn + h;

  if (t < 32) qe_s[t] = qe[h * HDn + t];
  for (int i = t; i < HDn * LLn; i += 256) lt_s[i] = lt[h * HDn * LLn + i];
  if (t < LLn) { lb_s[t] = lb[h * LLn + t]; rpb_s[t] = rpb[h * LLn + t]; }
  // stage the 178-row local k/v window (rows clamped; out-of-range slots unused)
  const int base_n = tile * 64 - 57;
  for (int i = t; i < 712; i += 256) {
    const int row = i >> 2, c4 = i & 3;
    int rg = base_n + row; rg = rg < 0 ? 0 : (rg > Nn - 1 ? Nn - 1 : rg);
    const unsigned short* src = fused + ((size_t)(b * Nn + rg)) * 1024 + 256 + h * HDn + c4 * 8;
    *(uint4*)(k_s + row * 40 + c4 * 8) = *(const uint4*)src;
    *(uint4*)(v_s + row * 40 + c4 * 8) = *(const uint4*)(src + 256);
  }
  __syncthreads();

  // ---- pool part (MFMA), wave w owns q-rows nb..nb+15 ----
  const int nb = tile * 64 + w * 16;
  const int nt2 = tile * 4 + w;
  const short8v afrag = *(const short8v*)(fused +
      ((size_t)(b * Nn + nb + ln)) * 1024 + h * HDn + quad * 8);
  float M4[4];
  const float sc = scal[0];
  #pragma unroll
  for (int r = 0; r < 4; ++r) M4[r] = Mq[(size_t)bh * Nn + nb + quad * 4 + r] + sc;

  // prefetch this thread's 4x14 bias row (coalesced 32 B per r)
  union U16 { uint4 u[2]; unsigned short s[16]; };
  U16 breg[4];
  #pragma unroll
  for (int r = 0; r < 4; ++r) {
    const unsigned short* bp = bias2 +
        ((((size_t)h * 196 + nt2) * 256 + (quad * 4 + r) * 16 + ln) << 4);
    breg[r].u[0] = *(const uint4*)bp;
    breg[r].u[1] = *(const uint4*)(bp + 8);
  }

  const unsigned short* kg = kbf + (size_t)bh * (MP * HDn);   // [224][32]
  const unsigned short* vg = vbf + (size_t)bh * (32 * MP);    // [32][224]
  unsigned short* pst = sh + 14240 + w * 1056;                 // strip in park

  float4v accO[2];
  accO[0] = (float4v){0.f,0.f,0.f,0.f};
  accO[1] = (float4v){0.f,0.f,0.f,0.f};
  float lsum[4] = {0.f, 0.f, 0.f, 0.f};

  #pragma unroll
  for (int kc = 0; kc < 7; ++kc) {
    #pragma unroll
    for (int mtl = 0; mtl < 2; ++mtl) {
      const int mt = kc * 2 + mtl;
      short8v bfrag = *(const short8v*)(kg + (mt * 16 + ln) * HDn + quad * 8);
      float4v s = __builtin_amdgcn_mfma_f32_16x16x32_bf16(afrag, bfrag,
                                                          (float4v){0.f,0.f,0.f,0.f}, 0, 0, 0);
      #pragma unroll
      for (int r = 0; r < 4; ++r) {
        const float bv = b2f(breg[r].s[mt]);
        const float p = __expf(s[r] + bv - M4[r]);
        const unsigned short pb = f2b(p);
        lsum[r] += b2f(pb);                       // bf16-rounded, matches ones-row MFMA
        pst[(quad * 4 + r) * 40 + mtl * 16 + ln] = pb;
      }
    }
    // P chunk (this wave's own strip; same-wave LDS ordering, no barrier)
    short8v pa = *(const short8v*)(pst + ln * 40 + quad * 8);
    #pragma unroll
    for (int nt = 0; nt < 2; ++nt) {
      short8v vb = *(const short8v*)(vg + (size_t)(nt * 16 + ln) * MP + kc * 32 + quad * 8);
      accO[nt] = __builtin_amdgcn_mfma_f32_16x16x32_bf16(pa, vb, accO[nt], 0, 0, 0);
    }
  }

  // row-sum of P (l_pool): reduce lsum across the 16 ln lanes of each quad
  #pragma unroll
  for (int r = 0; r < 4; ++r) {
    #pragma unroll
    for (int mk = 1; mk <= 8; mk <<= 1) lsum[r] += __shfl_xor(lsum[r], mk);
  }

  // park pool partials (overlays the now-dead P strip; ordered by accO dep)
  float* mypark = park + w * 528;
  #pragma unroll
  for (int r = 0; r < 4; ++r) {
    const int row = quad * 4 + r;
    mypark[row * 33 + ln]      = accO[0][r];
    mypark[row * 33 + 16 + ln] = accO[1][r];
    if (ln == 0) mypark[row * 33 + 32] = lsum[r];
  }

  // ---- local part: thread t -> n = tile*64 + (t>>2), d-slice dg = t&3 ----
  const int nl = t >> 2, dg = t & 3;
  const int n = tile * 64 + nl;
  float qs8[8];
  u4_to8f(*(const uint4*)(fused + ((size_t)(b * Nn + n)) * 1024 + h * HDn + dg * 8), qs8);
  const float M = Mq[(size_t)bh * Nn + n] + sc;
  const float spt = log1pf(__expf(temp[h]));
  const float inv_qs = 1.f / (spt * slsp[n]);

  float acc8[8], ext8[8];
  #pragma unroll
  for (int j = 0; j < 8; ++j) { acc8[j] = 0.f; ext8[j] = 0.f; }
  float l_run = 0.f;
  const int pi = n / Wn, pj = n % Wn;
  const int sb = nl + 57;
  #pragma unroll
  for (int lc = 0; lc < LLn; ++lc) {
    const int ii = pi + lc/3 - 1, jj = pj + (lc%3) - 1;
    if (ii < 0 || ii >= Hh || jj < 0 || jj >= Wn) continue;   // uniform in 4-group
    const int slot = sb + (lc/3 - 1) * 56 + (lc%3) - 1;
    float kk8[8], vv8[8];
    u4_to8f(*(const uint4*)(k_s + slot * 40 + dg * 8), kk8);
    u4_to8f(*(const uint4*)(v_s + slot * 40 + dg * 8), vv8);
    float pp = 0.f, ep = 0.f;
    #pragma unroll
    for (int j = 0; j < 8; ++j) {
      pp += qs8[j] * kk8[j];
      ep += (qs8[j] * inv_qs - qe_s[dg*8 + j]) * lt_s[(dg*8 + j) * LLn + lc];
    }
    pp += __shfl_xor(pp, 1); pp += __shfl_xor(pp, 2);
    ep += __shfl_xor(ep, 1); ep += __shfl_xor(ep, 2);
    const float e = ep + lb_s[lc];
    const float p = __expf(pp + rpb_s[lc] - M);
    l_run += p;
    #pragma unroll
    for (int j = 0; j < 8; ++j) { acc8[j] += p * vv8[j]; ext8[j] += e * vv8[j]; }
  }

  // combine with pool partials (this wave's region; no barrier needed)
  const float* pool_r = park + w * 528 + (nl - w * 16) * 33;
  const float l_pool = pool_r[32];
  const float invl = 1.f / (l_run + l_pool);
  uint4 u;
  {
    const float* op = pool_r + dg * 8;
    float o0 = (acc8[0]+op[0])*invl + ext8[0], o1 = (acc8[1]+op[1])*invl + ext8[1];
    float o2 = (acc8[2]+op[2])*invl + ext8[2], o3 = (acc8[3]+op[3])*invl + ext8[3];
    float o4 = (acc8[4]+op[4])*invl + ext8[4], o5 = (acc8[5]+op[5])*invl + ext8[5];
    float o6 = (acc8[6]+op[6])*invl + ext8[6], o7 = (acc8[7]+op[7])*invl + ext8[7];
    u.x = f2b(o0) | ((unsigned int)f2b(o1) << 16);
    u.y = f2b(o2) | ((unsigned int)f2b(o3) << 16);
    u.z = f2b(o4) | ((unsigned int)f2b(o5) << 16);
    u.w = f2b(o6) | ((unsigned int)f2b(o7) << 16);
  }
  *(uint4*)(outp + ((size_t)b * Nn + n) * Cn + h * HDn + dg * 8) = u;
}

// ---------------------------------------------------------------------------
extern "C" void kernel_launch(void* const* d_in, const int* in_sizes, int n_in,
                              void* d_out, int out_size, void* d_ws, size_t ws_size,
                              hipStream_t stream)
{
  const float* x    = (const float*)d_in[0];
  const int*   rpi  = (const int*)d_in[3];
  const float* rct  = (const float*)d_in[4];
  const float* sls  = (const float*)d_in[5];
  const float* q_w  = (const float*)d_in[7];
  const float* q_b  = (const float*)d_in[8];
  const float* kv_w = (const float*)d_in[9];
  const float* kv_b = (const float*)d_in[10];
  const float* sr_w = (const float*)d_in[11];
  const float* sr_b = (const float*)d_in[12];
  const float* ng   = (const float*)d_in[13];
  const float* nbta = (const float*)d_in[14];
  const float* c1w  = (const float*)d_in[15];
  const float* c1b  = (const float*)d_in[16];
  const float* c2w  = (const float*)d_in[17];
  const float* c2b  = (const float*)d_in[18];
  const float* temp = (const float*)d_in[19];
  const float* qe   = (const float*)d_in[20];
  const float* rpb  = (const float*)d_in[21];
  const float* lt   = (const float*)d_in[22];
  const float* lb   = (const float*)d_in[23];
  const float* pw   = (const float*)d_in[24];
  const float* pb   = (const float*)d_in[25];

  float* ws = (float*)d_ws;
  size_t o = 0;
  unsigned short* bf = (unsigned short*)(ws + o); o += TOTCVT / 2;
  unsigned short* fused = (unsigned short*)(ws + o); o += (size_t)Mrows * 512;  // bf16 [12544][1024]
  float* Mq    = ws + o;  o += (size_t)Bn * NHn * Nn;
  float* pln   = ws + o;  o += (size_t)Bn * PLn * Cn;
  float* kvp   = ws + o;  o += (size_t)Bn * PLn * 2 * Cn;
  unsigned short* kbf = (unsigned short*)(ws + o); o += (size_t)Bn * NHn * MP * HDn / 2;
  unsigned short* vbf = (unsigned short*)(ws + o); o += (size_t)Bn * NHn * 32 * MP / 2;
  float* tab   = ws + o;  o += (size_t)KTABn * NHn;
  float* scal  = ws + o;  o += 8;
  unsigned short* bias2 = (unsigned short*)(ws + o); o += (size_t)NHn * 196 * 256 * 16 / 2;
  unsigned short* outp  = (unsigned short*)(ws + o); o += (size_t)Mrows * Cn / 2;

  const unsigned short* xbf   = bf;
  const unsigned short* qkvsw = bf + QWOFF;
  const unsigned short* pwbf  = bf + PWOFF;

  cvt5<<<TOTCVT/1024, 256, 0, stream>>>(x, q_w, kv_w, sr_w, pw, bf);
  mgemm<1><<<dim3(8, 98), 512, 0, stream>>>(xbf, qkvsw, q_b, kv_b, sr_b, fused, 1024,
                                            sls, qe, temp, Mq);
  pool_ln_k<<<Bn*PLn, 256, 0, stream>>>(fused, pln, ng, nbta);
  gemm_k<<<dim3(8, 13), 256, 0, stream>>>(pln, kv_w, kv_b, kvp, Bn*PLn, 512, 256);
  pool_pack<<<dim3(Bn*NHn, 7), 256, 0, stream>>>(kvp, kbf, vbf);
  cpb_k<<<KTABn, 64, 0, stream>>>(rct, c1w, c1b, c2w, c2b, tab);
  redmax_k<<<1, 1024, 0, stream>>>(tab, rpb, scal);
  bias_g2<<<dim3(196, NHn), 256, 0, stream>>>(rpi, tab, bias2);
  attn_f<<<dim3(49, NHn, Bn), 256, 0, stream>>>(fused, kbf, vbf, bias2, Mq, scal,
                                                sls, temp, qe, lt, lb, rpb, outp);
  mgemm<0><<<dim3(2, 98), 512, 0, stream>>>(outp, pwbf, pb, pb, pb, (float*)d_out, 256,
                                            nullptr, nullptr, nullptr, nullptr);
}

// Round 5
// 237.109 us; speedup vs baseline: 1.1323x; 1.0079x over previous
//
#include <hip/hip_runtime.h>
#include <hip/hip_bf16.h>
#include <math.h>

#define Bn   4
#define Hh   56
#define Wn   56
#define Cn   256
#define NHn  8
#define HDn  32
#define Nn   3136
#define LLn  9
#define PLn  196
#define PWn  14
#define KTABn 2048
#define Mrows 12544
#define MP   224            // padded pool-key count (14 x 16)

// cvt5 segment offsets (elements)
#define XCNT   3211264
#define QWOFF  XCNT
#define KVWOFF (QWOFF + 65536)
#define SRWOFF (KVWOFF + 131072)
#define PWOFF  (SRWOFF + 65536)
#define TOTCVT (PWOFF + 65536)

typedef __attribute__((ext_vector_type(8))) short short8v;
typedef __attribute__((ext_vector_type(4))) float float4v;

__device__ __forceinline__ unsigned short f2b(float f) {
  __hip_bfloat16 h = __float2bfloat16(f);
  return *(unsigned short*)&h;
}
__device__ __forceinline__ float b2f(unsigned short u) {
  union { unsigned int i; float f; } x; x.i = ((unsigned int)u) << 16; return x.f;
}
__device__ __forceinline__ void u4_to8f(uint4 u, float* o) {
  o[0]=b2f((unsigned short)(u.x&0xffff)); o[1]=b2f((unsigned short)(u.x>>16));
  o[2]=b2f((unsigned short)(u.y&0xffff)); o[3]=b2f((unsigned short)(u.y>>16));
  o[4]=b2f((unsigned short)(u.z&0xffff)); o[5]=b2f((unsigned short)(u.z>>16));
  o[6]=b2f((unsigned short)(u.w&0xffff)); o[7]=b2f((unsigned short)(u.w>>16));
}
// async global->LDS, 16 B per lane; LDS dest must be wave-uniform base + lane*16
__device__ __forceinline__ void gl_lds16(const unsigned short* g, unsigned short* l) {
  __builtin_amdgcn_global_load_lds(
      (const __attribute__((address_space(1))) unsigned int*)g,
      (__attribute__((address_space(3))) unsigned int*)l, 16, 0, 0);
}

// ---------------------------------------------------------------------------
// Convert x + q_w + kv_w + sr_w + proj_w to one contiguous bf16 area.
// ---------------------------------------------------------------------------
__launch_bounds__(256)
__global__ void cvt5(const float* __restrict__ x, const float* __restrict__ qw,
                     const float* __restrict__ kvw, const float* __restrict__ srw,
                     const float* __restrict__ pw, unsigned short* __restrict__ dst)
{
  const int i = (blockIdx.x * 256 + threadIdx.x) * 4;
  const float* src; int off;
  if      (i < XCNT)   { src = x;   off = 0; }
  else if (i < KVWOFF) { src = qw;  off = QWOFF; }
  else if (i < SRWOFF) { src = kvw; off = KVWOFF; }
  else if (i < PWOFF)  { src = srw; off = SRWOFF; }
  else                 { src = pw;  off = PWOFF; }
  const float4 v = *(const float4*)(src + (i - off));
  ushort4 o2;
  o2.x = f2b(v.x); o2.y = f2b(v.y); o2.z = f2b(v.z); o2.w = f2b(v.w);
  *(ushort4*)(dst + i) = o2;
}

// ---------------------------------------------------------------------------
// bf16 MFMA GEMM, 512 threads = 8 waves.
// Staging via global_load_lds (width 16): LDS dest linear (byte = 16*u), the
// XOR bank-swizzle is applied to the per-lane GLOBAL source chunk instead
// (LDS[r][c] = src chunk c^(r&7)); readers unchanged.
// MODE 0 (proj): fp32 out via LDS-staged stores (two row-halves).
// MODE 1 (QKVS): bf16 out, fused per-head norm epilogue, LDS-staged stores.
// ---------------------------------------------------------------------------
template <int MODE>
__launch_bounds__(512)
__global__ void mgemm(const unsigned short* __restrict__ A,
                      const unsigned short* __restrict__ Wb,
                      const float* __restrict__ b0, const float* __restrict__ b1,
                      const float* __restrict__ b2, void* __restrict__ Cv, int Nc,
                      const float* __restrict__ sls, const float* __restrict__ qe,
                      const float* __restrict__ temp, float* __restrict__ Mq)
{
  __shared__ __align__(16) unsigned char smem[34816];
  unsigned short* As = (unsigned short*)smem;            // [128][64]
  unsigned short* Bs = (unsigned short*)(smem + 16384);  // [128][64]
  const int t = threadIdx.x;
  const int w = t >> 6, lane = t & 63;
  const int q = lane >> 4, ln = lane & 15;
  const int n0 = blockIdx.x * 128, m0 = blockIdx.y * 128;
  const int wm = (w >> 1) * 32, wn = (w & 1) * 64;

  float4v acc[2][4];
  #pragma unroll
  for (int mt = 0; mt < 2; ++mt)
    #pragma unroll
    for (int nt = 0; nt < 4; ++nt)
      acc[mt][nt] = (float4v){0.f, 0.f, 0.f, 0.f};

  for (int k0 = 0; k0 < 256; k0 += 64) {
    #pragma unroll
    for (int j = 0; j < 2; ++j) {
      const int u = t + 512 * j;
      const int r = u >> 3, c = u & 7, sc = c ^ (r & 7);
      gl_lds16(A  + (size_t)(m0 + r) * 256 + k0 + sc * 8, As + u * 8);
      gl_lds16(Wb + (size_t)(n0 + r) * 256 + k0 + sc * 8, Bs + u * 8);
    }
    __syncthreads();
    #pragma unroll
    for (int kk = 0; kk < 2; ++kk) {
      short8v af[2], bfr[4];
      const int cg = kk * 4 + q;
      #pragma unroll
      for (int mt = 0; mt < 2; ++mt) {
        const int r = wm + mt * 16 + ln;
        af[mt] = *(const short8v*)(As + r * 64 + (cg ^ (r & 7)) * 8);
      }
      #pragma unroll
      for (int nt = 0; nt < 4; ++nt) {
        const int r = wn + nt * 16 + ln;
        bfr[nt] = *(const short8v*)(Bs + r * 64 + (cg ^ (r & 7)) * 8);
      }
      #pragma unroll
      for (int mt = 0; mt < 2; ++mt)
        #pragma unroll
        for (int nt = 0; nt < 4; ++nt)
          acc[mt][nt] = __builtin_amdgcn_mfma_f32_16x16x32_bf16(af[mt], bfr[nt], acc[mt][nt], 0, 0, 0);
    }
    __syncthreads();
  }

  if constexpr (MODE == 0) {
    float* C = (float*)Cv;
    float* tileF = (float*)smem;
    float bia[4];
    #pragma unroll
    for (int nt = 0; nt < 4; ++nt) bia[nt] = b0[n0 + wn + nt * 16 + ln];
    #pragma unroll
    for (int half = 0; half < 2; ++half) {
      if ((w >> 2) == half) {
        #pragma unroll
        for (int mt = 0; mt < 2; ++mt)
          #pragma unroll
          for (int r = 0; r < 4; ++r)
            #pragma unroll
            for (int nt = 0; nt < 4; ++nt)
              tileF[(wm - half*64 + mt*16 + q*4 + r) * 132 + wn + nt*16 + ln] = acc[mt][nt][r] + bia[nt];
      }
      __syncthreads();
      #pragma unroll
      for (int j = 0; j < 4; ++j) {
        const int i = j * 512 + t;
        const int row = i >> 5, ch = i & 31;
        float4 v = *(const float4*)(tileF + row * 132 + ch * 4);
        *(float4*)(C + (size_t)(m0 + half * 64 + row) * Nc + n0 + ch * 4) = v;
      }
      __syncthreads();
    }
  } else {
    unsigned short* Cb = (unsigned short*)Cv;
    unsigned short* tileC = (unsigned short*)smem;     // [128][136] bf16
    const int seg = n0 >> 8;
    const int h0 = (n0 + wn) >> 5, h1 = h0 + 1;
    float spt0 = 0.f, spt1 = 0.f;
    if (seg == 0) { spt0 = log1pf(__expf(temp[h0])); spt1 = log1pf(__expf(temp[h1])); }
    float bia[4], qev[4];
    #pragma unroll
    for (int nt = 0; nt < 4; ++nt) {
      const int col = n0 + wn + nt * 16 + ln;
      bia[nt] = (seg == 0) ? b0[col] : (seg == 3 ? b2[col - 768] : b1[col - 256]);
      if (seg == 0) qev[nt] = qe[col];
    }
    #pragma unroll
    for (int mt = 0; mt < 2; ++mt) {
      #pragma unroll
      for (int r = 0; r < 4; ++r) {
        const int row = m0 + wm + mt * 16 + q * 4 + r;
        const int lrow = wm + mt * 16 + q * 4 + r;
        float vals[4];
        #pragma unroll
        for (int nt = 0; nt < 4; ++nt) vals[nt] = acc[mt][nt][r] + bia[nt];
        if (seg == 0) {
          float ss0 = vals[0]*vals[0] + vals[1]*vals[1];
          float ss1 = vals[2]*vals[2] + vals[3]*vals[3];
          #pragma unroll
          for (int mk = 1; mk <= 8; mk <<= 1) { ss0 += __shfl_xor(ss0, mk); ss1 += __shfl_xor(ss1, mk); }
          const float i0 = 1.f / fmaxf(sqrtf(ss0), 1e-12f);
          const float i1 = 1.f / fmaxf(sqrtf(ss1), 1e-12f);
          const int nidx = row % Nn, bb = row / Nn;
          const float sl = sls[nidx];
          float qsv[4];
          #pragma unroll
          for (int nt = 0; nt < 4; ++nt) {
            const float inv = (nt < 2) ? i0 : i1;
            const float sp  = (nt < 2) ? spt0 : spt1;
            qsv[nt] = (vals[nt] * inv + qev[nt]) * sp * sl;
          }
          float t0 = qsv[0]*qsv[0] + qsv[1]*qsv[1];
          float t1 = qsv[2]*qsv[2] + qsv[3]*qsv[3];
          #pragma unroll
          for (int mk = 1; mk <= 8; mk <<= 1) { t0 += __shfl_xor(t0, mk); t1 += __shfl_xor(t1, mk); }
          if (ln == 0) {
            Mq[((size_t)(bb * NHn + h0)) * Nn + nidx] = sqrtf(t0);
            Mq[((size_t)(bb * NHn + h1)) * Nn + nidx] = sqrtf(t1);
          }
          #pragma unroll
          for (int nt = 0; nt < 4; ++nt)
            tileC[lrow * 136 + wn + nt*16 + ln] = f2b(qsv[nt]);
        } else if (seg == 1) {
          float ss0 = vals[0]*vals[0] + vals[1]*vals[1];
          float ss1 = vals[2]*vals[2] + vals[3]*vals[3];
          #pragma unroll
          for (int mk = 1; mk <= 8; mk <<= 1) { ss0 += __shfl_xor(ss0, mk); ss1 += __shfl_xor(ss1, mk); }
          const float i0 = 1.f / fmaxf(sqrtf(ss0), 1e-12f);
          const float i1 = 1.f / fmaxf(sqrtf(ss1), 1e-12f);
          #pragma unroll
          for (int nt = 0; nt < 4; ++nt)
            tileC[lrow * 136 + wn + nt*16 + ln] = f2b(vals[nt] * ((nt < 2) ? i0 : i1));
        } else if (seg == 2) {
          #pragma unroll
          for (int nt = 0; nt < 4; ++nt)
            tileC[lrow * 136 + wn + nt*16 + ln] = f2b(vals[nt]);
        } else {
          #pragma unroll
          for (int nt = 0; nt < 4; ++nt) {
            const float v = vals[nt];
            tileC[lrow * 136 + wn + nt*16 + ln] =
              f2b(0.5f * v * (1.0f + erff(v * 0.70710678118654752f)));
          }
        }
      }
    }
    __syncthreads();
    #pragma unroll
    for (int j = 0; j < 4; ++j) {
      const int i = j * 512 + t;
      const int row = i >> 4, ch = i & 15;
      uint4 v = *(const uint4*)(tileC + row * 136 + ch * 8);
      *(uint4*)(Cb + (size_t)(m0 + row) * 1024 + n0 + ch * 8) = v;
    }
  }
}

// ---------------------------------------------------------------------------
// fp32 tiled GEMM (pool path only)
// ---------------------------------------------------------------------------
__launch_bounds__(256)
__global__ void gemm_k(const float* __restrict__ A, const float* __restrict__ W,
                       const float* __restrict__ bias, float* __restrict__ Co,
                       int Mr, int Nc, int K)
{
  __shared__ __align__(16) float As[16][64];
  __shared__ __align__(16) float Ws[16][64];
  const int t  = threadIdx.x;
  const int m0 = blockIdx.y * 64, n0 = blockIdx.x * 64;
  const int lm = t >> 2, lk = (t & 3) << 2;
  const int tx = t & 15, ty = t >> 4;
  float acc[4][4] = {};
  int arow = m0 + lm; if (arow >= Mr) arow = Mr - 1;
  const int wrow = n0 + lm;
  for (int k0 = 0; k0 < K; k0 += 16) {
    float4 av = *(const float4*)(A + (size_t)arow * K + k0 + lk);
    As[lk+0][lm] = av.x; As[lk+1][lm] = av.y; As[lk+2][lm] = av.z; As[lk+3][lm] = av.w;
    float4 wv = *(const float4*)(W + (size_t)wrow * K + k0 + lk);
    Ws[lk+0][lm] = wv.x; Ws[lk+1][lm] = wv.y; Ws[lk+2][lm] = wv.z; Ws[lk+3][lm] = wv.w;
    __syncthreads();
    #pragma unroll
    for (int k = 0; k < 16; ++k) {
      float4 a = *(const float4*)&As[k][ty << 2];
      float4 w = *(const float4*)&Ws[k][tx << 2];
      acc[0][0] += a.x*w.x; acc[0][1] += a.x*w.y; acc[0][2] += a.x*w.z; acc[0][3] += a.x*w.w;
      acc[1][0] += a.y*w.x; acc[1][1] += a.y*w.y; acc[1][2] += a.y*w.z; acc[1][3] += a.y*w.w;
      acc[2][0] += a.z*w.x; acc[2][1] += a.z*w.y; acc[2][2] += a.z*w.z; acc[2][3] += a.z*w.w;
      acc[3][0] += a.w*w.x; acc[3][1] += a.w*w.y; acc[3][2] += a.w*w.z; acc[3][3] += a.w*w.w;
    }
    __syncthreads();
  }
  #pragma unroll
  for (int i = 0; i < 4; ++i) {
    const int row = m0 + (ty << 2) + i;
    if (row >= Mr) continue;
    #pragma unroll
    for (int j = 0; j < 4; ++j) {
      const int col = n0 + (tx << 2) + j;
      Co[(size_t)row * Nc + col] = acc[i][j] + bias[col];
    }
  }
}

// ---------------------------------------------------------------------------
// 4x4 average pool of gelu'd sr (fused bf16 cols 768..1023) + LayerNorm over C
// ---------------------------------------------------------------------------
__launch_bounds__(256)
__global__ void pool_ln_k(const unsigned short* __restrict__ fused, float* __restrict__ pln,
                          const float* __restrict__ g, const float* __restrict__ bb)
{
  const int blk = blockIdx.x;
  const int b = blk / PLn, pc = blk % PLn;
  const int pi = pc / PWn, pj = pc % PWn;
  const int c = threadIdx.x;
  float s = 0.f;
  #pragma unroll
  for (int r = 0; r < 4; ++r)
    #pragma unroll
    for (int cc = 0; cc < 4; ++cc) {
      const int n = (pi*4 + r) * Wn + pj*4 + cc;
      s += b2f(fused[((size_t)b * Nn + n) * 1024 + 768 + c]);
    }
  s *= (1.f/16.f);
  float sum = s, sq = s*s;
  #pragma unroll
  for (int m = 32; m >= 1; m >>= 1) { sum += __shfl_xor(sum, m); sq += __shfl_xor(sq, m); }
  __shared__ float sm[8];
  const int lane = c & 63, wid = c >> 6;
  if (lane == 0) { sm[wid] = sum; sm[4+wid] = sq; }
  __syncthreads();
  const float tot  = sm[0]+sm[1]+sm[2]+sm[3];
  const float totq = sm[4]+sm[5]+sm[6]+sm[7];
  const float mu  = tot * (1.f/256.f);
  const float var = totq * (1.f/256.f) - mu*mu;
  pln[(size_t)blk * Cn + c] = (s - mu) / sqrtf(var + 1e-5f) * g[c] + bb[c];
}

// ---------------------------------------------------------------------------
// pool_pack: kvp -> kbf [bh][224 m][32 d] bf16 (L2-normed k, zero pad m>=196)
//            and vbf [bh][32 d][224 m] bf16 (v transposed)
// ---------------------------------------------------------------------------
__launch_bounds__(256)
__global__ void pool_pack(const float* __restrict__ kvp, unsigned short* __restrict__ kbf,
                          unsigned short* __restrict__ vbf)
{
  const int bh = blockIdx.x;
  const int b = bh >> 3, h = bh & 7;
  const int t = threadIdx.x, mg = t >> 5, d = t & 31;
  const int mi0 = blockIdx.y * 4;
  for (int mi = mi0; mi < mi0 + 4; ++mi) {
    const int m = mi * 8 + mg;
    float kv2 = 0.f, vv = 0.f;
    if (m < PLn) {
      kv2 = kvp[((size_t)(b * PLn + m)) * 512 + h * HDn + d];
      vv  = kvp[((size_t)(b * PLn + m)) * 512 + 256 + h * HDn + d];
    }
    float ssn = kv2 * kv2;
    #pragma unroll
    for (int mm = 16; mm >= 1; mm >>= 1) ssn += __shfl_xor(ssn, mm);
    const float kn = (m < PLn) ? kv2 / fmaxf(sqrtf(ssn), 1e-12f) : 0.f;
    kbf[((size_t)bh * MP + m) * HDn + d] = f2b(kn);
    vbf[((size_t)bh * 32 + d) * MP + m] = f2b(vv);
  }
}

// ---------------------------------------------------------------------------
// CPB MLP
// ---------------------------------------------------------------------------
__launch_bounds__(64)
__global__ void cpb_k(const float* __restrict__ rct, const float* __restrict__ w1,
                      const float* __restrict__ b1, const float* __restrict__ w2,
                      const float* __restrict__ b2, float* __restrict__ tab)
{
  const int r = blockIdx.x, t = threadIdx.x;
  const float c0 = rct[r*2], c1 = rct[r*2+1];
  float part[8] = {};
  #pragma unroll
  for (int jj = 0; jj < 8; ++jj) {
    const int j = t * 8 + jj;
    float hv = fmaxf(c0 * w1[j*2] + c1 * w1[j*2+1] + b1[j], 0.f);
    #pragma unroll
    for (int h = 0; h < 8; ++h) part[h] += hv * w2[h*512 + j];
  }
  #pragma unroll
  for (int h = 0; h < 8; ++h)
    for (int mm = 32; mm >= 1; mm >>= 1) part[h] += __shfl_xor(part[h], mm);
  if (t < 8) tab[r*8 + t] = part[t] + b2[t];
}

// ---------------------------------------------------------------------------
// global max over tab and rpb -> scal[0]
// ---------------------------------------------------------------------------
__launch_bounds__(1024)
__global__ void redmax_k(const float* __restrict__ tab, const float* __restrict__ rpb,
                         float* __restrict__ scal)
{
  float mx = -1e30f;
  for (int i = threadIdx.x; i < KTABn*NHn; i += 1024) mx = fmaxf(mx, tab[i]);
  if (threadIdx.x < NHn*LLn) mx = fmaxf(mx, rpb[threadIdx.x]);
  #pragma unroll
  for (int m = 32; m >= 1; m >>= 1) mx = fmaxf(mx, __shfl_xor(mx, m));
  __shared__ float sm[16];
  if ((threadIdx.x & 63) == 0) sm[threadIdx.x >> 6] = mx;
  __syncthreads();
  if (threadIdx.x == 0) {
    float m2 = sm[0];
    #pragma unroll
    for (int i = 1; i < 16; ++i) m2 = fmaxf(m2, sm[i]);
    scal[0] = m2;
  }
}

// ---------------------------------------------------------------------------
// bias_g2: bias2[h][nt(196)][16 qrow][16 m][16 mt-pad] bf16.
// Block (nt, h): thread t=(qrow,ln) packs its 14 mt values contiguously and
// stores 32 B coalesced. attn_f prefetches these rows into registers.
// ---------------------------------------------------------------------------
__launch_bounds__(256)
__global__ void bias_g2(const int* __restrict__ rpi, const float* __restrict__ tab,
                        unsigned short* __restrict__ bias2)
{
  const int nt = blockIdx.x, h = blockIdx.y;
  const int t = threadIdx.x;
  const int row = t >> 4, ln = t & 15;
  const int n = nt * 16 + row;
  union { uint4 u[2]; unsigned short s[16]; } pk;
  #pragma unroll
  for (int mt = 0; mt < 16; ++mt) {
    const int m = mt * 16 + ln;
    unsigned short v;
    if (mt < 14 && m < PLn) {
      const int idx = rpi[(size_t)n * PLn + m];
      v = f2b(tab[(size_t)idx * NHn + h]);
    } else {
      v = 0xFF80;   // bf16 -inf (also fills pad slots)
    }
    pk.s[mt] = v;
  }
  unsigned short* dst = bias2 + ((((size_t)h * 196 + nt) * 256 + t) << 4);
  *(uint4*)dst = pk.u[0];
  *(uint4*)(dst + 8) = pk.u[1];
}

// ---------------------------------------------------------------------------
// attn_f: FUSED attention.
//  - local k/v window [tile*64-57, tile*64+120] staged once into LDS via
//    global_load_lds (rows stride 32 -> linear dest = 16*i bytes; the local
//    loop's 16 B/lane contiguous reads are conflict-free without padding).
//  - bias2 row prefetched into registers before the pool loop.
//  - park region OVERLAYS the dead P strips. LDS 32,584 B -> 5 blocks/CU.
// ---------------------------------------------------------------------------
__launch_bounds__(256, 5)
__global__ void attn_f(const unsigned short* __restrict__ fused,
                       const unsigned short* __restrict__ kbf,
                       const unsigned short* __restrict__ vbf,
                       const unsigned short* __restrict__ bias2,
                       const float* __restrict__ Mq, const float* __restrict__ scal,
                       const float* __restrict__ slsp, const float* __restrict__ temp,
                       const float* __restrict__ qe, const float* __restrict__ lt,
                       const float* __restrict__ lb, const float* __restrict__ rpb,
                       unsigned short* __restrict__ outp)
{
  __shared__ __align__(16) unsigned short sh[16292];   // 32,584 B
  unsigned short* k_s = sh;                  // [178][32] bf16 local-k window
  unsigned short* v_s = sh + 5696;           // [178][32] bf16 local-v window
  // overlay: 4 waves x 528 fp32 park; P strip [16][40] lives in low 640 shorts
  float* park = (float*)(sh + 11392);
  float* tabf = (float*)(sh + 15616);        // qe[32] lt[288] lb[9] rpb[9]
  float* qe_s  = tabf;
  float* lt_s  = tabf + 32;
  float* lb_s  = tabf + 320;
  float* rpb_s = tabf + 329;
  const int t = threadIdx.x;
  const int w = t >> 6, lane = t & 63;
  const int ln = lane & 15, quad = lane >> 4;
  const int tile = blockIdx.x, h = blockIdx.y, b = blockIdx.z;
  const int bh = b * NHn + h;

  // stage the 178-row local k/v window (rows clamped; out-of-range slots unused)
  const int base_n = tile * 64 - 57;
  for (int i = t; i < 712; i += 256) {
    const int c4 = i & 3;
    int rg = base_n + (i >> 2); rg = rg < 0 ? 0 : (rg > Nn - 1 ? Nn - 1 : rg);
    const unsigned short* src = fused + ((size_t)(b * Nn + rg)) * 1024 + 256 + h * HDn + c4 * 8;
    gl_lds16(src, k_s + i * 8);
    gl_lds16(src + 256, v_s + i * 8);
  }
  if (t < 32) qe_s[t] = qe[h * HDn + t];
  for (int i = t; i < HDn * LLn; i += 256) lt_s[i] = lt[h * HDn * LLn + i];
  if (t < LLn) { lb_s[t] = lb[h * LLn + t]; rpb_s[t] = rpb[h * LLn + t]; }
  __syncthreads();

  // ---- pool part (MFMA), wave w owns q-rows nb..nb+15 ----
  const int nb = tile * 64 + w * 16;
  const int nt2 = tile * 4 + w;
  const short8v afrag = *(const short8v*)(fused +
      ((size_t)(b * Nn + nb + ln)) * 1024 + h * HDn + quad * 8);
  float M4[4];
  const float sc = scal[0];
  #pragma unroll
  for (int r = 0; r < 4; ++r) M4[r] = Mq[(size_t)bh * Nn + nb + quad * 4 + r] + sc;

  // prefetch this thread's 4x14 bias row (coalesced 32 B per r)
  union U16 { uint4 u[2]; unsigned short s[16]; };
  U16 breg[4];
  #pragma unroll
  for (int r = 0; r < 4; ++r) {
    const unsigned short* bp = bias2 +
        ((((size_t)h * 196 + nt2) * 256 + (quad * 4 + r) * 16 + ln) << 4);
    breg[r].u[0] = *(const uint4*)bp;
    breg[r].u[1] = *(const uint4*)(bp + 8);
  }

  const unsigned short* kg = kbf + (size_t)bh * (MP * HDn);   // [224][32]
  const unsigned short* vg = vbf + (size_t)bh * (32 * MP);    // [32][224]
  unsigned short* pst = sh + 11392 + w * 1056;                 // strip in park

  float4v accO[2];
  accO[0] = (float4v){0.f,0.f,0.f,0.f};
  accO[1] = (float4v){0.f,0.f,0.f,0.f};
  float lsum[4] = {0.f, 0.f, 0.f, 0.f};

  #pragma unroll
  for (int kc = 0; kc < 7; ++kc) {
    #pragma unroll
    for (int mtl = 0; mtl < 2; ++mtl) {
      const int mt = kc * 2 + mtl;
      short8v bfrag = *(const short8v*)(kg + (mt * 16 + ln) * HDn + quad * 8);
      float4v s = __builtin_amdgcn_mfma_f32_16x16x32_bf16(afrag, bfrag,
                                                          (float4v){0.f,0.f,0.f,0.f}, 0, 0, 0);
      #pragma unroll
      for (int r = 0; r < 4; ++r) {
        const float bv = b2f(breg[r].s[mt]);
        const float p = __expf(s[r] + bv - M4[r]);
        const unsigned short pb = f2b(p);
        lsum[r] += b2f(pb);                       // bf16-rounded, matches ones-row MFMA
        pst[(quad * 4 + r) * 40 + mtl * 16 + ln] = pb;
      }
    }
    // P chunk (this wave's own strip; same-wave LDS ordering, no barrier)
    short8v pa = *(const short8v*)(pst + ln * 40 + quad * 8);
    #pragma unroll
    for (int nt = 0; nt < 2; ++nt) {
      short8v vb = *(const short8v*)(vg + (size_t)(nt * 16 + ln) * MP + kc * 32 + quad * 8);
      accO[nt] = __builtin_amdgcn_mfma_f32_16x16x32_bf16(pa, vb, accO[nt], 0, 0, 0);
    }
  }

  // row-sum of P (l_pool): reduce lsum across the 16 ln lanes of each quad
  #pragma unroll
  for (int r = 0; r < 4; ++r) {
    #pragma unroll
    for (int mk = 1; mk <= 8; mk <<= 1) lsum[r] += __shfl_xor(lsum[r], mk);
  }

  // park pool partials (overlays the now-dead P strip; ordered by accO dep)
  float* mypark = park + w * 528;
  #pragma unroll
  for (int r = 0; r < 4; ++r) {
    const int row = quad * 4 + r;
    mypark[row * 33 + ln]      = accO[0][r];
    mypark[row * 33 + 16 + ln] = accO[1][r];
    if (ln == 0) mypark[row * 33 + 32] = lsum[r];
  }

  // ---- local part: thread t -> n = tile*64 + (t>>2), d-slice dg = t&3 ----
  const int nl = t >> 2, dg = t & 3;
  const int n = tile * 64 + nl;
  float qs8[8];
  u4_to8f(*(const uint4*)(fused + ((size_t)(b * Nn + n)) * 1024 + h * HDn + dg * 8), qs8);
  const float M = Mq[(size_t)bh * Nn + n] + sc;
  const float spt = log1pf(__expf(temp[h]));
  const float inv_qs = 1.f / (spt * slsp[n]);

  float acc8[8], ext8[8];
  #pragma unroll
  for (int j = 0; j < 8; ++j) { acc8[j] = 0.f; ext8[j] = 0.f; }
  float l_run = 0.f;
  const int pi = n / Wn, pj = n % Wn;
  const int sb = nl + 57;
  #pragma unroll
  for (int lc = 0; lc < LLn; ++lc) {
    const int ii = pi + lc/3 - 1, jj = pj + (lc%3) - 1;
    if (ii < 0 || ii >= Hh || jj < 0 || jj >= Wn) continue;   // uniform in 4-group
    const int slot = sb + (lc/3 - 1) * 56 + (lc%3) - 1;
    float kk8[8], vv8[8];
    u4_to8f(*(const uint4*)(k_s + slot * 32 + dg * 8), kk8);
    u4_to8f(*(const uint4*)(v_s + slot * 32 + dg * 8), vv8);
    float pp = 0.f, ep = 0.f;
    #pragma unroll
    for (int j = 0; j < 8; ++j) {
      pp += qs8[j] * kk8[j];
      ep += (qs8[j] * inv_qs - qe_s[dg*8 + j]) * lt_s[(dg*8 + j) * LLn + lc];
    }
    pp += __shfl_xor(pp, 1); pp += __shfl_xor(pp, 2);
    ep += __shfl_xor(ep, 1); ep += __shfl_xor(ep, 2);
    const float e = ep + lb_s[lc];
    const float p = __expf(pp + rpb_s[lc] - M);
    l_run += p;
    #pragma unroll
    for (int j = 0; j < 8; ++j) { acc8[j] += p * vv8[j]; ext8[j] += e * vv8[j]; }
  }

  // combine with pool partials (this wave's region; no barrier needed)
  const float* pool_r = park + w * 528 + (nl - w * 16) * 33;
  const float l_pool = pool_r[32];
  const float invl = 1.f / (l_run + l_pool);
  uint4 u;
  {
    const float* op = pool_r + dg * 8;
    float o0 = (acc8[0]+op[0])*invl + ext8[0], o1 = (acc8[1]+op[1])*invl + ext8[1];
    float o2 = (acc8[2]+op[2])*invl + ext8[2], o3 = (acc8[3]+op[3])*invl + ext8[3];
    float o4 = (acc8[4]+op[4])*invl + ext8[4], o5 = (acc8[5]+op[5])*invl + ext8[5];
    float o6 = (acc8[6]+op[6])*invl + ext8[6], o7 = (acc8[7]+op[7])*invl + ext8[7];
    u.x = f2b(o0) | ((unsigned int)f2b(o1) << 16);
    u.y = f2b(o2) | ((unsigned int)f2b(o3) << 16);
    u.z = f2b(o4) | ((unsigned int)f2b(o5) << 16);
    u.w = f2b(o6) | ((unsigned int)f2b(o7) << 16);
  }
  *(uint4*)(outp + ((size_t)b * Nn + n) * Cn + h * HDn + dg * 8) = u;
}

// ---------------------------------------------------------------------------
extern "C" void kernel_launch(void* const* d_in, const int* in_sizes, int n_in,
                              void* d_out, int out_size, void* d_ws, size_t ws_size,
                              hipStream_t stream)
{
  const float* x    = (const float*)d_in[0];
  const int*   rpi  = (const int*)d_in[3];
  const float* rct  = (const float*)d_in[4];
  const float* sls  = (const float*)d_in[5];
  const float* q_w  = (const float*)d_in[7];
  const float* q_b  = (const float*)d_in[8];
  const float* kv_w = (const float*)d_in[9];
  const float* kv_b = (const float*)d_in[10];
  const float* sr_w = (const float*)d_in[11];
  const float* sr_b = (const float*)d_in[12];
  const float* ng   = (const float*)d_in[13];
  const float* nbta = (const float*)d_in[14];
  const float* c1w  = (const float*)d_in[15];
  const float* c1b  = (const float*)d_in[16];
  const float* c2w  = (const float*)d_in[17];
  const float* c2b  = (const float*)d_in[18];
  const float* temp = (const float*)d_in[19];
  const float* qe   = (const float*)d_in[20];
  const float* rpb  = (const float*)d_in[21];
  const float* lt   = (const float*)d_in[22];
  const float* lb   = (const float*)d_in[23];
  const float* pw   = (const float*)d_in[24];
  const float* pb   = (const float*)d_in[25];

  float* ws = (float*)d_ws;
  size_t o = 0;
  unsigned short* bf = (unsigned short*)(ws + o); o += TOTCVT / 2;
  unsigned short* fused = (unsigned short*)(ws + o); o += (size_t)Mrows * 512;  // bf16 [12544][1024]
  float* Mq    = ws + o;  o += (size_t)Bn * NHn * Nn;
  float* pln   = ws + o;  o += (size_t)Bn * PLn * Cn;
  float* kvp   = ws + o;  o += (size_t)Bn * PLn * 2 * Cn;
  unsigned short* kbf = (unsigned short*)(ws + o); o += (size_t)Bn * NHn * MP * HDn / 2;
  unsigned short* vbf = (unsigned short*)(ws + o); o += (size_t)Bn * NHn * 32 * MP / 2;
  float* tab   = ws + o;  o += (size_t)KTABn * NHn;
  float* scal  = ws + o;  o += 8;
  unsigned short* bias2 = (unsigned short*)(ws + o); o += (size_t)NHn * 196 * 256 * 16 / 2;
  unsigned short* outp  = (unsigned short*)(ws + o); o += (size_t)Mrows * Cn / 2;

  const unsigned short* xbf   = bf;
  const unsigned short* qkvsw = bf + QWOFF;
  const unsigned short* pwbf  = bf + PWOFF;

  cvt5<<<TOTCVT/1024, 256, 0, stream>>>(x, q_w, kv_w, sr_w, pw, bf);
  mgemm<1><<<dim3(8, 98), 512, 0, stream>>>(xbf, qkvsw, q_b, kv_b, sr_b, fused, 1024,
                                            sls, qe, temp, Mq);
  pool_ln_k<<<Bn*PLn, 256, 0, stream>>>(fused, pln, ng, nbta);
  gemm_k<<<dim3(8, 13), 256, 0, stream>>>(pln, kv_w, kv_b, kvp, Bn*PLn, 512, 256);
  pool_pack<<<dim3(Bn*NHn, 7), 256, 0, stream>>>(kvp, kbf, vbf);
  cpb_k<<<KTABn, 64, 0, stream>>>(rct, c1w, c1b, c2w, c2b, tab);
  redmax_k<<<1, 1024, 0, stream>>>(tab, rpb, scal);
  bias_g2<<<dim3(196, NHn), 256, 0, stream>>>(rpi, tab, bias2);
  attn_f<<<dim3(49, NHn, Bn), 256, 0, stream>>>(fused, kbf, vbf, bias2, Mq, scal,
                                                sls, temp, qe, lt, lb, rpb, outp);
  mgemm<0><<<dim3(2, 98), 512, 0, stream>>>(outp, pwbf, pb, pb, pb, (float*)d_out, 256,
                                            nullptr, nullptr, nullptr, nullptr);
}

// Round 6
// 226.521 us; speedup vs baseline: 1.1852x; 1.0467x over previous
//
#include <hip/hip_runtime.h>
#include <hip/hip_bf16.h>
#include <math.h>

#define Bn   4
#define Hh   56
#define Wn   56
#define Cn   256
#define NHn  8
#define HDn  32
#define Nn   3136
#define LLn  9
#define PLn  196
#define PWn  14
#define KTABn 2048
#define Mrows 12544
#define MP   224            // padded pool-key count (14 x 16)

// cvt5 segment offsets (elements)
#define XCNT   3211264
#define QWOFF  XCNT
#define KVWOFF (QWOFF + 65536)
#define SRWOFF (KVWOFF + 131072)
#define PWOFF  (SRWOFF + 65536)
#define TOTCVT (PWOFF + 65536)

typedef __attribute__((ext_vector_type(8))) short short8v;
typedef __attribute__((ext_vector_type(4))) float float4v;

__device__ __forceinline__ unsigned short f2b(float f) {
  __hip_bfloat16 h = __float2bfloat16(f);
  return *(unsigned short*)&h;
}
__device__ __forceinline__ float b2f(unsigned short u) {
  union { unsigned int i; float f; } x; x.i = ((unsigned int)u) << 16; return x.f;
}
__device__ __forceinline__ void u4_to8f(uint4 u, float* o) {
  o[0]=b2f((unsigned short)(u.x&0xffff)); o[1]=b2f((unsigned short)(u.x>>16));
  o[2]=b2f((unsigned short)(u.y&0xffff)); o[3]=b2f((unsigned short)(u.y>>16));
  o[4]=b2f((unsigned short)(u.z&0xffff)); o[5]=b2f((unsigned short)(u.z>>16));
  o[6]=b2f((unsigned short)(u.w&0xffff)); o[7]=b2f((unsigned short)(u.w>>16));
}
// async global->LDS, 16 B per lane; LDS dest must be wave-uniform base + lane*16
__device__ __forceinline__ void gl_lds16(const unsigned short* g, unsigned short* l) {
  __builtin_amdgcn_global_load_lds(
      (const __attribute__((address_space(1))) unsigned int*)g,
      (__attribute__((address_space(3))) unsigned int*)l, 16, 0, 0);
}

// ---------------------------------------------------------------------------
// Convert x + q_w + kv_w + sr_w + proj_w to one contiguous bf16 area.
// ---------------------------------------------------------------------------
__launch_bounds__(256)
__global__ void cvt5(const float* __restrict__ x, const float* __restrict__ qw,
                     const float* __restrict__ kvw, const float* __restrict__ srw,
                     const float* __restrict__ pw, unsigned short* __restrict__ dst)
{
  const int i = (blockIdx.x * 256 + threadIdx.x) * 4;
  const float* src; int off;
  if      (i < XCNT)   { src = x;   off = 0; }
  else if (i < KVWOFF) { src = qw;  off = QWOFF; }
  else if (i < SRWOFF) { src = kvw; off = KVWOFF; }
  else if (i < PWOFF)  { src = srw; off = SRWOFF; }
  else                 { src = pw;  off = PWOFF; }
  const float4 v = *(const float4*)(src + (i - off));
  ushort4 o2;
  o2.x = f2b(v.x); o2.y = f2b(v.y); o2.z = f2b(v.z); o2.w = f2b(v.w);
  *(ushort4*)(dst + i) = o2;
}

// ---------------------------------------------------------------------------
// bf16 MFMA GEMM, 512 threads = 8 waves, 1D grid with XCD-bijective swizzle
// (same-A-panel column blocks land on the SAME XCD -> A panel L2-resident).
// Staging via global_load_lds (width 16); XOR bank-swizzle pre-applied to the
// per-lane GLOBAL source chunk; LDS dest linear; readers unchanged.
// MODE 0 (proj, nwg=196): fp32 out via LDS-staged stores.
// MODE 1 (QKVS, nwg=784): bf16 out, fused per-head norm epilogue.
// ---------------------------------------------------------------------------
template <int MODE>
__launch_bounds__(512)
__global__ void mgemm(const unsigned short* __restrict__ A,
                      const unsigned short* __restrict__ Wb,
                      const float* __restrict__ b0, const float* __restrict__ b1,
                      const float* __restrict__ b2, void* __restrict__ Cv, int Nc,
                      const float* __restrict__ sls, const float* __restrict__ qe,
                      const float* __restrict__ temp, float* __restrict__ Mq)
{
  __shared__ __align__(16) unsigned char smem[34816];
  unsigned short* As = (unsigned short*)smem;            // [128][64]
  unsigned short* Bs = (unsigned short*)(smem + 16384);  // [128][64]
  const int t = threadIdx.x;
  const int w = t >> 6, lane = t & 63;
  const int q = lane >> 4, ln = lane & 15;
  int n0, m0;
  if constexpr (MODE == 1) {
    const int hw = blockIdx.x;                       // 784 = 8*98
    const int wid = (hw & 7) * 98 + (hw >> 3);
    n0 = (wid & 7) * 128; m0 = (wid >> 3) * 128;
  } else {
    const int hw = blockIdx.x;                       // 196 = 8*24 + 4
    const int xcd = hw & 7, idx = hw >> 3;
    const int wid = (xcd < 4 ? xcd * 25 : 100 + (xcd - 4) * 24) + idx;
    n0 = (wid & 1) * 128; m0 = (wid >> 1) * 128;
  }
  const int wm = (w >> 1) * 32, wn = (w & 1) * 64;

  float4v acc[2][4];
  #pragma unroll
  for (int mt = 0; mt < 2; ++mt)
    #pragma unroll
    for (int nt = 0; nt < 4; ++nt)
      acc[mt][nt] = (float4v){0.f, 0.f, 0.f, 0.f};

  for (int k0 = 0; k0 < 256; k0 += 64) {
    #pragma unroll
    for (int j = 0; j < 2; ++j) {
      const int u = t + 512 * j;
      const int r = u >> 3, c = u & 7, sc = c ^ (r & 7);
      gl_lds16(A  + (size_t)(m0 + r) * 256 + k0 + sc * 8, As + u * 8);
      gl_lds16(Wb + (size_t)(n0 + r) * 256 + k0 + sc * 8, Bs + u * 8);
    }
    __syncthreads();
    #pragma unroll
    for (int kk = 0; kk < 2; ++kk) {
      short8v af[2], bfr[4];
      const int cg = kk * 4 + q;
      #pragma unroll
      for (int mt = 0; mt < 2; ++mt) {
        const int r = wm + mt * 16 + ln;
        af[mt] = *(const short8v*)(As + r * 64 + (cg ^ (r & 7)) * 8);
      }
      #pragma unroll
      for (int nt = 0; nt < 4; ++nt) {
        const int r = wn + nt * 16 + ln;
        bfr[nt] = *(const short8v*)(Bs + r * 64 + (cg ^ (r & 7)) * 8);
      }
      #pragma unroll
      for (int mt = 0; mt < 2; ++mt)
        #pragma unroll
        for (int nt = 0; nt < 4; ++nt)
          acc[mt][nt] = __builtin_amdgcn_mfma_f32_16x16x32_bf16(af[mt], bfr[nt], acc[mt][nt], 0, 0, 0);
    }
    __syncthreads();
  }

  if constexpr (MODE == 0) {
    float* C = (float*)Cv;
    float* tileF = (float*)smem;
    float bia[4];
    #pragma unroll
    for (int nt = 0; nt < 4; ++nt) bia[nt] = b0[n0 + wn + nt * 16 + ln];
    #pragma unroll
    for (int half = 0; half < 2; ++half) {
      if ((w >> 2) == half) {
        #pragma unroll
        for (int mt = 0; mt < 2; ++mt)
          #pragma unroll
          for (int r = 0; r < 4; ++r)
            #pragma unroll
            for (int nt = 0; nt < 4; ++nt)
              tileF[(wm - half*64 + mt*16 + q*4 + r) * 132 + wn + nt*16 + ln] = acc[mt][nt][r] + bia[nt];
      }
      __syncthreads();
      #pragma unroll
      for (int j = 0; j < 4; ++j) {
        const int i = j * 512 + t;
        const int row = i >> 5, ch = i & 31;
        float4 v = *(const float4*)(tileF + row * 132 + ch * 4);
        *(float4*)(C + (size_t)(m0 + half * 64 + row) * Nc + n0 + ch * 4) = v;
      }
      __syncthreads();
    }
  } else {
    unsigned short* Cb = (unsigned short*)Cv;
    unsigned short* tileC = (unsigned short*)smem;     // [128][136] bf16
    const int seg = n0 >> 8;
    const int h0 = (n0 + wn) >> 5, h1 = h0 + 1;
    float spt0 = 0.f, spt1 = 0.f;
    if (seg == 0) { spt0 = log1pf(__expf(temp[h0])); spt1 = log1pf(__expf(temp[h1])); }
    float bia[4], qev[4];
    #pragma unroll
    for (int nt = 0; nt < 4; ++nt) {
      const int col = n0 + wn + nt * 16 + ln;
      bia[nt] = (seg == 0) ? b0[col] : (seg == 3 ? b2[col - 768] : b1[col - 256]);
      if (seg == 0) qev[nt] = qe[col];
    }
    #pragma unroll
    for (int mt = 0; mt < 2; ++mt) {
      #pragma unroll
      for (int r = 0; r < 4; ++r) {
        const int row = m0 + wm + mt * 16 + q * 4 + r;
        const int lrow = wm + mt * 16 + q * 4 + r;
        float vals[4];
        #pragma unroll
        for (int nt = 0; nt < 4; ++nt) vals[nt] = acc[mt][nt][r] + bia[nt];
        if (seg == 0) {
          float ss0 = vals[0]*vals[0] + vals[1]*vals[1];
          float ss1 = vals[2]*vals[2] + vals[3]*vals[3];
          #pragma unroll
          for (int mk = 1; mk <= 8; mk <<= 1) { ss0 += __shfl_xor(ss0, mk); ss1 += __shfl_xor(ss1, mk); }
          const float i0 = 1.f / fmaxf(sqrtf(ss0), 1e-12f);
          const float i1 = 1.f / fmaxf(sqrtf(ss1), 1e-12f);
          const int nidx = row % Nn, bb = row / Nn;
          const float sl = sls[nidx];
          float qsv[4];
          #pragma unroll
          for (int nt = 0; nt < 4; ++nt) {
            const float inv = (nt < 2) ? i0 : i1;
            const float sp  = (nt < 2) ? spt0 : spt1;
            qsv[nt] = (vals[nt] * inv + qev[nt]) * sp * sl;
          }
          float t0 = qsv[0]*qsv[0] + qsv[1]*qsv[1];
          float t1 = qsv[2]*qsv[2] + qsv[3]*qsv[3];
          #pragma unroll
          for (int mk = 1; mk <= 8; mk <<= 1) { t0 += __shfl_xor(t0, mk); t1 += __shfl_xor(t1, mk); }
          if (ln == 0) {
            Mq[((size_t)(bb * NHn + h0)) * Nn + nidx] = sqrtf(t0);
            Mq[((size_t)(bb * NHn + h1)) * Nn + nidx] = sqrtf(t1);
          }
          #pragma unroll
          for (int nt = 0; nt < 4; ++nt)
            tileC[lrow * 136 + wn + nt*16 + ln] = f2b(qsv[nt]);
        } else if (seg == 1) {
          float ss0 = vals[0]*vals[0] + vals[1]*vals[1];
          float ss1 = vals[2]*vals[2] + vals[3]*vals[3];
          #pragma unroll
          for (int mk = 1; mk <= 8; mk <<= 1) { ss0 += __shfl_xor(ss0, mk); ss1 += __shfl_xor(ss1, mk); }
          const float i0 = 1.f / fmaxf(sqrtf(ss0), 1e-12f);
          const float i1 = 1.f / fmaxf(sqrtf(ss1), 1e-12f);
          #pragma unroll
          for (int nt = 0; nt < 4; ++nt)
            tileC[lrow * 136 + wn + nt*16 + ln] = f2b(vals[nt] * ((nt < 2) ? i0 : i1));
        } else if (seg == 2) {
          #pragma unroll
          for (int nt = 0; nt < 4; ++nt)
            tileC[lrow * 136 + wn + nt*16 + ln] = f2b(vals[nt]);
        } else {
          #pragma unroll
          for (int nt = 0; nt < 4; ++nt) {
            const float v = vals[nt];
            tileC[lrow * 136 + wn + nt*16 + ln] =
              f2b(0.5f * v * (1.0f + erff(v * 0.70710678118654752f)));
          }
        }
      }
    }
    __syncthreads();
    #pragma unroll
    for (int j = 0; j < 4; ++j) {
      const int i = j * 512 + t;
      const int row = i >> 4, ch = i & 15;
      uint4 v = *(const uint4*)(tileC + row * 136 + ch * 8);
      *(uint4*)(Cb + (size_t)(m0 + row) * 1024 + n0 + ch * 8) = v;
    }
  }
}

// ---------------------------------------------------------------------------
// gemm_pp: fp32 tiled GEMM (pool path) with FUSED pool_pack epilogue.
// Computes kvp = pln @ kv_w^T + kv_b, then directly emits:
//   kbf [bh][224 m][32 d] bf16 (L2-normed k)  for col-blocks < 256
//   vbf [bh][32 d][224 m] bf16 (v transposed) for col-blocks >= 256
// (pad m>=196 zeroed separately in redmax_k). Bit-identical values to the
// old kvp-roundtrip path (fp32 store/load was exact).
// ---------------------------------------------------------------------------
__launch_bounds__(256)
__global__ void gemm_pp(const float* __restrict__ A, const float* __restrict__ W,
                        const float* __restrict__ bias,
                        unsigned short* __restrict__ kbf,
                        unsigned short* __restrict__ vbf)
{
  __shared__ __align__(16) float As[16][64];
  __shared__ __align__(16) float Ws[16][64];
  const int t  = threadIdx.x;
  const int m0 = blockIdx.y * 64, n0 = blockIdx.x * 64;
  const int lm = t >> 2, lk = (t & 3) << 2;
  const int tx = t & 15, ty = t >> 4;
  float acc[4][4] = {};
  int arow = m0 + lm; if (arow >= Bn*PLn) arow = Bn*PLn - 1;
  const int wrow = n0 + lm;
  for (int k0 = 0; k0 < 256; k0 += 16) {
    float4 av = *(const float4*)(A + (size_t)arow * 256 + k0 + lk);
    As[lk+0][lm] = av.x; As[lk+1][lm] = av.y; As[lk+2][lm] = av.z; As[lk+3][lm] = av.w;
    float4 wv = *(const float4*)(W + (size_t)wrow * 256 + k0 + lk);
    Ws[lk+0][lm] = wv.x; Ws[lk+1][lm] = wv.y; Ws[lk+2][lm] = wv.z; Ws[lk+3][lm] = wv.w;
    __syncthreads();
    #pragma unroll
    for (int k = 0; k < 16; ++k) {
      float4 a = *(const float4*)&As[k][ty << 2];
      float4 w = *(const float4*)&Ws[k][tx << 2];
      acc[0][0] += a.x*w.x; acc[0][1] += a.x*w.y; acc[0][2] += a.x*w.z; acc[0][3] += a.x*w.w;
      acc[1][0] += a.y*w.x; acc[1][1] += a.y*w.y; acc[1][2] += a.y*w.z; acc[1][3] += a.y*w.w;
      acc[2][0] += a.z*w.x; acc[2][1] += a.z*w.y; acc[2][2] += a.z*w.z; acc[2][3] += a.z*w.w;
      acc[3][0] += a.w*w.x; acc[3][1] += a.w*w.y; acc[3][2] += a.w*w.z; acc[3][3] += a.w*w.w;
    }
    __syncthreads();
  }
  // epilogue: bias + norm/transpose + bf16 emit
  const bool is_k = (n0 < 256);
  const int cb = is_k ? n0 : n0 - 256;
  const int head = (cb + tx * 4) >> 5;        // 0..7 (const per thread)
  const int d0   = (cb + tx * 4) & 31;        // 0,4,...,28
  float vals[4][4];
  #pragma unroll
  for (int i = 0; i < 4; ++i)
    #pragma unroll
    for (int j = 0; j < 4; ++j)
      vals[i][j] = acc[i][j] + bias[n0 + tx * 4 + j];

  if (is_k) {
    #pragma unroll
    for (int i = 0; i < 4; ++i) {
      const int row = m0 + (ty << 2) + i;
      float ss = vals[i][0]*vals[i][0] + vals[i][1]*vals[i][1]
               + vals[i][2]*vals[i][2] + vals[i][3]*vals[i][3];
      ss += __shfl_xor(ss, 1); ss += __shfl_xor(ss, 2); ss += __shfl_xor(ss, 4);
      if (row < Bn*PLn) {
        const float inv = 1.f / fmaxf(sqrtf(ss), 1e-12f);
        const int bb = row / PLn, m = row - bb * PLn;
        const int bh = bb * NHn + head;
        ushort4 o;
        o.x = f2b(vals[i][0] * inv); o.y = f2b(vals[i][1] * inv);
        o.z = f2b(vals[i][2] * inv); o.w = f2b(vals[i][3] * inv);
        *(ushort4*)(kbf + ((size_t)bh * MP + m) * HDn + d0) = o;
      }
    }
  } else {
    const int row0 = m0 + (ty << 2);          // 4 consecutive rows, never cross
    if (row0 < Bn*PLn) {                      // a 196-boundary mid-run (196%4==0)
      const int bb = row0 / PLn, m = row0 - bb * PLn;
      const int bh = bb * NHn + head;
      #pragma unroll
      for (int j = 0; j < 4; ++j) {
        ushort4 o;
        o.x = f2b(vals[0][j]); o.y = f2b(vals[1][j]);
        o.z = f2b(vals[2][j]); o.w = f2b(vals[3][j]);
        *(ushort4*)(vbf + ((size_t)bh * 32 + d0 + j) * MP + m) = o;
      }
    }
  }
}

// ---------------------------------------------------------------------------
// 4x4 average pool of gelu'd sr (fused bf16 cols 768..1023) + LayerNorm over C
// ---------------------------------------------------------------------------
__launch_bounds__(256)
__global__ void pool_ln_k(const unsigned short* __restrict__ fused, float* __restrict__ pln,
                          const float* __restrict__ g, const float* __restrict__ bb)
{
  const int blk = blockIdx.x;
  const int b = blk / PLn, pc = blk % PLn;
  const int pi = pc / PWn, pj = pc % PWn;
  const int c = threadIdx.x;
  float s = 0.f;
  #pragma unroll
  for (int r = 0; r < 4; ++r)
    #pragma unroll
    for (int cc = 0; cc < 4; ++cc) {
      const int n = (pi*4 + r) * Wn + pj*4 + cc;
      s += b2f(fused[((size_t)b * Nn + n) * 1024 + 768 + c]);
    }
  s *= (1.f/16.f);
  float sum = s, sq = s*s;
  #pragma unroll
  for (int m = 32; m >= 1; m >>= 1) { sum += __shfl_xor(sum, m); sq += __shfl_xor(sq, m); }
  __shared__ float sm[8];
  const int lane = c & 63, wid = c >> 6;
  if (lane == 0) { sm[wid] = sum; sm[4+wid] = sq; }
  __syncthreads();
  const float tot  = sm[0]+sm[1]+sm[2]+sm[3];
  const float totq = sm[4]+sm[5]+sm[6]+sm[7];
  const float mu  = tot * (1.f/256.f);
  const float var = totq * (1.f/256.f) - mu*mu;
  pln[(size_t)blk * Cn + c] = (s - mu) / sqrtf(var + 1e-5f) * g[c] + bb[c];
}

// ---------------------------------------------------------------------------
// CPB MLP
// ---------------------------------------------------------------------------
__launch_bounds__(64)
__global__ void cpb_k(const float* __restrict__ rct, const float* __restrict__ w1,
                      const float* __restrict__ b1, const float* __restrict__ w2,
                      const float* __restrict__ b2, float* __restrict__ tab)
{
  const int r = blockIdx.x, t = threadIdx.x;
  const float c0 = rct[r*2], c1 = rct[r*2+1];
  float part[8] = {};
  #pragma unroll
  for (int jj = 0; jj < 8; ++jj) {
    const int j = t * 8 + jj;
    float hv = fmaxf(c0 * w1[j*2] + c1 * w1[j*2+1] + b1[j], 0.f);
    #pragma unroll
    for (int h = 0; h < 8; ++h) part[h] += hv * w2[h*512 + j];
  }
  #pragma unroll
  for (int h = 0; h < 8; ++h)
    for (int mm = 32; mm >= 1; mm >>= 1) part[h] += __shfl_xor(part[h], mm);
  if (t < 8) tab[r*8 + t] = part[t] + b2[t];
}

// ---------------------------------------------------------------------------
// global max over tab and rpb -> scal[0]; also zeroes kbf/vbf pad regions
// (m >= 196) — disjoint from gemm_pp's writes, stream-ordered before attn_f.
// ---------------------------------------------------------------------------
__launch_bounds__(1024)
__global__ void redmax_k(const float* __restrict__ tab, const float* __restrict__ rpb,
                         float* __restrict__ scal,
                         unsigned short* __restrict__ kbf,
                         unsigned short* __restrict__ vbf)
{
  float mx = -1e30f;
  for (int i = threadIdx.x; i < KTABn*NHn; i += 1024) mx = fmaxf(mx, tab[i]);
  if (threadIdx.x < NHn*LLn) mx = fmaxf(mx, rpb[threadIdx.x]);
  #pragma unroll
  for (int m = 32; m >= 1; m >>= 1) mx = fmaxf(mx, __shfl_xor(mx, m));
  __shared__ float sm[16];
  if ((threadIdx.x & 63) == 0) sm[threadIdx.x >> 6] = mx;
  __syncthreads();
  if (threadIdx.x == 0) {
    float m2 = sm[0];
    #pragma unroll
    for (int i = 1; i < 16; ++i) m2 = fmaxf(m2, sm[i]);
    scal[0] = m2;
  }
  // kbf pad: per bh, rows 196..223 contiguous (896 shorts = 112 uint4)
  for (int i = threadIdx.x; i < 32*112; i += 1024) {
    const int bh = i / 112;
    *(uint4*)(kbf + (size_t)bh * (MP*HDn) + PLn*HDn + (i % 112) * 8) = (uint4){0,0,0,0};
  }
  // vbf pad: per (bh,d), cols 196..223 (28 shorts = 7 ushort4)
  for (int i = threadIdx.x; i < 1024*7; i += 1024) {
    const int bhd = i / 7;
    *(ushort4*)(vbf + (size_t)bhd * MP + PLn + (i % 7) * 4) = (ushort4){0,0,0,0};
  }
}

// ---------------------------------------------------------------------------
// bias_g2: bias2[h][nt(196)][16 qrow][16 m][16 mt-pad] bf16.
// ---------------------------------------------------------------------------
__launch_bounds__(256)
__global__ void bias_g2(const int* __restrict__ rpi, const float* __restrict__ tab,
                        unsigned short* __restrict__ bias2)
{
  const int nt = blockIdx.x, h = blockIdx.y;
  const int t = threadIdx.x;
  const int row = t >> 4, ln = t & 15;
  const int n = nt * 16 + row;
  union { uint4 u[2]; unsigned short s[16]; } pk;
  #pragma unroll
  for (int mt = 0; mt < 16; ++mt) {
    const int m = mt * 16 + ln;
    unsigned short v;
    if (mt < 14 && m < PLn) {
      const int idx = rpi[(size_t)n * PLn + m];
      v = f2b(tab[(size_t)idx * NHn + h]);
    } else {
      v = 0xFF80;   // bf16 -inf (also fills pad slots)
    }
    pk.s[mt] = v;
  }
  unsigned short* dst = bias2 + ((((size_t)h * 196 + nt) * 256 + t) << 4);
  *(uint4*)dst = pk.u[0];
  *(uint4*)(dst + 8) = pk.u[1];
}

// ---------------------------------------------------------------------------
// attn_f: FUSED attention, 1D grid with XCD-bijective swizzle: each XCD owns
// 4 complete (b,h) groups (49 tiles each) -> kbf/vbf + window overlap stay in
// that XCD's private L2.
//  - local k/v window staged via global_load_lds (linear dest, stride 32).
//  - bias2 row prefetched into registers before the pool loop.
//  - park overlays the dead P strips. LDS 32,584 B -> 5 blocks/CU.
// ---------------------------------------------------------------------------
__launch_bounds__(256, 5)
__global__ void attn_f(const unsigned short* __restrict__ fused,
                       const unsigned short* __restrict__ kbf,
                       const unsigned short* __restrict__ vbf,
                       const unsigned short* __restrict__ bias2,
                       const float* __restrict__ Mq, const float* __restrict__ scal,
                       const float* __restrict__ slsp, const float* __restrict__ temp,
                       const float* __restrict__ qe, const float* __restrict__ lt,
                       const float* __restrict__ lb, const float* __restrict__ rpb,
                       unsigned short* __restrict__ outp)
{
  __shared__ __align__(16) unsigned short sh[16292];   // 32,584 B
  unsigned short* k_s = sh;                  // [178][32] bf16 local-k window
  unsigned short* v_s = sh + 5696;           // [178][32] bf16 local-v window
  float* park = (float*)(sh + 11392);        // overlay: 4 waves x 528 fp32
  float* tabf = (float*)(sh + 15616);        // qe[32] lt[288] lb[9] rpb[9]
  float* qe_s  = tabf;
  float* lt_s  = tabf + 32;
  float* lb_s  = tabf + 320;
  float* rpb_s = tabf + 329;
  const int t = threadIdx.x;
  const int w = t >> 6, lane = t & 63;
  const int ln = lane & 15, quad = lane >> 4;
  const int hw = blockIdx.x;                 // 1568 = 8*196
  const int wid = (hw & 7) * 196 + (hw >> 3);
  const int tile = wid % 49;
  const int bh = wid / 49;                   // 0..31
  const int h = bh & 7, b = bh >> 3;

  // stage the 178-row local k/v window (rows clamped; out-of-range slots unused)
  const int base_n = tile * 64 - 57;
  for (int i = t; i < 712; i += 256) {
    const int c4 = i & 3;
    int rg = base_n + (i >> 2); rg = rg < 0 ? 0 : (rg > Nn - 1 ? Nn - 1 : rg);
    const unsigned short* src = fused + ((size_t)(b * Nn + rg)) * 1024 + 256 + h * HDn + c4 * 8;
    gl_lds16(src, k_s + i * 8);
    gl_lds16(src + 256, v_s + i * 8);
  }
  if (t < 32) qe_s[t] = qe[h * HDn + t];
  for (int i = t; i < HDn * LLn; i += 256) lt_s[i] = lt[h * HDn * LLn + i];
  if (t < LLn) { lb_s[t] = lb[h * LLn + t]; rpb_s[t] = rpb[h * LLn + t]; }
  __syncthreads();

  // ---- pool part (MFMA), wave w owns q-rows nb..nb+15 ----
  const int nb = tile * 64 + w * 16;
  const int nt2 = tile * 4 + w;
  const short8v afrag = *(const short8v*)(fused +
      ((size_t)(b * Nn + nb + ln)) * 1024 + h * HDn + quad * 8);
  float M4[4];
  const float sc = scal[0];
  #pragma unroll
  for (int r = 0; r < 4; ++r) M4[r] = Mq[(size_t)bh * Nn + nb + quad * 4 + r] + sc;

  // prefetch this thread's 4x14 bias row (coalesced 32 B per r)
  union U16 { uint4 u[2]; unsigned short s[16]; };
  U16 breg[4];
  #pragma unroll
  for (int r = 0; r < 4; ++r) {
    const unsigned short* bp = bias2 +
        ((((size_t)h * 196 + nt2) * 256 + (quad * 4 + r) * 16 + ln) << 4);
    breg[r].u[0] = *(const uint4*)bp;
    breg[r].u[1] = *(const uint4*)(bp + 8);
  }

  const unsigned short* kg = kbf + (size_t)bh * (MP * HDn);   // [224][32]
  const unsigned short* vg = vbf + (size_t)bh * (32 * MP);    // [32][224]
  unsigned short* pst = sh + 11392 + w * 1056;                 // strip in park

  float4v accO[2];
  accO[0] = (float4v){0.f,0.f,0.f,0.f};
  accO[1] = (float4v){0.f,0.f,0.f,0.f};
  float lsum[4] = {0.f, 0.f, 0.f, 0.f};

  #pragma unroll
  for (int kc = 0; kc < 7; ++kc) {
    #pragma unroll
    for (int mtl = 0; mtl < 2; ++mtl) {
      const int mt = kc * 2 + mtl;
      short8v bfrag = *(const short8v*)(kg + (mt * 16 + ln) * HDn + quad * 8);
      float4v s = __builtin_amdgcn_mfma_f32_16x16x32_bf16(afrag, bfrag,
                                                          (float4v){0.f,0.f,0.f,0.f}, 0, 0, 0);
      #pragma unroll
      for (int r = 0; r < 4; ++r) {
        const float bv = b2f(breg[r].s[mt]);
        const float p = __expf(s[r] + bv - M4[r]);
        const unsigned short pb = f2b(p);
        lsum[r] += b2f(pb);                       // bf16-rounded, matches ones-row MFMA
        pst[(quad * 4 + r) * 40 + mtl * 16 + ln] = pb;
      }
    }
    // P chunk (this wave's own strip; same-wave LDS ordering, no barrier)
    short8v pa = *(const short8v*)(pst + ln * 40 + quad * 8);
    #pragma unroll
    for (int nt = 0; nt < 2; ++nt) {
      short8v vb = *(const short8v*)(vg + (size_t)(nt * 16 + ln) * MP + kc * 32 + quad * 8);
      accO[nt] = __builtin_amdgcn_mfma_f32_16x16x32_bf16(pa, vb, accO[nt], 0, 0, 0);
    }
  }

  // row-sum of P (l_pool): reduce lsum across the 16 ln lanes of each quad
  #pragma unroll
  for (int r = 0; r < 4; ++r) {
    #pragma unroll
    for (int mk = 1; mk <= 8; mk <<= 1) lsum[r] += __shfl_xor(lsum[r], mk);
  }

  // park pool partials (overlays the now-dead P strip; ordered by accO dep)
  float* mypark = park + w * 528;
  #pragma unroll
  for (int r = 0; r < 4; ++r) {
    const int row = quad * 4 + r;
    mypark[row * 33 + ln]      = accO[0][r];
    mypark[row * 33 + 16 + ln] = accO[1][r];
    if (ln == 0) mypark[row * 33 + 32] = lsum[r];
  }

  // ---- local part: thread t -> n = tile*64 + (t>>2), d-slice dg = t&3 ----
  const int nl = t >> 2, dg = t & 3;
  const int n = tile * 64 + nl;
  float qs8[8];
  u4_to8f(*(const uint4*)(fused + ((size_t)(b * Nn + n)) * 1024 + h * HDn + dg * 8), qs8);
  const float M = Mq[(size_t)bh * Nn + n] + sc;
  const float spt = log1pf(__expf(temp[h]));
  const float inv_qs = 1.f / (spt * slsp[n]);

  float acc8[8], ext8[8];
  #pragma unroll
  for (int j = 0; j < 8; ++j) { acc8[j] = 0.f; ext8[j] = 0.f; }
  float l_run = 0.f;
  const int pi = n / Wn, pj = n % Wn;
  const int sb = nl + 57;
  #pragma unroll
  for (int lc = 0; lc < LLn; ++lc) {
    const int ii = pi + lc/3 - 1, jj = pj + (lc%3) - 1;
    if (ii < 0 || ii >= Hh || jj < 0 || jj >= Wn) continue;   // uniform in 4-group
    const int slot = sb + (lc/3 - 1) * 56 + (lc%3) - 1;
    float kk8[8], vv8[8];
    u4_to8f(*(const uint4*)(k_s + slot * 32 + dg * 8), kk8);
    u4_to8f(*(const uint4*)(v_s + slot * 32 + dg * 8), vv8);
    float pp = 0.f, ep = 0.f;
    #pragma unroll
    for (int j = 0; j < 8; ++j) {
      pp += qs8[j] * kk8[j];
      ep += (qs8[j] * inv_qs - qe_s[dg*8 + j]) * lt_s[(dg*8 + j) * LLn + lc];
    }
    pp += __shfl_xor(pp, 1); pp += __shfl_xor(pp, 2);
    ep += __shfl_xor(ep, 1); ep += __shfl_xor(ep, 2);
    const float e = ep + lb_s[lc];
    const float p = __expf(pp + rpb_s[lc] - M);
    l_run += p;
    #pragma unroll
    for (int j = 0; j < 8; ++j) { acc8[j] += p * vv8[j]; ext8[j] += e * vv8[j]; }
  }

  // combine with pool partials (this wave's region; no barrier needed)
  const float* pool_r = park + w * 528 + (nl - w * 16) * 33;
  const float l_pool = pool_r[32];
  const float invl = 1.f / (l_run + l_pool);
  uint4 u;
  {
    const float* op = pool_r + dg * 8;
    float o0 = (acc8[0]+op[0])*invl + ext8[0], o1 = (acc8[1]+op[1])*invl + ext8[1];
    float o2 = (acc8[2]+op[2])*invl + ext8[2], o3 = (acc8[3]+op[3])*invl + ext8[3];
    float o4 = (acc8[4]+op[4])*invl + ext8[4], o5 = (acc8[5]+op[5])*invl + ext8[5];
    float o6 = (acc8[6]+op[6])*invl + ext8[6], o7 = (acc8[7]+op[7])*invl + ext8[7];
    u.x = f2b(o0) | ((unsigned int)f2b(o1) << 16);
    u.y = f2b(o2) | ((unsigned int)f2b(o3) << 16);
    u.z = f2b(o4) | ((unsigned int)f2b(o5) << 16);
    u.w = f2b(o6) | ((unsigned int)f2b(o7) << 16);
  }
  *(uint4*)(outp + ((size_t)b * Nn + n) * Cn + h * HDn + dg * 8) = u;
}

// ---------------------------------------------------------------------------
extern "C" void kernel_launch(void* const* d_in, const int* in_sizes, int n_in,
                              void* d_out, int out_size, void* d_ws, size_t ws_size,
                              hipStream_t stream)
{
  const float* x    = (const float*)d_in[0];
  const int*   rpi  = (const int*)d_in[3];
  const float* rct  = (const float*)d_in[4];
  const float* sls  = (const float*)d_in[5];
  const float* q_w  = (const float*)d_in[7];
  const float* q_b  = (const float*)d_in[8];
  const float* kv_w = (const float*)d_in[9];
  const float* kv_b = (const float*)d_in[10];
  const float* sr_w = (const float*)d_in[11];
  const float* sr_b = (const float*)d_in[12];
  const float* ng   = (const float*)d_in[13];
  const float* nbta = (const float*)d_in[14];
  const float* c1w  = (const float*)d_in[15];
  const float* c1b  = (const float*)d_in[16];
  const float* c2w  = (const float*)d_in[17];
  const float* c2b  = (const float*)d_in[18];
  const float* temp = (const float*)d_in[19];
  const float* qe   = (const float*)d_in[20];
  const float* rpb  = (const float*)d_in[21];
  const float* lt   = (const float*)d_in[22];
  const float* lb   = (const float*)d_in[23];
  const float* pw   = (const float*)d_in[24];
  const float* pb   = (const float*)d_in[25];

  float* ws = (float*)d_ws;
  size_t o = 0;
  unsigned short* bf = (unsigned short*)(ws + o); o += TOTCVT / 2;
  unsigned short* fused = (unsigned short*)(ws + o); o += (size_t)Mrows * 512;  // bf16 [12544][1024]
  float* Mq    = ws + o;  o += (size_t)Bn * NHn * Nn;
  float* pln   = ws + o;  o += (size_t)Bn * PLn * Cn;
  unsigned short* kbf = (unsigned short*)(ws + o); o += (size_t)Bn * NHn * MP * HDn / 2;
  unsigned short* vbf = (unsigned short*)(ws + o); o += (size_t)Bn * NHn * 32 * MP / 2;
  float* tab   = ws + o;  o += (size_t)KTABn * NHn;
  float* scal  = ws + o;  o += 8;
  unsigned short* bias2 = (unsigned short*)(ws + o); o += (size_t)NHn * 196 * 256 * 16 / 2;
  unsigned short* outp  = (unsigned short*)(ws + o); o += (size_t)Mrows * Cn / 2;

  const unsigned short* xbf   = bf;
  const unsigned short* qkvsw = bf + QWOFF;
  const unsigned short* pwbf  = bf + PWOFF;

  cvt5<<<TOTCVT/1024, 256, 0, stream>>>(x, q_w, kv_w, sr_w, pw, bf);
  mgemm<1><<<784, 512, 0, stream>>>(xbf, qkvsw, q_b, kv_b, sr_b, fused, 1024,
                                    sls, qe, temp, Mq);
  pool_ln_k<<<Bn*PLn, 256, 0, stream>>>(fused, pln, ng, nbta);
  gemm_pp<<<dim3(8, 13), 256, 0, stream>>>(pln, kv_w, kv_b, kbf, vbf);
  cpb_k<<<KTABn, 64, 0, stream>>>(rct, c1w, c1b, c2w, c2b, tab);
  redmax_k<<<1, 1024, 0, stream>>>(tab, rpb, scal, kbf, vbf);
  bias_g2<<<dim3(196, NHn), 256, 0, stream>>>(rpi, tab, bias2);
  attn_f<<<1568, 256, 0, stream>>>(fused, kbf, vbf, bias2, Mq, scal,
                                   sls, temp, qe, lt, lb, rpb, outp);
  mgemm<0><<<196, 512, 0, stream>>>(outp, pwbf, pb, pb, pb, (float*)d_out, 256,
                                    nullptr, nullptr, nullptr, nullptr);
}

// Round 7
// 218.436 us; speedup vs baseline: 1.2291x; 1.0370x over previous
//
#include <hip/hip_runtime.h>
#include <hip/hip_bf16.h>
#include <math.h>

#define Bn   4
#define Hh   56
#define Wn   56
#define Cn   256
#define NHn  8
#define HDn  32
#define Nn   3136
#define LLn  9
#define PLn  196
#define PWn  14
#define KTABn 2048
#define Mrows 12544
#define MP   224            // padded pool-key count (14 x 16)

// cvt5 segment offsets (elements)
#define XCNT   3211264
#define QWOFF  XCNT
#define KVWOFF (QWOFF + 65536)
#define SRWOFF (KVWOFF + 131072)
#define PWOFF  (SRWOFF + 65536)
#define TOTCVT (PWOFF + 65536)
#define CVTBLK (TOTCVT/1024)     // 3456

typedef __attribute__((ext_vector_type(8))) short short8v;
typedef __attribute__((ext_vector_type(4))) float float4v;

__device__ __forceinline__ unsigned short f2b(float f) {
  __hip_bfloat16 h = __float2bfloat16(f);
  return *(unsigned short*)&h;
}
__device__ __forceinline__ float b2f(unsigned short u) {
  union { unsigned int i; float f; } x; x.i = ((unsigned int)u) << 16; return x.f;
}
__device__ __forceinline__ void u4_to8f(uint4 u, float* o) {
  o[0]=b2f((unsigned short)(u.x&0xffff)); o[1]=b2f((unsigned short)(u.x>>16));
  o[2]=b2f((unsigned short)(u.y&0xffff)); o[3]=b2f((unsigned short)(u.y>>16));
  o[4]=b2f((unsigned short)(u.z&0xffff)); o[5]=b2f((unsigned short)(u.z>>16));
  o[6]=b2f((unsigned short)(u.w&0xffff)); o[7]=b2f((unsigned short)(u.w>>16));
}
// async global->LDS, 16 B per lane; LDS dest must be wave-uniform base + lane*16
__device__ __forceinline__ void gl_lds16(const unsigned short* g, unsigned short* l) {
  __builtin_amdgcn_global_load_lds(
      (const __attribute__((address_space(1))) unsigned int*)g,
      (__attribute__((address_space(3))) unsigned int*)l, 16, 0, 0);
}

// ---------------------------------------------------------------------------
// Launch 1: cvt5 (blocks 0..3455)  ||  CPB MLP (3456..3967, 4 r per block)
//           ||  kbf/vbf pad-zero (3968..3983) — pads are disjoint from
//           gemm_pp's later writes, so any-order is safe.
// ---------------------------------------------------------------------------
__launch_bounds__(256)
__global__ void cvt_misc(const float* __restrict__ x, const float* __restrict__ qw,
                         const float* __restrict__ kvw, const float* __restrict__ srw,
                         const float* __restrict__ pw, unsigned short* __restrict__ dst,
                         const float* __restrict__ rct, const float* __restrict__ w1,
                         const float* __restrict__ b1, const float* __restrict__ w2,
                         const float* __restrict__ b2c, float* __restrict__ tab,
                         unsigned short* __restrict__ kbf, unsigned short* __restrict__ vbf)
{
  const int blk = blockIdx.x;
  const int t = threadIdx.x;
  if (blk < CVTBLK) {
    const int i = (blk * 256 + t) * 4;
    const float* src; int off;
    if      (i < XCNT)   { src = x;   off = 0; }
    else if (i < KVWOFF) { src = qw;  off = QWOFF; }
    else if (i < SRWOFF) { src = kvw; off = KVWOFF; }
    else if (i < PWOFF)  { src = srw; off = SRWOFF; }
    else                 { src = pw;  off = PWOFF; }
    const float4 v = *(const float4*)(src + (i - off));
    ushort4 o2;
    o2.x = f2b(v.x); o2.y = f2b(v.y); o2.z = f2b(v.z); o2.w = f2b(v.w);
    *(ushort4*)(dst + i) = o2;
  } else if (blk < CVTBLK + 512) {
    // CPB MLP: 4 waves, each computes one table row r
    const int w = t >> 6, lane = t & 63;
    const int r = (blk - CVTBLK) * 4 + w;
    const float c0 = rct[r*2], c1 = rct[r*2+1];
    float part[8] = {};
    #pragma unroll
    for (int jj = 0; jj < 8; ++jj) {
      const int j = lane * 8 + jj;
      float hv = fmaxf(c0 * w1[j*2] + c1 * w1[j*2+1] + b1[j], 0.f);
      #pragma unroll
      for (int h = 0; h < 8; ++h) part[h] += hv * w2[h*512 + j];
    }
    #pragma unroll
    for (int h = 0; h < 8; ++h)
      for (int mm = 32; mm >= 1; mm >>= 1) part[h] += __shfl_xor(part[h], mm);
    if (lane < 8) tab[r*8 + lane] = part[lane] + b2c[lane];
  } else {
    // pad-zero: kbf rows 196..223 (32 bh x 112 uint4), vbf cols 196..223
    const int i = (blk - (CVTBLK + 512)) * 256 + t;     // 0..4095
    for (int j = i; j < 32*112; j += 4096) {
      const int bh = j / 112;
      *(uint4*)(kbf + (size_t)bh * (MP*HDn) + PLn*HDn + (j % 112) * 8) = (uint4){0,0,0,0};
    }
    for (int j = i; j < 1024*7; j += 4096) {
      const int bhd = j / 7;
      *(ushort4*)(vbf + (size_t)bhd * MP + PLn + (j % 7) * 4) = (ushort4){0,0,0,0};
    }
  }
}

// ---------------------------------------------------------------------------
// bf16 MFMA GEMM, 512 threads = 8 waves, 1D grid with XCD-bijective swizzle
// (same-A-panel column blocks land on the SAME XCD -> A panel L2-resident).
// Staging via global_load_lds (width 16); XOR bank-swizzle pre-applied to the
// per-lane GLOBAL source chunk; LDS dest linear; readers unchanged.
// MODE 0 (proj, nwg=196): fp32 out via LDS-staged stores.
// MODE 1 (QKVS, nwg=784): bf16 out, fused per-head norm epilogue.
// ---------------------------------------------------------------------------
template <int MODE>
__launch_bounds__(512)
__global__ void mgemm(const unsigned short* __restrict__ A,
                      const unsigned short* __restrict__ Wb,
                      const float* __restrict__ b0, const float* __restrict__ b1,
                      const float* __restrict__ b2, void* __restrict__ Cv, int Nc,
                      const float* __restrict__ sls, const float* __restrict__ qe,
                      const float* __restrict__ temp, float* __restrict__ Mq)
{
  __shared__ __align__(16) unsigned char smem[34816];
  unsigned short* As = (unsigned short*)smem;            // [128][64]
  unsigned short* Bs = (unsigned short*)(smem + 16384);  // [128][64]
  const int t = threadIdx.x;
  const int w = t >> 6, lane = t & 63;
  const int q = lane >> 4, ln = lane & 15;
  int n0, m0;
  if constexpr (MODE == 1) {
    const int hw = blockIdx.x;                       // 784 = 8*98
    const int wid = (hw & 7) * 98 + (hw >> 3);
    n0 = (wid & 7) * 128; m0 = (wid >> 3) * 128;
  } else {
    const int hw = blockIdx.x;                       // 196 = 8*24 + 4
    const int xcd = hw & 7, idx = hw >> 3;
    const int wid = (xcd < 4 ? xcd * 25 : 100 + (xcd - 4) * 24) + idx;
    n0 = (wid & 1) * 128; m0 = (wid >> 1) * 128;
  }
  const int wm = (w >> 1) * 32, wn = (w & 1) * 64;

  float4v acc[2][4];
  #pragma unroll
  for (int mt = 0; mt < 2; ++mt)
    #pragma unroll
    for (int nt = 0; nt < 4; ++nt)
      acc[mt][nt] = (float4v){0.f, 0.f, 0.f, 0.f};

  for (int k0 = 0; k0 < 256; k0 += 64) {
    #pragma unroll
    for (int j = 0; j < 2; ++j) {
      const int u = t + 512 * j;
      const int r = u >> 3, c = u & 7, sc = c ^ (r & 7);
      gl_lds16(A  + (size_t)(m0 + r) * 256 + k0 + sc * 8, As + u * 8);
      gl_lds16(Wb + (size_t)(n0 + r) * 256 + k0 + sc * 8, Bs + u * 8);
    }
    __syncthreads();
    #pragma unroll
    for (int kk = 0; kk < 2; ++kk) {
      short8v af[2], bfr[4];
      const int cg = kk * 4 + q;
      #pragma unroll
      for (int mt = 0; mt < 2; ++mt) {
        const int r = wm + mt * 16 + ln;
        af[mt] = *(const short8v*)(As + r * 64 + (cg ^ (r & 7)) * 8);
      }
      #pragma unroll
      for (int nt = 0; nt < 4; ++nt) {
        const int r = wn + nt * 16 + ln;
        bfr[nt] = *(const short8v*)(Bs + r * 64 + (cg ^ (r & 7)) * 8);
      }
      #pragma unroll
      for (int mt = 0; mt < 2; ++mt)
        #pragma unroll
        for (int nt = 0; nt < 4; ++nt)
          acc[mt][nt] = __builtin_amdgcn_mfma_f32_16x16x32_bf16(af[mt], bfr[nt], acc[mt][nt], 0, 0, 0);
    }
    __syncthreads();
  }

  if constexpr (MODE == 0) {
    float* C = (float*)Cv;
    float* tileF = (float*)smem;
    float bia[4];
    #pragma unroll
    for (int nt = 0; nt < 4; ++nt) bia[nt] = b0[n0 + wn + nt * 16 + ln];
    #pragma unroll
    for (int half = 0; half < 2; ++half) {
      if ((w >> 2) == half) {
        #pragma unroll
        for (int mt = 0; mt < 2; ++mt)
          #pragma unroll
          for (int r = 0; r < 4; ++r)
            #pragma unroll
            for (int nt = 0; nt < 4; ++nt)
              tileF[(wm - half*64 + mt*16 + q*4 + r) * 132 + wn + nt*16 + ln] = acc[mt][nt][r] + bia[nt];
      }
      __syncthreads();
      #pragma unroll
      for (int j = 0; j < 4; ++j) {
        const int i = j * 512 + t;
        const int row = i >> 5, ch = i & 31;
        float4 v = *(const float4*)(tileF + row * 132 + ch * 4);
        *(float4*)(C + (size_t)(m0 + half * 64 + row) * Nc + n0 + ch * 4) = v;
      }
      __syncthreads();
    }
  } else {
    unsigned short* Cb = (unsigned short*)Cv;
    unsigned short* tileC = (unsigned short*)smem;     // [128][136] bf16
    const int seg = n0 >> 8;
    const int h0 = (n0 + wn) >> 5, h1 = h0 + 1;
    float spt0 = 0.f, spt1 = 0.f;
    if (seg == 0) { spt0 = log1pf(__expf(temp[h0])); spt1 = log1pf(__expf(temp[h1])); }
    float bia[4], qev[4];
    #pragma unroll
    for (int nt = 0; nt < 4; ++nt) {
      const int col = n0 + wn + nt * 16 + ln;
      bia[nt] = (seg == 0) ? b0[col] : (seg == 3 ? b2[col - 768] : b1[col - 256]);
      if (seg == 0) qev[nt] = qe[col];
    }
    #pragma unroll
    for (int mt = 0; mt < 2; ++mt) {
      #pragma unroll
      for (int r = 0; r < 4; ++r) {
        const int row = m0 + wm + mt * 16 + q * 4 + r;
        const int lrow = wm + mt * 16 + q * 4 + r;
        float vals[4];
        #pragma unroll
        for (int nt = 0; nt < 4; ++nt) vals[nt] = acc[mt][nt][r] + bia[nt];
        if (seg == 0) {
          float ss0 = vals[0]*vals[0] + vals[1]*vals[1];
          float ss1 = vals[2]*vals[2] + vals[3]*vals[3];
          #pragma unroll
          for (int mk = 1; mk <= 8; mk <<= 1) { ss0 += __shfl_xor(ss0, mk); ss1 += __shfl_xor(ss1, mk); }
          const float i0 = 1.f / fmaxf(sqrtf(ss0), 1e-12f);
          const float i1 = 1.f / fmaxf(sqrtf(ss1), 1e-12f);
          const int nidx = row % Nn, bb = row / Nn;
          const float sl = sls[nidx];
          float qsv[4];
          #pragma unroll
          for (int nt = 0; nt < 4; ++nt) {
            const float inv = (nt < 2) ? i0 : i1;
            const float sp  = (nt < 2) ? spt0 : spt1;
            qsv[nt] = (vals[nt] * inv + qev[nt]) * sp * sl;
          }
          float t0 = qsv[0]*qsv[0] + qsv[1]*qsv[1];
          float t1 = qsv[2]*qsv[2] + qsv[3]*qsv[3];
          #pragma unroll
          for (int mk = 1; mk <= 8; mk <<= 1) { t0 += __shfl_xor(t0, mk); t1 += __shfl_xor(t1, mk); }
          if (ln == 0) {
            Mq[((size_t)(bb * NHn + h0)) * Nn + nidx] = sqrtf(t0);
            Mq[((size_t)(bb * NHn + h1)) * Nn + nidx] = sqrtf(t1);
          }
          #pragma unroll
          for (int nt = 0; nt < 4; ++nt)
            tileC[lrow * 136 + wn + nt*16 + ln] = f2b(qsv[nt]);
        } else if (seg == 1) {
          float ss0 = vals[0]*vals[0] + vals[1]*vals[1];
          float ss1 = vals[2]*vals[2] + vals[3]*vals[3];
          #pragma unroll
          for (int mk = 1; mk <= 8; mk <<= 1) { ss0 += __shfl_xor(ss0, mk); ss1 += __shfl_xor(ss1, mk); }
          const float i0 = 1.f / fmaxf(sqrtf(ss0), 1e-12f);
          const float i1 = 1.f / fmaxf(sqrtf(ss1), 1e-12f);
          #pragma unroll
          for (int nt = 0; nt < 4; ++nt)
            tileC[lrow * 136 + wn + nt*16 + ln] = f2b(vals[nt] * ((nt < 2) ? i0 : i1));
        } else if (seg == 2) {
          #pragma unroll
          for (int nt = 0; nt < 4; ++nt)
            tileC[lrow * 136 + wn + nt*16 + ln] = f2b(vals[nt]);
        } else {
          #pragma unroll
          for (int nt = 0; nt < 4; ++nt) {
            const float v = vals[nt];
            tileC[lrow * 136 + wn + nt*16 + ln] =
              f2b(0.5f * v * (1.0f + erff(v * 0.70710678118654752f)));
          }
        }
      }
    }
    __syncthreads();
    #pragma unroll
    for (int j = 0; j < 4; ++j) {
      const int i = j * 512 + t;
      const int row = i >> 4, ch = i & 15;
      uint4 v = *(const uint4*)(tileC + row * 136 + ch * 8);
      *(uint4*)(Cb + (size_t)(m0 + row) * 1024 + n0 + ch * 8) = v;
    }
  }
}

// ---------------------------------------------------------------------------
// Launch 3: pool_ln (blocks 0..783)  ||  bias_g2 (784..2351)  ||  redmax (2352)
// All three depend only on {fused, tab} which are complete by launch 3.
// ---------------------------------------------------------------------------
__launch_bounds__(256)
__global__ void mid_k(const unsigned short* __restrict__ fused, float* __restrict__ pln,
                      const float* __restrict__ g, const float* __restrict__ bbln,
                      const int* __restrict__ rpi, const float* __restrict__ tab,
                      unsigned short* __restrict__ bias2,
                      const float* __restrict__ rpb, float* __restrict__ scal)
{
  const int blk = blockIdx.x;
  const int t = threadIdx.x;
  __shared__ float sm[8];
  if (blk < 784) {
    // ---- pool_ln ----
    const int b = blk / PLn, pc = blk % PLn;
    const int pi = pc / PWn, pj = pc % PWn;
    const int c = t;
    float s = 0.f;
    #pragma unroll
    for (int r = 0; r < 4; ++r)
      #pragma unroll
      for (int cc = 0; cc < 4; ++cc) {
        const int n = (pi*4 + r) * Wn + pj*4 + cc;
        s += b2f(fused[((size_t)b * Nn + n) * 1024 + 768 + c]);
      }
    s *= (1.f/16.f);
    float sum = s, sq = s*s;
    #pragma unroll
    for (int m = 32; m >= 1; m >>= 1) { sum += __shfl_xor(sum, m); sq += __shfl_xor(sq, m); }
    const int lane = c & 63, wid = c >> 6;
    if (lane == 0) { sm[wid] = sum; sm[4+wid] = sq; }
    __syncthreads();
    const float tot  = sm[0]+sm[1]+sm[2]+sm[3];
    const float totq = sm[4]+sm[5]+sm[6]+sm[7];
    const float mu  = tot * (1.f/256.f);
    const float var = totq * (1.f/256.f) - mu*mu;
    pln[(size_t)blk * Cn + c] = (s - mu) / sqrtf(var + 1e-5f) * g[c] + bbln[c];
  } else if (blk < 2352) {
    // ---- bias_g2: bias2[h][nt][16 qrow][16 m][16 mt-pad] bf16 ----
    const int idx = blk - 784;
    const int nt = idx % 196, h = idx / 196;
    const int row = t >> 4, ln = t & 15;
    const int n = nt * 16 + row;
    union { uint4 u[2]; unsigned short s[16]; } pk;
    #pragma unroll
    for (int mt = 0; mt < 16; ++mt) {
      const int m = mt * 16 + ln;
      unsigned short v;
      if (mt < 14 && m < PLn) {
        const int ix = rpi[(size_t)n * PLn + m];
        v = f2b(tab[(size_t)ix * NHn + h]);
      } else {
        v = 0xFF80;   // bf16 -inf (also fills pad slots)
      }
      pk.s[mt] = v;
    }
    unsigned short* dst = bias2 + ((((size_t)h * 196 + nt) * 256 + t) << 4);
    *(uint4*)dst = pk.u[0];
    *(uint4*)(dst + 8) = pk.u[1];
  } else {
    // ---- redmax: global max over tab and rpb -> scal[0] ----
    float mx = -1e30f;
    for (int i = t; i < KTABn*NHn; i += 256) mx = fmaxf(mx, tab[i]);
    if (t < NHn*LLn) mx = fmaxf(mx, rpb[t]);
    #pragma unroll
    for (int m = 32; m >= 1; m >>= 1) mx = fmaxf(mx, __shfl_xor(mx, m));
    if ((t & 63) == 0) sm[t >> 6] = mx;
    __syncthreads();
    if (t == 0) scal[0] = fmaxf(fmaxf(sm[0], sm[1]), fmaxf(sm[2], sm[3]));
  }
}

// ---------------------------------------------------------------------------
// gemm_pp: fp32 tiled GEMM (pool path) with FUSED pool_pack epilogue.
// Computes kvp = pln @ kv_w^T + kv_b, then directly emits:
//   kbf [bh][224 m][32 d] bf16 (L2-normed k)  for col-blocks < 256
//   vbf [bh][32 d][224 m] bf16 (v transposed) for col-blocks >= 256
// (pad m>=196 zeroed in launch 1). Bit-identical to the kvp-roundtrip path.
// ---------------------------------------------------------------------------
__launch_bounds__(256)
__global__ void gemm_pp(const float* __restrict__ A, const float* __restrict__ W,
                        const float* __restrict__ bias,
                        unsigned short* __restrict__ kbf,
                        unsigned short* __restrict__ vbf)
{
  __shared__ __align__(16) float As[16][64];
  __shared__ __align__(16) float Ws[16][64];
  const int t  = threadIdx.x;
  const int m0 = blockIdx.y * 64, n0 = blockIdx.x * 64;
  const int lm = t >> 2, lk = (t & 3) << 2;
  const int tx = t & 15, ty = t >> 4;
  float acc[4][4] = {};
  int arow = m0 + lm; if (arow >= Bn*PLn) arow = Bn*PLn - 1;
  const int wrow = n0 + lm;
  for (int k0 = 0; k0 < 256; k0 += 16) {
    float4 av = *(const float4*)(A + (size_t)arow * 256 + k0 + lk);
    As[lk+0][lm] = av.x; As[lk+1][lm] = av.y; As[lk+2][lm] = av.z; As[lk+3][lm] = av.w;
    float4 wv = *(const float4*)(W + (size_t)wrow * 256 + k0 + lk);
    Ws[lk+0][lm] = wv.x; Ws[lk+1][lm] = wv.y; Ws[lk+2][lm] = wv.z; Ws[lk+3][lm] = wv.w;
    __syncthreads();
    #pragma unroll
    for (int k = 0; k < 16; ++k) {
      float4 a = *(const float4*)&As[k][ty << 2];
      float4 w = *(const float4*)&Ws[k][tx << 2];
      acc[0][0] += a.x*w.x; acc[0][1] += a.x*w.y; acc[0][2] += a.x*w.z; acc[0][3] += a.x*w.w;
      acc[1][0] += a.y*w.x; acc[1][1] += a.y*w.y; acc[1][2] += a.y*w.z; acc[1][3] += a.y*w.w;
      acc[2][0] += a.z*w.x; acc[2][1] += a.z*w.y; acc[2][2] += a.z*w.z; acc[2][3] += a.z*w.w;
      acc[3][0] += a.w*w.x; acc[3][1] += a.w*w.y; acc[3][2] += a.w*w.z; acc[3][3] += a.w*w.w;
    }
    __syncthreads();
  }
  // epilogue: bias + norm/transpose + bf16 emit
  const bool is_k = (n0 < 256);
  const int cb = is_k ? n0 : n0 - 256;
  const int head = (cb + tx * 4) >> 5;        // 0..7 (const per thread)
  const int d0   = (cb + tx * 4) & 31;        // 0,4,...,28
  float vals[4][4];
  #pragma unroll
  for (int i = 0; i < 4; ++i)
    #pragma unroll
    for (int j = 0; j < 4; ++j)
      vals[i][j] = acc[i][j] + bias[n0 + tx * 4 + j];

  if (is_k) {
    #pragma unroll
    for (int i = 0; i < 4; ++i) {
      const int row = m0 + (ty << 2) + i;
      float ss = vals[i][0]*vals[i][0] + vals[i][1]*vals[i][1]
               + vals[i][2]*vals[i][2] + vals[i][3]*vals[i][3];
      ss += __shfl_xor(ss, 1); ss += __shfl_xor(ss, 2); ss += __shfl_xor(ss, 4);
      if (row < Bn*PLn) {
        const float inv = 1.f / fmaxf(sqrtf(ss), 1e-12f);
        const int bb = row / PLn, m = row - bb * PLn;
        const int bh = bb * NHn + head;
        ushort4 o;
        o.x = f2b(vals[i][0] * inv); o.y = f2b(vals[i][1] * inv);
        o.z = f2b(vals[i][2] * inv); o.w = f2b(vals[i][3] * inv);
        *(ushort4*)(kbf + ((size_t)bh * MP + m) * HDn + d0) = o;
      }
    }
  } else {
    const int row0 = m0 + (ty << 2);          // 4 consecutive rows, never cross
    if (row0 < Bn*PLn) {                      // a 196-boundary mid-run (196%4==0)
      const int bb = row0 / PLn, m = row0 - bb * PLn;
      const int bh = bb * NHn + head;
      #pragma unroll
      for (int j = 0; j < 4; ++j) {
        ushort4 o;
        o.x = f2b(vals[0][j]); o.y = f2b(vals[1][j]);
        o.z = f2b(vals[2][j]); o.w = f2b(vals[3][j]);
        *(ushort4*)(vbf + ((size_t)bh * 32 + d0 + j) * MP + m) = o;
      }
    }
  }
}

// ---------------------------------------------------------------------------
// attn_f: FUSED attention, 1D grid with XCD-bijective swizzle: each XCD owns
// 4 complete (b,h) groups (49 tiles each) -> kbf/vbf + window overlap stay in
// that XCD's private L2.
//  - local k/v window staged via global_load_lds (linear dest, stride 32).
//  - bias2 row prefetched into registers before the pool loop.
//  - park overlays the dead P strips. LDS 32,584 B -> 5 blocks/CU.
// ---------------------------------------------------------------------------
__launch_bounds__(256, 5)
__global__ void attn_f(const unsigned short* __restrict__ fused,
                       const unsigned short* __restrict__ kbf,
                       const unsigned short* __restrict__ vbf,
                       const unsigned short* __restrict__ bias2,
                       const float* __restrict__ Mq, const float* __restrict__ scal,
                       const float* __restrict__ slsp, const float* __restrict__ temp,
                       const float* __restrict__ qe, const float* __restrict__ lt,
                       const float* __restrict__ lb, const float* __restrict__ rpb,
                       unsigned short* __restrict__ outp)
{
  __shared__ __align__(16) unsigned short sh[16292];   // 32,584 B
  unsigned short* k_s = sh;                  // [178][32] bf16 local-k window
  unsigned short* v_s = sh + 5696;           // [178][32] bf16 local-v window
  float* park = (float*)(sh + 11392);        // overlay: 4 waves x 528 fp32
  float* tabf = (float*)(sh + 15616);        // qe[32] lt[288] lb[9] rpb[9]
  float* qe_s  = tabf;
  float* lt_s  = tabf + 32;
  float* lb_s  = tabf + 320;
  float* rpb_s = tabf + 329;
  const int t = threadIdx.x;
  const int w = t >> 6, lane = t & 63;
  const int ln = lane & 15, quad = lane >> 4;
  const int hw = blockIdx.x;                 // 1568 = 8*196
  const int wid = (hw & 7) * 196 + (hw >> 3);
  const int tile = wid % 49;
  const int bh = wid / 49;                   // 0..31
  const int h = bh & 7, b = bh >> 3;

  // stage the 178-row local k/v window (rows clamped; out-of-range slots unused)
  const int base_n = tile * 64 - 57;
  for (int i = t; i < 712; i += 256) {
    const int c4 = i & 3;
    int rg = base_n + (i >> 2); rg = rg < 0 ? 0 : (rg > Nn - 1 ? Nn - 1 : rg);
    const unsigned short* src = fused + ((size_t)(b * Nn + rg)) * 1024 + 256 + h * HDn + c4 * 8;
    gl_lds16(src, k_s + i * 8);
    gl_lds16(src + 256, v_s + i * 8);
  }
  if (t < 32) qe_s[t] = qe[h * HDn + t];
  for (int i = t; i < HDn * LLn; i += 256) lt_s[i] = lt[h * HDn * LLn + i];
  if (t < LLn) { lb_s[t] = lb[h * LLn + t]; rpb_s[t] = rpb[h * LLn + t]; }
  __syncthreads();

  // ---- pool part (MFMA), wave w owns q-rows nb..nb+15 ----
  const int nb = tile * 64 + w * 16;
  const int nt2 = tile * 4 + w;
  const short8v afrag = *(const short8v*)(fused +
      ((size_t)(b * Nn + nb + ln)) * 1024 + h * HDn + quad * 8);
  float M4[4];
  const float sc = scal[0];
  #pragma unroll
  for (int r = 0; r < 4; ++r) M4[r] = Mq[(size_t)bh * Nn + nb + quad * 4 + r] + sc;

  // prefetch this thread's 4x14 bias row (coalesced 32 B per r)
  union U16 { uint4 u[2]; unsigned short s[16]; };
  U16 breg[4];
  #pragma unroll
  for (int r = 0; r < 4; ++r) {
    const unsigned short* bp = bias2 +
        ((((size_t)h * 196 + nt2) * 256 + (quad * 4 + r) * 16 + ln) << 4);
    breg[r].u[0] = *(const uint4*)bp;
    breg[r].u[1] = *(const uint4*)(bp + 8);
  }

  const unsigned short* kg = kbf + (size_t)bh * (MP * HDn);   // [224][32]
  const unsigned short* vg = vbf + (size_t)bh * (32 * MP);    // [32][224]
  unsigned short* pst = sh + 11392 + w * 1056;                 // strip in park

  float4v accO[2];
  accO[0] = (float4v){0.f,0.f,0.f,0.f};
  accO[1] = (float4v){0.f,0.f,0.f,0.f};
  float lsum[4] = {0.f, 0.f, 0.f, 0.f};

  #pragma unroll
  for (int kc = 0; kc < 7; ++kc) {
    #pragma unroll
    for (int mtl = 0; mtl < 2; ++mtl) {
      const int mt = kc * 2 + mtl;
      short8v bfrag = *(const short8v*)(kg + (mt * 16 + ln) * HDn + quad * 8);
      float4v s = __builtin_amdgcn_mfma_f32_16x16x32_bf16(afrag, bfrag,
                                                          (float4v){0.f,0.f,0.f,0.f}, 0, 0, 0);
      #pragma unroll
      for (int r = 0; r < 4; ++r) {
        const float bv = b2f(breg[r].s[mt]);
        const float p = __expf(s[r] + bv - M4[r]);
        const unsigned short pb = f2b(p);
        lsum[r] += b2f(pb);                       // bf16-rounded, matches ones-row MFMA
        pst[(quad * 4 + r) * 40 + mtl * 16 + ln] = pb;
      }
    }
    // P chunk (this wave's own strip; same-wave LDS ordering, no barrier)
    short8v pa = *(const short8v*)(pst + ln * 40 + quad * 8);
    #pragma unroll
    for (int nt = 0; nt < 2; ++nt) {
      short8v vb = *(const short8v*)(vg + (size_t)(nt * 16 + ln) * MP + kc * 32 + quad * 8);
      accO[nt] = __builtin_amdgcn_mfma_f32_16x16x32_bf16(pa, vb, accO[nt], 0, 0, 0);
    }
  }

  // row-sum of P (l_pool): reduce lsum across the 16 ln lanes of each quad
  #pragma unroll
  for (int r = 0; r < 4; ++r) {
    #pragma unroll
    for (int mk = 1; mk <= 8; mk <<= 1) lsum[r] += __shfl_xor(lsum[r], mk);
  }

  // park pool partials (overlays the now-dead P strip; ordered by accO dep)
  float* mypark = park + w * 528;
  #pragma unroll
  for (int r = 0; r < 4; ++r) {
    const int row = quad * 4 + r;
    mypark[row * 33 + ln]      = accO[0][r];
    mypark[row * 33 + 16 + ln] = accO[1][r];
    if (ln == 0) mypark[row * 33 + 32] = lsum[r];
  }

  // ---- local part: thread t -> n = tile*64 + (t>>2), d-slice dg = t&3 ----
  const int nl = t >> 2, dg = t & 3;
  const int n = tile * 64 + nl;
  float qs8[8];
  u4_to8f(*(const uint4*)(fused + ((size_t)(b * Nn + n)) * 1024 + h * HDn + dg * 8), qs8);
  const float M = Mq[(size_t)bh * Nn + n] + sc;
  const float spt = log1pf(__expf(temp[h]));
  const float inv_qs = 1.f / (spt * slsp[n]);

  float acc8[8], ext8[8];
  #pragma unroll
  for (int j = 0; j < 8; ++j) { acc8[j] = 0.f; ext8[j] = 0.f; }
  float l_run = 0.f;
  const int pi = n / Wn, pj = n % Wn;
  const int sb = nl + 57;
  #pragma unroll
  for (int lc = 0; lc < LLn; ++lc) {
    const int ii = pi + lc/3 - 1, jj = pj + (lc%3) - 1;
    if (ii < 0 || ii >= Hh || jj < 0 || jj >= Wn) continue;   // uniform in 4-group
    const int slot = sb + (lc/3 - 1) * 56 + (lc%3) - 1;
    float kk8[8], vv8[8];
    u4_to8f(*(const uint4*)(k_s + slot * 32 + dg * 8), kk8);
    u4_to8f(*(const uint4*)(v_s + slot * 32 + dg * 8), vv8);
    float pp = 0.f, ep = 0.f;
    #pragma unroll
    for (int j = 0; j < 8; ++j) {
      pp += qs8[j] * kk8[j];
      ep += (qs8[j] * inv_qs - qe_s[dg*8 + j]) * lt_s[(dg*8 + j) * LLn + lc];
    }
    pp += __shfl_xor(pp, 1); pp += __shfl_xor(pp, 2);
    ep += __shfl_xor(ep, 1); ep += __shfl_xor(ep, 2);
    const float e = ep + lb_s[lc];
    const float p = __expf(pp + rpb_s[lc] - M);
    l_run += p;
    #pragma unroll
    for (int j = 0; j < 8; ++j) { acc8[j] += p * vv8[j]; ext8[j] += e * vv8[j]; }
  }

  // combine with pool partials (this wave's region; no barrier needed)
  const float* pool_r = park + w * 528 + (nl - w * 16) * 33;
  const float l_pool = pool_r[32];
  const float invl = 1.f / (l_run + l_pool);
  uint4 u;
  {
    const float* op = pool_r + dg * 8;
    float o0 = (acc8[0]+op[0])*invl + ext8[0], o1 = (acc8[1]+op[1])*invl + ext8[1];
    float o2 = (acc8[2]+op[2])*invl + ext8[2], o3 = (acc8[3]+op[3])*invl + ext8[3];
    float o4 = (acc8[4]+op[4])*invl + ext8[4], o5 = (acc8[5]+op[5])*invl + ext8[5];
    float o6 = (acc8[6]+op[6])*invl + ext8[6], o7 = (acc8[7]+op[7])*invl + ext8[7];
    u.x = f2b(o0) | ((unsigned int)f2b(o1) << 16);
    u.y = f2b(o2) | ((unsigned int)f2b(o3) << 16);
    u.z = f2b(o4) | ((unsigned int)f2b(o5) << 16);
    u.w = f2b(o6) | ((unsigned int)f2b(o7) << 16);
  }
  *(uint4*)(outp + ((size_t)b * Nn + n) * Cn + h * HDn + dg * 8) = u;
}

// ---------------------------------------------------------------------------
extern "C" void kernel_launch(void* const* d_in, const int* in_sizes, int n_in,
                              void* d_out, int out_size, void* d_ws, size_t ws_size,
                              hipStream_t stream)
{
  const float* x    = (const float*)d_in[0];
  const int*   rpi  = (const int*)d_in[3];
  const float* rct  = (const float*)d_in[4];
  const float* sls  = (const float*)d_in[5];
  const float* q_w  = (const float*)d_in[7];
  const float* q_b  = (const float*)d_in[8];
  const float* kv_w = (const float*)d_in[9];
  const float* kv_b = (const float*)d_in[10];
  const float* sr_w = (const float*)d_in[11];
  const float* sr_b = (const float*)d_in[12];
  const float* ng   = (const float*)d_in[13];
  const float* nbta = (const float*)d_in[14];
  const float* c1w  = (const float*)d_in[15];
  const float* c1b  = (const float*)d_in[16];
  const float* c2w  = (const float*)d_in[17];
  const float* c2b  = (const float*)d_in[18];
  const float* temp = (const float*)d_in[19];
  const float* qe   = (const float*)d_in[20];
  const float* rpb  = (const float*)d_in[21];
  const float* lt   = (const float*)d_in[22];
  const float* lb   = (const float*)d_in[23];
  const float* pw   = (const float*)d_in[24];
  const float* pb   = (const float*)d_in[25];

  float* ws = (float*)d_ws;
  size_t o = 0;
  unsigned short* bf = (unsigned short*)(ws + o); o += TOTCVT / 2;
  unsigned short* fused = (unsigned short*)(ws + o); o += (size_t)Mrows * 512;  // bf16 [12544][1024]
  float* Mq    = ws + o;  o += (size_t)Bn * NHn * Nn;
  float* pln   = ws + o;  o += (size_t)Bn * PLn * Cn;
  unsigned short* kbf = (unsigned short*)(ws + o); o += (size_t)Bn * NHn * MP * HDn / 2;
  unsigned short* vbf = (unsigned short*)(ws + o); o += (size_t)Bn * NHn * 32 * MP / 2;
  float* tab   = ws + o;  o += (size_t)KTABn * NHn;
  float* scal  = ws + o;  o += 8;
  unsigned short* bias2 = (unsigned short*)(ws + o); o += (size_t)NHn * 196 * 256 * 16 / 2;
  unsigned short* outp  = (unsigned short*)(ws + o); o += (size_t)Mrows * Cn / 2;

  const unsigned short* xbf   = bf;
  const unsigned short* qkvsw = bf + QWOFF;
  const unsigned short* pwbf  = bf + PWOFF;

  cvt_misc<<<CVTBLK + 512 + 16, 256, 0, stream>>>(x, q_w, kv_w, sr_w, pw, bf,
                                                  rct, c1w, c1b, c2w, c2b, tab, kbf, vbf);
  mgemm<1><<<784, 512, 0, stream>>>(xbf, qkvsw, q_b, kv_b, sr_b, fused, 1024,
                                    sls, qe, temp, Mq);
  mid_k<<<2353, 256, 0, stream>>>(fused, pln, ng, nbta, rpi, tab, bias2, rpb, scal);
  gemm_pp<<<dim3(8, 13), 256, 0, stream>>>(pln, kv_w, kv_b, kbf, vbf);
  attn_f<<<1568, 256, 0, stream>>>(fused, kbf, vbf, bias2, Mq, scal,
                                   sls, temp, qe, lt, lb, rpb, outp);
  mgemm<0><<<196, 512, 0, stream>>>(outp, pwbf, pb, pb, pb, (float*)d_out, 256,
                                    nullptr, nullptr, nullptr, nullptr);
}